// Round 1
// baseline (3146.192 us; speedup 1.0000x reference)
//
#include <hip/hip_runtime.h>
#include <hip/hip_bf16.h>
#include <cmath>

namespace {

constexpr int CB = 4, CS = 1024, CD = 1024, CH = 4, CE = 32, CF = 512;
constexpr int CKS = 8, CNC = 10, CDK = 256, CDKV = 256;
constexpr int CT = CB * CS;          // 4096 tokens
constexpr float CEPS = 1e-6f;

// ---------------- reductions ----------------
__device__ __forceinline__ float blockSum256(float v) {
    __shared__ float red[4];
    int lane = threadIdx.x & 63, wid = threadIdx.x >> 6;
#pragma unroll
    for (int o = 32; o > 0; o >>= 1) v += __shfl_down(v, o, 64);
    if (lane == 0) red[wid] = v;
    __syncthreads();
    float s = red[0] + red[1] + red[2] + red[3];
    __syncthreads();
    return s;
}

__device__ __forceinline__ float blockMax256(float v) {
    __shared__ float red[4];
    int lane = threadIdx.x & 63, wid = threadIdx.x >> 6;
#pragma unroll
    for (int o = 32; o > 0; o >>= 1) v = fmaxf(v, __shfl_down(v, o, 64));
    if (lane == 0) red[wid] = v;
    __syncthreads();
    float s = fmaxf(fmaxf(red[0], red[1]), fmaxf(red[2], red[3]));
    __syncthreads();
    return s;
}

// ---------------- embedding gather ----------------
__global__ void k_embed(const int* __restrict__ tokens, const float* __restrict__ emb,
                        float* __restrict__ X) {
    int t = blockIdx.x;
    int tok = tokens[t];
    const float4* src = (const float4*)(emb + (size_t)tok * CD);
    float4* dst = (float4*)(X + (size_t)t * CD);
    dst[threadIdx.x] = src[threadIdx.x];   // 256 threads * float4 = 1024 floats
}

// ---------------- rmsnorm (row per block) ----------------
__global__ void k_rmsnorm(const float* __restrict__ in, const float* __restrict__ w,
                          float* __restrict__ out) {
    int t = blockIdx.x;
    const float* row = in + (size_t)t * CD;
    float ss = 0.f;
    for (int i = threadIdx.x; i < CD; i += 256) { float v = row[i]; ss += v * v; }
    float tot = blockSum256(ss);
    float sc = rsqrtf(tot / CD + CEPS);
    for (int i = threadIdx.x; i < CD; i += 256)
        out[(size_t)t * CD + i] = row[i] * sc * w[i];
}

// ---------------- generic 64x64x16 f32 GEMM ----------------
// C[m,n] = alpha * sum_k A[m,k]*B(k,n)  (+ Cin[m,n] if RES)
// BT=false: B is [K,N] row-major (ldb=N stride). BT=true: B is [N,K] row-major.
// z-batch: z1 = z/Zi, z2 = z%Zi applied with the given strides.
template<bool BT, bool RES>
__global__ void k_gemm(const float* __restrict__ A, int lda, long sA1, long sA2,
                       const float* __restrict__ Bm, int ldb, long sB1, long sB2,
                       const float* __restrict__ Cin,
                       float* __restrict__ C, int ldc, long sC1, long sC2,
                       int M, int N, int K, int Zi, float alpha) {
    int z = blockIdx.z, z1 = z / Zi, z2 = z % Zi;
    A  += (size_t)z1 * sA1 + (size_t)z2 * sA2;
    Bm += (size_t)z1 * sB1 + (size_t)z2 * sB2;
    C  += (size_t)z1 * sC1 + (size_t)z2 * sC2;
    __shared__ float As[16][68];
    __shared__ float Bs[16][68];
    int row0 = blockIdx.y * 64, col0 = blockIdx.x * 64;
    float acc[4][4] = {};
    int tid = threadIdx.x;
    int tx = tid & 15, ty = tid >> 4;
    for (int k0 = 0; k0 < K; k0 += 16) {
        int ka = tid & 15, ma = tid >> 4;
#pragma unroll
        for (int r = 0; r < 4; ++r) {
            int m = ma + r * 16, gm = row0 + m;
            As[ka][m] = (gm < M) ? A[(size_t)gm * lda + k0 + ka] : 0.f;
        }
        if (!BT) {
            int nb = tid & 63, kb = tid >> 6;
#pragma unroll
            for (int r = 0; r < 4; ++r) {
                int k = kb + r * 4, gn = col0 + nb;
                Bs[k][nb] = (gn < N) ? Bm[(size_t)(k0 + k) * ldb + gn] : 0.f;
            }
        } else {
            int kb = tid & 15, nb = tid >> 4;
#pragma unroll
            for (int r = 0; r < 4; ++r) {
                int n = nb + r * 16, gn = col0 + n;
                Bs[kb][n] = (gn < N) ? Bm[(size_t)gn * ldb + k0 + kb] : 0.f;
            }
        }
        __syncthreads();
#pragma unroll
        for (int kk = 0; kk < 16; ++kk) {
            float a0[4], b0[4];
#pragma unroll
            for (int i = 0; i < 4; ++i) a0[i] = As[kk][ty * 4 + i];
#pragma unroll
            for (int j = 0; j < 4; ++j) b0[j] = Bs[kk][tx * 4 + j];
#pragma unroll
            for (int i = 0; i < 4; ++i)
#pragma unroll
                for (int j = 0; j < 4; ++j)
                    acc[i][j] = fmaf(a0[i], b0[j], acc[i][j]);
        }
        __syncthreads();
    }
#pragma unroll
    for (int i = 0; i < 4; ++i) {
        int gm = row0 + ty * 4 + i;
        if (gm >= M) continue;
#pragma unroll
        for (int j = 0; j < 4; ++j) {
            int gn = col0 + tx * 4 + j;
            if (gn >= N) continue;
            float v = alpha * acc[i][j];
            if (RES) v += Cin[(size_t)gm * ldc + gn];
            C[(size_t)gm * ldc + gn] = v;
        }
    }
}

// ---------------- dual GEMM + SiLU (swiglu up-proj), optional row gather ----------------
// Cf[base+m, n] = silu(A[row(m)]@W1[e]) * (A[row(m)]@W3[e])
__global__ void k_dual_silu(const float* __restrict__ Aflat, int lda,
                            const float* __restrict__ W1, const float* __restrict__ W3,
                            int ldb, long sB,
                            float* __restrict__ Cf, int ldc,
                            const int* __restrict__ lists, const int* __restrict__ offs,
                            int Mfix, int N, int K) {
    int e = blockIdx.z;
    int base = 0, cnt = Mfix;
    if (offs) { base = offs[e]; cnt = offs[e + 1] - base; }
    int row0 = blockIdx.y * 64;
    if (row0 >= cnt) return;
    const float* B1 = W1 + (size_t)e * sB;
    const float* B3 = W3 + (size_t)e * sB;
    int col0 = blockIdx.x * 64;
    __shared__ float As[16][68], Bs1[16][68], Bs3[16][68];
    __shared__ int rowmap[64];
    int tid = threadIdx.x, tx = tid & 15, ty = tid >> 4;
    if (tid < 64) {
        int rm = row0 + tid; if (rm >= cnt) rm = cnt - 1;
        rowmap[tid] = lists ? lists[base + rm] : rm;
    }
    __syncthreads();
    float acc1[4][4] = {}, acc3[4][4] = {};
    for (int k0 = 0; k0 < K; k0 += 16) {
        int ka = tid & 15, ma = tid >> 4;
#pragma unroll
        for (int r = 0; r < 4; ++r) {
            int m = ma + r * 16;
            As[ka][m] = Aflat[(size_t)rowmap[m] * lda + k0 + ka];
        }
        int nb = tid & 63, kb = tid >> 6;
#pragma unroll
        for (int r = 0; r < 4; ++r) {
            int k = kb + r * 4, gn = col0 + nb;
            Bs1[k][nb] = B1[(size_t)(k0 + k) * ldb + gn];
            Bs3[k][nb] = B3[(size_t)(k0 + k) * ldb + gn];
        }
        __syncthreads();
#pragma unroll
        for (int kk = 0; kk < 16; ++kk) {
            float a0[4], b1[4], b3[4];
#pragma unroll
            for (int i = 0; i < 4; ++i) a0[i] = As[kk][ty * 4 + i];
#pragma unroll
            for (int j = 0; j < 4; ++j) { b1[j] = Bs1[kk][tx * 4 + j]; b3[j] = Bs3[kk][tx * 4 + j]; }
#pragma unroll
            for (int i = 0; i < 4; ++i)
#pragma unroll
                for (int j = 0; j < 4; ++j) {
                    acc1[i][j] = fmaf(a0[i], b1[j], acc1[i][j]);
                    acc3[i][j] = fmaf(a0[i], b3[j], acc3[i][j]);
                }
        }
        __syncthreads();
    }
#pragma unroll
    for (int i = 0; i < 4; ++i) {
        int gm = row0 + ty * 4 + i;
        if (gm >= cnt) continue;
#pragma unroll
        for (int j = 0; j < 4; ++j) {
            int gn = col0 + tx * 4 + j;
            float x = acc1[i][j], y = acc3[i][j];
            float s = x / (1.f + __expf(-x));
            Cf[(size_t)(base + gm) * ldc + gn] = s * y;
        }
    }
}

// ---------------- GEMM + weighted atomic scatter (down-proj / combine) ----------------
__global__ void k_gemm_scatter(const float* __restrict__ Aflat, int lda,
                               const float* __restrict__ W2, int ldb, long sB,
                               float* __restrict__ spec, int ldc,
                               const int* __restrict__ lists, const float* __restrict__ wl,
                               const int* __restrict__ offs, int Mfix, int N, int K) {
    int e = blockIdx.z;
    int base = 0, cnt = Mfix;
    if (offs) { base = offs[e]; cnt = offs[e + 1] - base; }
    int row0 = blockIdx.y * 64;
    if (row0 >= cnt) return;
    const float* Bm = W2 + (size_t)e * sB;
    const float* A = Aflat + (size_t)base * lda;
    int col0 = blockIdx.x * 64;
    __shared__ float As[16][68], Bs[16][68];
    int tid = threadIdx.x, tx = tid & 15, ty = tid >> 4;
    float acc[4][4] = {};
    for (int k0 = 0; k0 < K; k0 += 16) {
        int ka = tid & 15, ma = tid >> 4;
#pragma unroll
        for (int r = 0; r < 4; ++r) {
            int m = ma + r * 16;
            int rm = row0 + m; if (rm >= cnt) rm = cnt - 1;
            As[ka][m] = A[(size_t)rm * lda + k0 + ka];
        }
        int nb = tid & 63, kb = tid >> 6;
#pragma unroll
        for (int r = 0; r < 4; ++r) {
            int k = kb + r * 4;
            Bs[k][nb] = Bm[(size_t)(k0 + k) * ldb + col0 + nb];
        }
        __syncthreads();
#pragma unroll
        for (int kk = 0; kk < 16; ++kk) {
            float a0[4], b0[4];
#pragma unroll
            for (int i = 0; i < 4; ++i) a0[i] = As[kk][ty * 4 + i];
#pragma unroll
            for (int j = 0; j < 4; ++j) b0[j] = Bs[kk][tx * 4 + j];
#pragma unroll
            for (int i = 0; i < 4; ++i)
#pragma unroll
                for (int j = 0; j < 4; ++j)
                    acc[i][j] = fmaf(a0[i], b0[j], acc[i][j]);
        }
        __syncthreads();
    }
#pragma unroll
    for (int i = 0; i < 4; ++i) {
        int gm = row0 + ty * 4 + i;
        if (gm >= cnt) continue;
        int token = lists ? lists[base + gm] : gm;
        float w = wl ? wl[base + gm] : 1.f;
#pragma unroll
        for (int j = 0; j < 4; ++j) {
            int gn = col0 + tx * 4 + j;
            atomicAdd(&spec[(size_t)token * ldc + gn], w * acc[i][j]);
        }
    }
}

// ---------------- softmax over rows of length CS (in place) ----------------
__global__ void k_softmax(float* __restrict__ sc) {
    float* row = sc + (size_t)blockIdx.x * CS;
    float m = -1e30f;
    for (int i = threadIdx.x; i < CS; i += 256) m = fmaxf(m, row[i]);
    m = blockMax256(m);
    float s = 0.f;
    for (int i = threadIdx.x; i < CS; i += 256) { float e = __expf(row[i] - m); row[i] = e; s += e; }
    s = blockSum256(s);
    float inv = 1.f / s;
    for (int i = threadIdx.x; i < CS; i += 256) row[i] *= inv;
}

// ---------------- router: logits -> softmax -> top8 -> renorm weights ----------------
__global__ void k_router(const float* __restrict__ h2, const float* __restrict__ rw,
                         const float* __restrict__ bias, int* __restrict__ topi,
                         float* __restrict__ topw, int* __restrict__ counts) {
    int t = blockIdx.x;
    const float* row = h2 + (size_t)t * CD;
    int e = threadIdx.x & 31, j = threadIdx.x >> 5;     // 32 experts x 8 partials
    float p = 0.f;
    for (int d = j; d < CD; d += 8) p += row[d] * rw[(size_t)d * CE + e];
    __shared__ float red[8][32];
    __shared__ float probs[32];
    red[j][e] = p;
    __syncthreads();
    if (threadIdx.x < 32) {
        float lg = bias[threadIdx.x];
#pragma unroll
        for (int q = 0; q < 8; ++q) lg += red[q][threadIdx.x];
        probs[threadIdx.x] = lg;
    }
    __syncthreads();
    if (threadIdx.x == 0) {
        float mx = -1e30f;
        for (int q = 0; q < CE; ++q) mx = fmaxf(mx, probs[q]);
        float s = 0.f;
        for (int q = 0; q < CE; ++q) { float v = __expf(probs[q] - mx); probs[q] = v; s += v; }
        float inv = 1.f / s;
        for (int q = 0; q < CE; ++q) probs[q] *= inv;
        float vals[CKS]; int ids[CKS];
        for (int k = 0; k < CKS; ++k) {          // selection, lowest index wins ties
            float bv = -1.f; int bi = 0;
            for (int q = 0; q < CE; ++q) if (probs[q] > bv) { bv = probs[q]; bi = q; }
            vals[k] = bv; ids[k] = bi; probs[bi] = -2.f;
        }
        float ss = 0.f;
        for (int k = 0; k < CKS; ++k) { float v = __expf(vals[k] - vals[0]); vals[k] = v; ss += v; }
        float iv = 1.f / ss;
        for (int k = 0; k < CKS; ++k) {
            topi[t * CKS + k] = ids[k];
            topw[t * CKS + k] = vals[k] * iv;
            atomicAdd(&counts[ids[k]], 1);
        }
    }
}

__global__ void k_scan(const int* __restrict__ counts, int* __restrict__ offs) {
    if (threadIdx.x == 0) {
        int a = 0;
        for (int e = 0; e < CE; ++e) { offs[e] = a; a += counts[e]; }
        offs[CE] = a;
    }
}

__global__ void k_fill(const int* __restrict__ topi, const float* __restrict__ topw,
                       const int* __restrict__ offs, int* __restrict__ cursor,
                       int* __restrict__ lists, float* __restrict__ wl) {
    int idx = blockIdx.x * 256 + threadIdx.x;
    if (idx >= CT * CKS) return;
    int e = topi[idx];
    int pos = atomicAdd(&cursor[e], 1);
    int slot = offs[e] + pos;
    lists[slot] = idx >> 3;        // token
    wl[slot] = topw[idx];
}

__global__ void k_add(float* __restrict__ x, const float* __restrict__ y, int n4) {
    int i = blockIdx.x * 256 + threadIdx.x;
    if (i < n4) {
        float4 a = ((float4*)x)[i];
        float4 b = ((const float4*)y)[i];
        a.x += b.x; a.y += b.y; a.z += b.z; a.w += b.w;
        ((float4*)x)[i] = a;
    }
}

__global__ void k_pool(const float* __restrict__ nx, float* __restrict__ pooled) {
    int b = blockIdx.y;
    int d = blockIdx.x * 256 + threadIdx.x;
    float s = 0.f;
    for (int t = 0; t < CS; ++t) s += nx[((size_t)(b * CS + t)) * CD + d];
    pooled[b * CD + d] = s * (1.f / CS);
}

__global__ void k_head(const float* __restrict__ pooled, const float* __restrict__ cw,
                       const float* __restrict__ cb, float* __restrict__ out) {
    __shared__ float lg[CB * CNC];
    int i = threadIdx.x;
    if (i < CB * CNC) {
        int b = i / CNC, c = i % CNC;
        float s = cb[c];
        for (int d = 0; d < CD; ++d) s += pooled[b * CD + d] * cw[(size_t)d * CNC + c];
        lg[i] = s;
    }
    __syncthreads();
    if (i < CB) {
        float mx = -1e30f;
        for (int c = 0; c < CNC; ++c) mx = fmaxf(mx, lg[i * CNC + c]);
        float ex[CNC]; float s = 0.f;
        for (int c = 0; c < CNC; ++c) { ex[c] = __expf(lg[i * CNC + c] - mx); s += ex[c]; }
        for (int c = 0; c < CNC; ++c) out[i * CNC + c] = ex[c] / s;
    }
}

} // namespace

extern "C" void kernel_launch(void* const* d_in, const int* in_sizes, int n_in,
                              void* d_out, int out_size, void* d_ws, size_t ws_size,
                              hipStream_t stream) {
    const int*   tokens = (const int*)d_in[0];
    const float* emb    = (const float*)d_in[1];
    const float* n1w    = (const float*)d_in[2];
    const float* n2w    = (const float*)d_in[3];
    const float* Wq     = (const float*)d_in[4];
    const float* Wk     = (const float*)d_in[5];
    const float* Wv     = (const float*)d_in[6];
    const float* Wo     = (const float*)d_in[7];
    const float* rw     = (const float*)d_in[8];
    const float* ebias  = (const float*)d_in[9];
    const float* shw1   = (const float*)d_in[10];
    const float* shw3   = (const float*)d_in[11];
    const float* shw2   = (const float*)d_in[12];
    const float* exw1   = (const float*)d_in[13];
    const float* exw3   = (const float*)d_in[14];
    const float* exw2   = (const float*)d_in[15];
    const float* fnw    = (const float*)d_in[16];
    const float* clsw   = (const float*)d_in[17];
    const float* clsb   = (const float*)d_in[18];
    float* out = (float*)d_out;

    // workspace layout (~152 MB f32)
    float* ws  = (float*)d_ws;
    float* X   = ws;                                  // [T,D] residual
    float* Xh  = X  + (size_t)CT * CD;                // h, then X2
    float* Qb  = Xh + (size_t)CT * CD;                // Q, then h2
    float* Kc  = Qb + (size_t)CT * CD;                // [T,DKV]
    float* Vc  = Kc + (size_t)CT * CDKV;              // [T,DKV]
    float* SCb = Vc + (size_t)CT * CDKV;              // scores [B,H,S,S] / g [R,F] / normX
    float* AO  = SCb + (size_t)CB * CH * CS * CS;     // attn out, then spec accumulator
    float* HS  = AO + (size_t)CT * CD;                // shared hid [T,F]
    float* pooled = HS + (size_t)CT * CF;             // [B,D]
    float* topw = pooled + CB * CD;                   // [T,8]
    float* wl   = topw + CT * CKS;                    // [T*8]
    int* topi   = (int*)(wl + CT * CKS);              // [T,8]
    int* lists  = topi + CT * CKS;                    // [T*8]
    int* counts = lists + CT * CKS;                   // [E]
    int* cursor = counts + CE;                        // [E]
    int* offs   = cursor + CE;                        // [E+1]

    dim3 b256(256);

    k_embed<<<CT, b256, 0, stream>>>(tokens, emb, X);
    k_rmsnorm<<<CT, b256, 0, stream>>>(X, n1w, Xh);

    // QKV projections
    k_gemm<false, false><<<dim3(CD / 64, CT / 64, 1), b256, 0, stream>>>(
        Xh, CD, 0, 0, Wq, CD, 0, 0, nullptr, Qb, CD, 0, 0, CT, CD, CD, 1, 1.f);
    k_gemm<false, false><<<dim3(CDKV / 64, CT / 64, 1), b256, 0, stream>>>(
        Xh, CD, 0, 0, Wk, CDKV, 0, 0, nullptr, Kc, CDKV, 0, 0, CT, CDKV, CD, 1, 1.f);
    k_gemm<false, false><<<dim3(CDKV / 64, CT / 64, 1), b256, 0, stream>>>(
        Xh, CD, 0, 0, Wv, CDKV, 0, 0, nullptr, Vc, CDKV, 0, 0, CT, CDKV, CD, 1, 1.f);

    // scores = (1/16) Q @ Kc^T   (z = b*H + h)
    k_gemm<true, false><<<dim3(CS / 64, CS / 64, CB * CH), b256, 0, stream>>>(
        Qb, CD, (long)CS * CD, CDK,
        Kc, CDKV, (long)CS * CDKV, 0,
        nullptr,
        SCb, CS, (long)CH * CS * CS, (long)CS * CS,
        CS, CS, CDK, CH, 1.f / 16.f);
    k_softmax<<<CB * CH * CS, b256, 0, stream>>>(SCb);
    // attn @ Vc -> AO[b,s,h*DK+d]
    k_gemm<false, false><<<dim3(CDK / 64, CS / 64, CB * CH), b256, 0, stream>>>(
        SCb, CS, (long)CH * CS * CS, (long)CS * CS,
        Vc, CDKV, (long)CS * CDKV, 0,
        nullptr,
        AO, CD, (long)CS * CD, CDK,
        CS, CDK, CS, CH, 1.f);
    // X2 = X + AO @ Wo   -> Xh
    k_gemm<false, true><<<dim3(CD / 64, CT / 64, 1), b256, 0, stream>>>(
        AO, CD, 0, 0, Wo, CD, 0, 0, X, Xh, CD, 0, 0, CT, CD, CD, 1, 1.f);

    // ---- MoE ----
    hipMemsetAsync(AO, 0, (size_t)CT * CD * sizeof(float), stream);          // spec accumulator
    hipMemsetAsync(counts, 0, (size_t)(CE + CE + CE + 1) * sizeof(int), stream);
    k_rmsnorm<<<CT, b256, 0, stream>>>(Xh, n2w, Qb);                         // h2 in Qb
    k_router<<<CT, b256, 0, stream>>>(Qb, rw, ebias, topi, topw, counts);
    k_scan<<<1, 64, 0, stream>>>(counts, offs);
    k_fill<<<(CT * CKS + 255) / 256, b256, 0, stream>>>(topi, topw, offs, cursor, lists, wl);

    // shared expert
    k_dual_silu<<<dim3(CF / 64, CT / 64, 1), b256, 0, stream>>>(
        Qb, CD, shw1, shw3, CF, 0L, HS, CF, nullptr, nullptr, CT, CF, CD);
    k_gemm_scatter<<<dim3(CD / 64, CT / 64, 1), b256, 0, stream>>>(
        HS, CF, shw2, CD, 0L, AO, CD, nullptr, nullptr, nullptr, CT, CD, CF);

    // routed experts (top-8 sparse), g lives in SCb
    k_dual_silu<<<dim3(CF / 64, CT / 64, CE), b256, 0, stream>>>(
        Qb, CD, exw1, exw3, CF, (long)CD * CF, SCb, CF, lists, offs, 0, CF, CD);
    k_gemm_scatter<<<dim3(CD / 64, CT / 64, CE), b256, 0, stream>>>(
        SCb, CF, exw2, CD, (long)CF * CD, AO, CD, lists, wl, offs, 0, CD, CF);

    // X3 = X2 + (shared + spec)
    k_add<<<(CT * CD / 4 + 255) / 256, b256, 0, stream>>>(Xh, AO, CT * CD / 4);

    // head
    k_rmsnorm<<<CT, b256, 0, stream>>>(Xh, fnw, SCb);
    k_pool<<<dim3(CD / 256, CB), b256, 0, stream>>>(SCb, pooled);
    k_head<<<1, b256, 0, stream>>>(pooled, clsw, clsb, out);
}

// Round 2
// 1773.366 us; speedup vs baseline: 1.7741x; 1.7741x over previous
//
#include <hip/hip_runtime.h>
#include <hip/hip_bf16.h>
#include <cmath>

namespace {

constexpr int CB = 4, CS = 1024, CD = 1024, CH = 4, CE = 32, CF = 512;
constexpr int CKS = 8, CNC = 10, CDK = 256, CDKV = 256;
constexpr int CT = CB * CS;          // 4096 tokens
constexpr float CEPS = 1e-6f;

using hb = __hip_bfloat16;
typedef __bf16 bf16x8 __attribute__((ext_vector_type(8)));
typedef float f32x4 __attribute__((ext_vector_type(4)));

__device__ __forceinline__ void gload16(const void* g, void* l) {
    __builtin_amdgcn_global_load_lds((const __attribute__((address_space(1))) void*)g,
                                     (__attribute__((address_space(3))) void*)l, 16, 0, 0);
}

// ---------------- reductions ----------------
__device__ __forceinline__ float blockSum256(float v) {
    __shared__ float red[4];
    int lane = threadIdx.x & 63, wid = threadIdx.x >> 6;
#pragma unroll
    for (int o = 32; o > 0; o >>= 1) v += __shfl_down(v, o, 64);
    if (lane == 0) red[wid] = v;
    __syncthreads();
    float s = red[0] + red[1] + red[2] + red[3];
    __syncthreads();
    return s;
}

__device__ __forceinline__ float blockMax256(float v) {
    __shared__ float red[4];
    int lane = threadIdx.x & 63, wid = threadIdx.x >> 6;
#pragma unroll
    for (int o = 32; o > 0; o >>= 1) v = fmaxf(v, __shfl_down(v, o, 64));
    if (lane == 0) red[wid] = v;
    __syncthreads();
    float s = fmaxf(fmaxf(red[0], red[1]), fmaxf(red[2], red[3]));
    __syncthreads();
    return s;
}

// ---------------- embedding gather ----------------
__global__ void k_embed(const int* __restrict__ tokens, const float* __restrict__ emb,
                        float* __restrict__ X) {
    int t = blockIdx.x;
    int tok = tokens[t];
    const float4* src = (const float4*)(emb + (size_t)tok * CD);
    float4* dst = (float4*)(X + (size_t)t * CD);
    dst[threadIdx.x] = src[threadIdx.x];
}

// ---------------- rmsnorm ----------------
__global__ void k_rmsnorm(const float* __restrict__ in, const float* __restrict__ w,
                          float* __restrict__ out) {
    int t = blockIdx.x;
    const float* row = in + (size_t)t * CD;
    float ss = 0.f;
    for (int i = threadIdx.x; i < CD; i += 256) { float v = row[i]; ss += v * v; }
    float tot = blockSum256(ss);
    float sc = rsqrtf(tot / CD + CEPS);
    for (int i = threadIdx.x; i < CD; i += 256)
        out[(size_t)t * CD + i] = row[i] * sc * w[i];
}

// ---------------- generic 64x64x16 f32 GEMM (attention path) ----------------
template<bool BT, bool RES>
__global__ void k_gemm(const float* __restrict__ A, int lda, long sA1, long sA2,
                       const float* __restrict__ Bm, int ldb, long sB1, long sB2,
                       const float* __restrict__ Cin,
                       float* __restrict__ C, int ldc, long sC1, long sC2,
                       int M, int N, int K, int Zi, float alpha) {
    int z = blockIdx.z, z1 = z / Zi, z2 = z % Zi;
    A  += (size_t)z1 * sA1 + (size_t)z2 * sA2;
    Bm += (size_t)z1 * sB1 + (size_t)z2 * sB2;
    C  += (size_t)z1 * sC1 + (size_t)z2 * sC2;
    __shared__ float As[16][68];
    __shared__ float Bs[16][68];
    int row0 = blockIdx.y * 64, col0 = blockIdx.x * 64;
    float acc[4][4] = {};
    int tid = threadIdx.x;
    int tx = tid & 15, ty = tid >> 4;
    for (int k0 = 0; k0 < K; k0 += 16) {
        int ka = tid & 15, ma = tid >> 4;
#pragma unroll
        for (int r = 0; r < 4; ++r) {
            int m = ma + r * 16, gm = row0 + m;
            As[ka][m] = (gm < M) ? A[(size_t)gm * lda + k0 + ka] : 0.f;
        }
        if (!BT) {
            int nb = tid & 63, kb = tid >> 6;
#pragma unroll
            for (int r = 0; r < 4; ++r) {
                int k = kb + r * 4, gn = col0 + nb;
                Bs[k][nb] = (gn < N) ? Bm[(size_t)(k0 + k) * ldb + gn] : 0.f;
            }
        } else {
            int kb = tid & 15, nb = tid >> 4;
#pragma unroll
            for (int r = 0; r < 4; ++r) {
                int n = nb + r * 16, gn = col0 + n;
                Bs[kb][n] = (gn < N) ? Bm[(size_t)gn * ldb + k0 + kb] : 0.f;
            }
        }
        __syncthreads();
#pragma unroll
        for (int kk = 0; kk < 16; ++kk) {
            float a0[4], b0[4];
#pragma unroll
            for (int i = 0; i < 4; ++i) a0[i] = As[kk][ty * 4 + i];
#pragma unroll
            for (int j = 0; j < 4; ++j) b0[j] = Bs[kk][tx * 4 + j];
#pragma unroll
            for (int i = 0; i < 4; ++i)
#pragma unroll
                for (int j = 0; j < 4; ++j)
                    acc[i][j] = fmaf(a0[i], b0[j], acc[i][j]);
        }
        __syncthreads();
    }
#pragma unroll
    for (int i = 0; i < 4; ++i) {
        int gm = row0 + ty * 4 + i;
        if (gm >= M) continue;
#pragma unroll
        for (int j = 0; j < 4; ++j) {
            int gn = col0 + tx * 4 + j;
            if (gn >= N) continue;
            float v = alpha * acc[i][j];
            if (RES) v += Cin[(size_t)gm * ldc + gn];
            C[(size_t)gm * ldc + gn] = v;
        }
    }
}

// ---------------- bf16 MFMA GEMM: 128x128 tile, BK=32, 4 waves ----------------
// A [rows][lda] bf16 (k-contiguous); B [N][K] bf16 (k-contiguous rows).
// EPI: 0 = bf16 store (silu(acc1)*acc3 if DUAL), 2 = f32 store, 3 = weighted atomicAdd via lists/wl
template<bool GATHER, bool DUAL, int EPI>
__global__ __launch_bounds__(256, 2)
void k_mf(const hb* __restrict__ A, int lda,
          const hb* __restrict__ B1g, const hb* __restrict__ B3g, long sB,
          float* __restrict__ Cf, hb* __restrict__ Cb, int ldc,
          const int* __restrict__ lists, const float* __restrict__ wl,
          const int* __restrict__ offs,
          int M, int N, int K) {
    int e = blockIdx.z;
    int base = 0, cnt = M;
    if (offs) { base = offs[e]; cnt = offs[e + 1] - base; }
    int row0 = blockIdx.y * 128;
    if (row0 >= cnt) return;
    int col0 = blockIdx.x * 128;
    const hb* B1 = B1g + (size_t)e * sB;
    const hb* B3 = DUAL ? (B3g + (size_t)e * sB) : nullptr;

    __shared__ hb As[128 * 32];
    __shared__ hb Bs1[128 * 32];
    __shared__ hb Bs3[DUAL ? 128 * 32 : 8];

    int tid = threadIdx.x;
    int kq = (tid & 3) * 8;
    int r0i = tid >> 2, r1i = 64 + (tid >> 2);

    auto arowOf = [&](int r) -> size_t {
        int gr = row0 + r; gr = gr < cnt ? gr : cnt - 1;
        if (GATHER) return (size_t)lists[base + gr];
        return (size_t)(base + gr);
    };
    const hb* aS0 = A + arowOf(r0i) * lda + kq;
    const hb* aS1 = A + arowOf(r1i) * lda + kq;
    const hb* b1S0 = B1 + (size_t)(col0 + r0i) * K + kq;
    const hb* b1S1 = B1 + (size_t)(col0 + r1i) * K + kq;
    const hb* b3S0 = DUAL ? (B3 + (size_t)(col0 + r0i) * K + kq) : nullptr;
    const hb* b3S1 = DUAL ? (B3 + (size_t)(col0 + r1i) * K + kq) : nullptr;
    hb* aD0 = As + tid * 8;   hb* aD1 = As + (256 + tid) * 8;
    hb* bD0 = Bs1 + tid * 8;  hb* bD1 = Bs1 + (256 + tid) * 8;
    hb* cD0 = Bs3 + tid * 8;  hb* cD1 = Bs3 + (256 + tid) * 8;

    int lane = tid & 63, wid = tid >> 6;
    int wr = wid >> 1, wc = wid & 1;
    int lrow = lane & 15, lk = (lane >> 4) * 8;

    f32x4 acc1[4][4], acc3[4][4];
#pragma unroll
    for (int m = 0; m < 4; ++m)
#pragma unroll
        for (int n = 0; n < 4; ++n) {
            acc1[m][n] = (f32x4){0.f, 0.f, 0.f, 0.f};
            acc3[m][n] = (f32x4){0.f, 0.f, 0.f, 0.f};
        }

    for (int k0 = 0; k0 < K; k0 += 32) {
        gload16(aS0 + k0, aD0);
        gload16(aS1 + k0, aD1);
        gload16(b1S0 + k0, bD0);
        gload16(b1S1 + k0, bD1);
        if constexpr (DUAL) {
            gload16(b3S0 + k0, cD0);
            gload16(b3S1 + k0, cD1);
        }
        __syncthreads();
        bf16x8 af[4], bf1[4], bf3[4];
#pragma unroll
        for (int m = 0; m < 4; ++m)
            af[m] = *(const bf16x8*)(As + (size_t)(wr * 64 + m * 16 + lrow) * 32 + lk);
#pragma unroll
        for (int n = 0; n < 4; ++n)
            bf1[n] = *(const bf16x8*)(Bs1 + (size_t)(wc * 64 + n * 16 + lrow) * 32 + lk);
        if constexpr (DUAL) {
#pragma unroll
            for (int n = 0; n < 4; ++n)
                bf3[n] = *(const bf16x8*)(Bs3 + (size_t)(wc * 64 + n * 16 + lrow) * 32 + lk);
        }
#pragma unroll
        for (int m = 0; m < 4; ++m)
#pragma unroll
            for (int n = 0; n < 4; ++n) {
                acc1[m][n] = __builtin_amdgcn_mfma_f32_16x16x32_bf16(af[m], bf1[n], acc1[m][n], 0, 0, 0);
                if constexpr (DUAL)
                    acc3[m][n] = __builtin_amdgcn_mfma_f32_16x16x32_bf16(af[m], bf3[n], acc3[m][n], 0, 0, 0);
            }
        __syncthreads();
    }

    int lr4 = (lane >> 4) * 4;
#pragma unroll
    for (int m = 0; m < 4; ++m) {
#pragma unroll
        for (int q = 0; q < 4; ++q) {
            int r = row0 + wr * 64 + m * 16 + lr4 + q;
            if (r >= cnt) continue;
            size_t orow;
            float wgt = 1.f;
            if (EPI == 3) {
                int tok = lists[base + r];
                wgt = wl[base + r];
                orow = (size_t)tok * ldc;
            } else {
                orow = (size_t)(base + r) * ldc;
            }
#pragma unroll
            for (int n = 0; n < 4; ++n) {
                int cc = col0 + wc * 64 + n * 16 + (lane & 15);
                float v = acc1[m][n][q];
                if constexpr (EPI == 0) {
                    if constexpr (DUAL) {
                        float y = acc3[m][n][q];
                        v = v / (1.f + __expf(-v)) * y;
                    }
                    Cb[orow + cc] = __float2bfloat16(v);
                } else if constexpr (EPI == 2) {
                    Cf[orow + cc] = v;
                } else {
                    atomicAdd(&Cf[orow + cc], wgt * v);
                }
            }
        }
    }
}

// ---------------- conversions ----------------
__global__ void k_f2b(const float* __restrict__ in, hb* __restrict__ out) {
    int i = blockIdx.x * 256 + threadIdx.x;
    out[i] = __float2bfloat16(in[i]);
}

// in [z][R][C] f32 -> out [z][C][R] bf16
__global__ void k_cvt_t(const float* __restrict__ in, hb* __restrict__ out, int R, int C) {
    size_t zoff = (size_t)blockIdx.z * R * C;
    in += zoff; out += zoff;
    __shared__ float t[32][33];
    int c0 = blockIdx.x * 32, r0 = blockIdx.y * 32;
    int tx = threadIdx.x & 31, ty = threadIdx.x >> 5;
#pragma unroll
    for (int j = 0; j < 4; ++j)
        t[ty + 8 * j][tx] = in[(size_t)(r0 + ty + 8 * j) * C + c0 + tx];
    __syncthreads();
#pragma unroll
    for (int j = 0; j < 4; ++j)
        out[(size_t)(c0 + ty + 8 * j) * R + r0 + tx] = __float2bfloat16(t[tx][ty + 8 * j]);
}

// ---------------- softmax rows of CS (in place, f32) ----------------
__global__ void k_softmax(float* __restrict__ sc) {
    float* row = sc + (size_t)blockIdx.x * CS;
    float m = -1e30f;
    for (int i = threadIdx.x; i < CS; i += 256) m = fmaxf(m, row[i]);
    m = blockMax256(m);
    float s = 0.f;
    for (int i = threadIdx.x; i < CS; i += 256) { float e = __expf(row[i] - m); row[i] = e; s += e; }
    s = blockSum256(s);
    float inv = 1.f / s;
    for (int i = threadIdx.x; i < CS; i += 256) row[i] *= inv;
}

// ---------------- router ----------------
__global__ void k_router(const float* __restrict__ h2, const float* __restrict__ rw,
                         const float* __restrict__ bias, int* __restrict__ topi,
                         float* __restrict__ topw, int* __restrict__ counts) {
    int t = blockIdx.x;
    const float* row = h2 + (size_t)t * CD;
    int e = threadIdx.x & 31, j = threadIdx.x >> 5;
    float p = 0.f;
    for (int d = j; d < CD; d += 8) p += row[d] * rw[(size_t)d * CE + e];
    __shared__ float red[8][32];
    __shared__ float probs[32];
    red[j][e] = p;
    __syncthreads();
    if (threadIdx.x < 32) {
        float lg = bias[threadIdx.x];
#pragma unroll
        for (int q = 0; q < 8; ++q) lg += red[q][threadIdx.x];
        probs[threadIdx.x] = lg;
    }
    __syncthreads();
    if (threadIdx.x == 0) {
        float mx = -1e30f;
        for (int q = 0; q < CE; ++q) mx = fmaxf(mx, probs[q]);
        float s = 0.f;
        for (int q = 0; q < CE; ++q) { float v = __expf(probs[q] - mx); probs[q] = v; s += v; }
        float inv = 1.f / s;
        for (int q = 0; q < CE; ++q) probs[q] *= inv;
        float vals[CKS]; int ids[CKS];
        for (int k = 0; k < CKS; ++k) {
            float bv = -1.f; int bi = 0;
            for (int q = 0; q < CE; ++q) if (probs[q] > bv) { bv = probs[q]; bi = q; }
            vals[k] = bv; ids[k] = bi; probs[bi] = -2.f;
        }
        float ss = 0.f;
        for (int k = 0; k < CKS; ++k) { float v = __expf(vals[k] - vals[0]); vals[k] = v; ss += v; }
        float iv = 1.f / ss;
        for (int k = 0; k < CKS; ++k) {
            topi[t * CKS + k] = ids[k];
            topw[t * CKS + k] = vals[k] * iv;
            atomicAdd(&counts[ids[k]], 1);
        }
    }
}

__global__ void k_scan(const int* __restrict__ counts, int* __restrict__ offs) {
    if (threadIdx.x == 0) {
        int a = 0;
        for (int e = 0; e < CE; ++e) { offs[e] = a; a += counts[e]; }
        offs[CE] = a;
    }
}

__global__ void k_fill(const int* __restrict__ topi, const float* __restrict__ topw,
                       const int* __restrict__ offs, int* __restrict__ cursor,
                       int* __restrict__ lists, float* __restrict__ wl) {
    int idx = blockIdx.x * 256 + threadIdx.x;
    if (idx >= CT * CKS) return;
    int e = topi[idx];
    int pos = atomicAdd(&cursor[e], 1);
    int slot = offs[e] + pos;
    lists[slot] = idx >> 3;
    wl[slot] = topw[idx];
}

__global__ void k_add(float* __restrict__ x, const float* __restrict__ y, int n4) {
    int i = blockIdx.x * 256 + threadIdx.x;
    if (i < n4) {
        float4 a = ((float4*)x)[i];
        float4 b = ((const float4*)y)[i];
        a.x += b.x; a.y += b.y; a.z += b.z; a.w += b.w;
        ((float4*)x)[i] = a;
    }
}

__global__ void k_pool(const float* __restrict__ nx, float* __restrict__ pooled) {
    int b = blockIdx.y;
    int d = blockIdx.x * 256 + threadIdx.x;
    float s = 0.f;
    for (int t = 0; t < CS; ++t) s += nx[((size_t)(b * CS + t)) * CD + d];
    pooled[b * CD + d] = s * (1.f / CS);
}

__global__ void k_head(const float* __restrict__ pooled, const float* __restrict__ cw,
                       const float* __restrict__ cb, float* __restrict__ out) {
    __shared__ float lg[CB * CNC];
    int i = threadIdx.x;
    if (i < CB * CNC) {
        int b = i / CNC, c = i % CNC;
        float s = cb[c];
        for (int d = 0; d < CD; ++d) s += pooled[b * CD + d] * cw[(size_t)d * CNC + c];
        lg[i] = s;
    }
    __syncthreads();
    if (i < CB) {
        float mx = -1e30f;
        for (int c = 0; c < CNC; ++c) mx = fmaxf(mx, lg[i * CNC + c]);
        float ex[CNC]; float s = 0.f;
        for (int c = 0; c < CNC; ++c) { ex[c] = __expf(lg[i * CNC + c] - mx); s += ex[c]; }
        for (int c = 0; c < CNC; ++c) out[i * CNC + c] = ex[c] / s;
    }
}

} // namespace

extern "C" void kernel_launch(void* const* d_in, const int* in_sizes, int n_in,
                              void* d_out, int out_size, void* d_ws, size_t ws_size,
                              hipStream_t stream) {
    const int*   tokens = (const int*)d_in[0];
    const float* emb    = (const float*)d_in[1];
    const float* n1w    = (const float*)d_in[2];
    const float* n2w    = (const float*)d_in[3];
    const float* Wq     = (const float*)d_in[4];
    const float* Wk     = (const float*)d_in[5];
    const float* Wv     = (const float*)d_in[6];
    const float* Wo     = (const float*)d_in[7];
    const float* rw     = (const float*)d_in[8];
    const float* ebias  = (const float*)d_in[9];
    const float* shw1   = (const float*)d_in[10];
    const float* shw3   = (const float*)d_in[11];
    const float* shw2   = (const float*)d_in[12];
    const float* exw1   = (const float*)d_in[13];
    const float* exw3   = (const float*)d_in[14];
    const float* exw2   = (const float*)d_in[15];
    const float* fnw    = (const float*)d_in[16];
    const float* clsw   = (const float*)d_in[17];
    const float* clsb   = (const float*)d_in[18];
    float* out = (float*)d_out;

    // ---- workspace layout ----
    float* ws  = (float*)d_ws;
    float* X    = ws;                       // 4M f32 (residual; later normX)
    float* Xh   = X  + 4194304;             // 4M (h1; X2 after Wo)
    float* Qb   = Xh + 4194304;             // 4M (Q f32; later h2 f32)
    float* Kc   = Qb + 4194304;             // 1M
    float* Vc   = Kc + 1048576;             // 1M
    float* SCb  = Vc + 1048576;             // 16M f32 scores; later exw1t+exw3t (bf16)
    float* AO   = SCb + 16777216;           // 4M (attn out; later shared+spec accumulator)
    float* pooled = AO + 4194304;           // 4096
    float* topw = pooled + 4096;            // 32768
    float* wl   = topw + 32768;             // 32768
    int* topi   = (int*)(wl + 32768);       // 32768
    int* lists  = topi + 32768;             // 32768
    int* counts = lists + 32768;            // 32
    int* cursor = counts + CE;              // 32
    int* offs   = cursor + CE;              // 33
    size_t foff = ((size_t)((char*)(offs + 33) - (char*)d_ws) + 255) & ~(size_t)255;
    hb* h2b   = (hb*)((char*)d_ws + foff);  // 4M bf16
    hb* shw1t = h2b + 4194304;              // 512K
    hb* shw3t = shw1t + 524288;
    hb* shw2t = shw3t + 524288;
    hb* HSb   = shw2t + 524288;             // 2M
    hb* g     = HSb + 2097152;              // 16M bf16
    hb* exw2t = g + 16777216;               // 16M bf16
    hb* exw1t = (hb*)SCb;                   // 16M bf16 (overlaid on scores)
    hb* exw3t = exw1t + 16777216;           // 16M bf16

    dim3 b256(256);

    // ---- attention (f32, unchanged) ----
    k_embed<<<CT, b256, 0, stream>>>(tokens, emb, X);
    k_rmsnorm<<<CT, b256, 0, stream>>>(X, n1w, Xh);
    k_gemm<false, false><<<dim3(CD / 64, CT / 64, 1), b256, 0, stream>>>(
        Xh, CD, 0, 0, Wq, CD, 0, 0, nullptr, Qb, CD, 0, 0, CT, CD, CD, 1, 1.f);
    k_gemm<false, false><<<dim3(CDKV / 64, CT / 64, 1), b256, 0, stream>>>(
        Xh, CD, 0, 0, Wk, CDKV, 0, 0, nullptr, Kc, CDKV, 0, 0, CT, CDKV, CD, 1, 1.f);
    k_gemm<false, false><<<dim3(CDKV / 64, CT / 64, 1), b256, 0, stream>>>(
        Xh, CD, 0, 0, Wv, CDKV, 0, 0, nullptr, Vc, CDKV, 0, 0, CT, CDKV, CD, 1, 1.f);
    k_gemm<true, false><<<dim3(CS / 64, CS / 64, CB * CH), b256, 0, stream>>>(
        Qb, CD, (long)CS * CD, CDK,
        Kc, CDKV, (long)CS * CDKV, 0,
        nullptr,
        SCb, CS, (long)CH * CS * CS, (long)CS * CS,
        CS, CS, CDK, CH, 1.f / 16.f);
    k_softmax<<<CB * CH * CS, b256, 0, stream>>>(SCb);
    k_gemm<false, false><<<dim3(CDK / 64, CS / 64, CB * CH), b256, 0, stream>>>(
        SCb, CS, (long)CH * CS * CS, (long)CS * CS,
        Vc, CDKV, (long)CS * CDKV, 0,
        nullptr,
        AO, CD, (long)CS * CD, CDK,
        CS, CDK, CS, CH, 1.f);
    k_gemm<false, true><<<dim3(CD / 64, CT / 64, 1), b256, 0, stream>>>(
        AO, CD, 0, 0, Wo, CD, 0, 0, X, Xh, CD, 0, 0, CT, CD, CD, 1, 1.f);

    // ---- weight conversions (SCb is dead now; exw1t/exw3t overlay it) ----
    k_cvt_t<<<dim3(CF / 32, CD / 32, 1), b256, 0, stream>>>(shw1, shw1t, CD, CF);
    k_cvt_t<<<dim3(CF / 32, CD / 32, 1), b256, 0, stream>>>(shw3, shw3t, CD, CF);
    k_cvt_t<<<dim3(CD / 32, CF / 32, 1), b256, 0, stream>>>(shw2, shw2t, CF, CD);
    k_cvt_t<<<dim3(CF / 32, CD / 32, CE), b256, 0, stream>>>(exw1, exw1t, CD, CF);
    k_cvt_t<<<dim3(CF / 32, CD / 32, CE), b256, 0, stream>>>(exw3, exw3t, CD, CF);
    k_cvt_t<<<dim3(CD / 32, CF / 32, CE), b256, 0, stream>>>(exw2, exw2t, CF, CD);

    // ---- MoE ----
    hipMemsetAsync(counts, 0, (size_t)(CE + CE + CE + 1) * sizeof(int), stream);
    k_rmsnorm<<<CT, b256, 0, stream>>>(Xh, n2w, Qb);                 // h2 f32 (router path, untouched)
    k_f2b<<<CT * CD / 256, b256, 0, stream>>>(Qb, h2b);
    k_router<<<CT, b256, 0, stream>>>(Qb, rw, ebias, topi, topw, counts);
    k_scan<<<1, 64, 0, stream>>>(counts, offs);
    k_fill<<<(CT * CKS + 255) / 256, b256, 0, stream>>>(topi, topw, offs, cursor, lists, wl);

    // shared expert (bf16 MFMA): HSb = silu(h2b@w1)*(h2b@w3); AO = HSb@w2 (plain store)
    k_mf<false, true, 0><<<dim3(CF / 128, CT / 128, 1), b256, 0, stream>>>(
        h2b, CD, shw1t, shw3t, 0, nullptr, HSb, CF, nullptr, nullptr, nullptr, CT, CF, CD);
    k_mf<false, false, 2><<<dim3(CD / 128, CT / 128, 1), b256, 0, stream>>>(
        HSb, CF, shw2t, nullptr, 0, AO, nullptr, CD, nullptr, nullptr, nullptr, CT, CD, CF);

    // routed experts (bf16 MFMA, gathered): g = silu(.)*(.); AO += w * (g@w2) scattered
    k_mf<true, true, 0><<<dim3(CF / 128, CT / 128, CE), b256, 0, stream>>>(
        h2b, CD, exw1t, exw3t, (long)CF * CD, nullptr, g, CF, lists, nullptr, offs, 0, CF, CD);
    k_mf<false, false, 3><<<dim3(CD / 128, CT / 128, CE), b256, 0, stream>>>(
        g, CF, exw2t, nullptr, (long)CD * CF, AO, nullptr, CD, lists, wl, offs, 0, CD, CF);

    // X3 = X2 + (shared + spec)
    k_add<<<(CT * CD / 4 + 255) / 256, b256, 0, stream>>>(Xh, AO, CT * CD / 4);

    // head
    k_rmsnorm<<<CT, b256, 0, stream>>>(Xh, fnw, X);
    k_pool<<<dim3(CD / 256, CB), b256, 0, stream>>>(X, pooled);
    k_head<<<1, b256, 0, stream>>>(pooled, clsw, clsb, out);
}

// Round 3
// 983.320 us; speedup vs baseline: 3.1996x; 1.8034x over previous
//
#include <hip/hip_runtime.h>
#include <hip/hip_bf16.h>
#include <cmath>

namespace {

constexpr int CB = 4, CS = 1024, CD = 1024, CH = 4, CE = 32, CF = 512;
constexpr int CKS = 8, CNC = 10, CDK = 256, CDKV = 256;
constexpr int CT = CB * CS;
constexpr float CEPS = 1e-6f;

using hb = __hip_bfloat16;
typedef __bf16 bf16x8 __attribute__((ext_vector_type(8)));
typedef float f32x4 __attribute__((ext_vector_type(4)));

__device__ __forceinline__ void gload16(const void* g, void* l) {
    __builtin_amdgcn_global_load_lds((const __attribute__((address_space(1))) void*)g,
                                     (__attribute__((address_space(3))) void*)l, 16, 0, 0);
}

__device__ __forceinline__ float b2f(unsigned short u) {
    return __uint_as_float(((unsigned)u) << 16);
}
__device__ __forceinline__ unsigned short f2bu(float x) {
    hb h = __float2bfloat16(x);
    unsigned short u;
    __builtin_memcpy(&u, &h, 2);
    return u;
}

// ---------------- reductions ----------------
__device__ __forceinline__ float blockSum256(float v) {
    __shared__ float red[4];
    int lane = threadIdx.x & 63, wid = threadIdx.x >> 6;
#pragma unroll
    for (int o = 32; o > 0; o >>= 1) v += __shfl_down(v, o, 64);
    if (lane == 0) red[wid] = v;
    __syncthreads();
    float s = red[0] + red[1] + red[2] + red[3];
    __syncthreads();
    return s;
}
__device__ __forceinline__ float blockMax256(float v) {
    __shared__ float red[4];
    int lane = threadIdx.x & 63, wid = threadIdx.x >> 6;
#pragma unroll
    for (int o = 32; o > 0; o >>= 1) v = fmaxf(v, __shfl_down(v, o, 64));
    if (lane == 0) red[wid] = v;
    __syncthreads();
    float s = fmaxf(fmaxf(red[0], red[1]), fmaxf(red[2], red[3]));
    __syncthreads();
    return s;
}

// ---------------- embedding gather ----------------
__global__ void k_embed(const int* __restrict__ tokens, const float* __restrict__ emb,
                        float* __restrict__ X) {
    int t = blockIdx.x;
    int tok = tokens[t];
    const float4* src = (const float4*)(emb + (size_t)tok * CD);
    float4* dst = (float4*)(X + (size_t)t * CD);
    dst[threadIdx.x] = src[threadIdx.x];
}

// ---------------- rmsnorm: f32 out / bf16 out ----------------
__global__ void k_rmsnorm(const float* __restrict__ in, const float* __restrict__ w,
                          float* __restrict__ out) {
    int t = blockIdx.x;
    const float* row = in + (size_t)t * CD;
    float ss = 0.f;
    for (int i = threadIdx.x; i < CD; i += 256) { float v = row[i]; ss += v * v; }
    float tot = blockSum256(ss);
    float sc = rsqrtf(tot / CD + CEPS);
    for (int i = threadIdx.x; i < CD; i += 256)
        out[(size_t)t * CD + i] = row[i] * sc * w[i];
}
__global__ void k_rmsnorm_b(const float* __restrict__ in, const float* __restrict__ w,
                            hb* __restrict__ out) {
    int t = blockIdx.x;
    const float* row = in + (size_t)t * CD;
    float ss = 0.f;
    for (int i = threadIdx.x; i < CD; i += 256) { float v = row[i]; ss += v * v; }
    float tot = blockSum256(ss);
    float sc = rsqrtf(tot / CD + CEPS);
    for (int i = threadIdx.x; i < CD; i += 256)
        out[(size_t)t * CD + i] = __float2bfloat16(row[i] * sc * w[i]);
}

// ---------------- bf16 MFMA GEMM: 128x128 tile, BK=32, 4 waves ----------------
// C[m,n] = alpha * sum_k A[m,k]*B[n,k]  (B rows are k-contiguous, stride ldb)
// z-batch: z1=z/Zi, z2=z%Zi offsets applied to A/B/C with given strides.
// EPI: 0 bf16 store (silu(acc1)*acc3 if DUAL, else alpha*acc)
//      2 f32 store (alpha*acc)
//      3 weighted f32 atomicAdd via lists/wl
//      4 f32 store alpha*acc + Cin (residual)
template<bool GATHER, bool DUAL, int EPI>
__global__ __launch_bounds__(256, 2)
void k_mf(const hb* __restrict__ A, int lda, long sA1, long sA2,
          const hb* __restrict__ B1g, const hb* __restrict__ B3g, int ldb, long sB1, long sB2,
          const float* __restrict__ Cin, float* __restrict__ Cf, hb* __restrict__ Cb,
          int ldc, long sC1, long sC2,
          const int* __restrict__ lists, const float* __restrict__ wl,
          const int* __restrict__ offs,
          int M, int N, int K, int Zi, float alpha) {
    int z = blockIdx.z, z1 = z / Zi, z2 = z % Zi;
    A += (size_t)z1 * sA1 + (size_t)z2 * sA2;
    const hb* B1 = B1g + (size_t)z1 * sB1 + (size_t)z2 * sB2;
    const hb* B3 = DUAL ? (B3g + (size_t)z1 * sB1 + (size_t)z2 * sB2) : nullptr;
    long coff = (size_t)z1 * sC1 + (size_t)z2 * sC2;
    if (Cf) Cf += coff;
    if (Cb) Cb += coff;
    if (Cin) Cin += coff;

    int base = 0, cnt = M;
    if (offs) { base = offs[z]; cnt = offs[z + 1] - base; }
    int row0 = blockIdx.y * 128;
    if (row0 >= cnt) return;
    int col0 = blockIdx.x * 128;

    __shared__ hb As[128 * 32];
    __shared__ hb Bs1[128 * 32];
    __shared__ hb Bs3[DUAL ? 128 * 32 : 8];

    int tid = threadIdx.x;
    int kq = (tid & 3) * 8;
    int r0i = tid >> 2, r1i = 64 + (tid >> 2);

    auto arowOf = [&](int r) -> size_t {
        int gr = row0 + r; gr = gr < cnt ? gr : cnt - 1;
        if (GATHER) return (size_t)lists[base + gr];
        return (size_t)(base + gr);
    };
    const hb* aS0 = A + arowOf(r0i) * lda + kq;
    const hb* aS1 = A + arowOf(r1i) * lda + kq;
    const hb* b1S0 = B1 + (size_t)(col0 + r0i) * ldb + kq;
    const hb* b1S1 = B1 + (size_t)(col0 + r1i) * ldb + kq;
    const hb* b3S0 = DUAL ? (B3 + (size_t)(col0 + r0i) * ldb + kq) : nullptr;
    const hb* b3S1 = DUAL ? (B3 + (size_t)(col0 + r1i) * ldb + kq) : nullptr;
    hb* aD0 = As + tid * 8;   hb* aD1 = As + (256 + tid) * 8;
    hb* bD0 = Bs1 + tid * 8;  hb* bD1 = Bs1 + (256 + tid) * 8;
    hb* cD0 = Bs3 + tid * 8;  hb* cD1 = Bs3 + (256 + tid) * 8;

    int lane = tid & 63, wid = tid >> 6;
    int wr = wid >> 1, wc = wid & 1;
    int lrow = lane & 15, lk = (lane >> 4) * 8;

    f32x4 acc1[4][4], acc3[4][4];
#pragma unroll
    for (int m = 0; m < 4; ++m)
#pragma unroll
        for (int n = 0; n < 4; ++n) {
            acc1[m][n] = (f32x4){0.f, 0.f, 0.f, 0.f};
            acc3[m][n] = (f32x4){0.f, 0.f, 0.f, 0.f};
        }

    for (int k0 = 0; k0 < K; k0 += 32) {
        gload16(aS0 + k0, aD0);
        gload16(aS1 + k0, aD1);
        gload16(b1S0 + k0, bD0);
        gload16(b1S1 + k0, bD1);
        if constexpr (DUAL) {
            gload16(b3S0 + k0, cD0);
            gload16(b3S1 + k0, cD1);
        }
        __syncthreads();
        bf16x8 af[4], bf1[4], bf3[4];
#pragma unroll
        for (int m = 0; m < 4; ++m)
            af[m] = *(const bf16x8*)(As + (size_t)(wr * 64 + m * 16 + lrow) * 32 + lk);
#pragma unroll
        for (int n = 0; n < 4; ++n)
            bf1[n] = *(const bf16x8*)(Bs1 + (size_t)(wc * 64 + n * 16 + lrow) * 32 + lk);
        if constexpr (DUAL) {
#pragma unroll
            for (int n = 0; n < 4; ++n)
                bf3[n] = *(const bf16x8*)(Bs3 + (size_t)(wc * 64 + n * 16 + lrow) * 32 + lk);
        }
#pragma unroll
        for (int m = 0; m < 4; ++m)
#pragma unroll
            for (int n = 0; n < 4; ++n) {
                acc1[m][n] = __builtin_amdgcn_mfma_f32_16x16x32_bf16(af[m], bf1[n], acc1[m][n], 0, 0, 0);
                if constexpr (DUAL)
                    acc3[m][n] = __builtin_amdgcn_mfma_f32_16x16x32_bf16(af[m], bf3[n], acc3[m][n], 0, 0, 0);
            }
        __syncthreads();
    }

    int lr4 = (lane >> 4) * 4;
#pragma unroll
    for (int m = 0; m < 4; ++m) {
#pragma unroll
        for (int q = 0; q < 4; ++q) {
            int r = row0 + wr * 64 + m * 16 + lr4 + q;
            if (r >= cnt) continue;
            size_t orow;
            float wgt = 1.f;
            if (EPI == 3) {
                int tok = lists[base + r];
                wgt = wl[base + r];
                orow = (size_t)tok * ldc;
            } else {
                orow = (size_t)(base + r) * ldc;
            }
#pragma unroll
            for (int n = 0; n < 4; ++n) {
                int cc = col0 + wc * 64 + n * 16 + (lane & 15);
                float v = acc1[m][n][q];
                if constexpr (EPI == 0) {
                    if constexpr (DUAL) {
                        float y = acc3[m][n][q];
                        v = v / (1.f + __expf(-v)) * y;
                    } else {
                        v *= alpha;
                    }
                    Cb[orow + cc] = __float2bfloat16(v);
                } else if constexpr (EPI == 2) {
                    Cf[orow + cc] = alpha * v;
                } else if constexpr (EPI == 4) {
                    Cf[orow + cc] = alpha * v + Cin[orow + cc];
                } else {
                    atomicAdd(&Cf[orow + cc], wgt * v);
                }
            }
        }
    }
}

// ---------------- conversions ----------------
// in [z][R][C] f32 -> out [z][C][R] bf16
__global__ void k_cvt_t(const float* __restrict__ in, hb* __restrict__ out, int R, int C) {
    size_t zoff = (size_t)blockIdx.z * R * C;
    in += zoff; out += zoff;
    __shared__ float t[32][33];
    int c0 = blockIdx.x * 32, r0 = blockIdx.y * 32;
    int tx = threadIdx.x & 31, ty = threadIdx.x >> 5;
#pragma unroll
    for (int j = 0; j < 4; ++j)
        t[ty + 8 * j][tx] = in[(size_t)(r0 + ty + 8 * j) * C + c0 + tx];
    __syncthreads();
#pragma unroll
    for (int j = 0; j < 4; ++j)
        out[(size_t)(c0 + ty + 8 * j) * R + r0 + tx] = __float2bfloat16(t[tx][ty + 8 * j]);
}
// in [R][C] f32 -> out [C][R] f32
__global__ void k_t32(const float* __restrict__ in, float* __restrict__ out, int R, int C) {
    __shared__ float t[32][33];
    int c0 = blockIdx.x * 32, r0 = blockIdx.y * 32;
    int tx = threadIdx.x & 31, ty = threadIdx.x >> 5;
#pragma unroll
    for (int j = 0; j < 4; ++j)
        t[ty + 8 * j][tx] = in[(size_t)(r0 + ty + 8 * j) * C + c0 + tx];
    __syncthreads();
#pragma unroll
    for (int j = 0; j < 4; ++j)
        out[(size_t)(c0 + ty + 8 * j) * R + r0 + tx] = t[tx][ty + 8 * j];
}

// ---------------- softmax rows of CS, bf16 in place, single pass ----------------
__global__ void k_softmaxb(hb* __restrict__ P) {
    unsigned* row = (unsigned*)(P + (size_t)blockIdx.x * CS);  // 2 bf16 per unsigned
    unsigned u0 = row[threadIdx.x * 2], u1 = row[threadIdx.x * 2 + 1];
    float f[4];
    f[0] = __uint_as_float(u0 << 16); f[1] = __uint_as_float(u0 & 0xffff0000u);
    f[2] = __uint_as_float(u1 << 16); f[3] = __uint_as_float(u1 & 0xffff0000u);
    float m = fmaxf(fmaxf(f[0], f[1]), fmaxf(f[2], f[3]));
    m = blockMax256(m);
    float s = 0.f;
#pragma unroll
    for (int i = 0; i < 4; ++i) { f[i] = __expf(f[i] - m); s += f[i]; }
    s = blockSum256(s);
    float inv = 1.f / s;
    unsigned o0 = ((unsigned)f2bu(f[0])) | (((unsigned)f2bu(f[1])) << 16);
    unsigned o1 = ((unsigned)f2bu(f[2])) | (((unsigned)f2bu(f[3])) << 16);
    // note: f2bu after scaling
    o0 = ((unsigned)f2bu(f[0] * inv)) | (((unsigned)f2bu(f[1] * inv)) << 16);
    o1 = ((unsigned)f2bu(f[2] * inv)) | (((unsigned)f2bu(f[3] * inv)) << 16);
    row[threadIdx.x * 2] = o0; row[threadIdx.x * 2 + 1] = o1;
}

// ---------------- router: logits GEMM (8 tokens/block) ----------------
__global__ void k_logits(const hb* __restrict__ h2b, const float* __restrict__ rwT,
                         const float* __restrict__ bias, float* __restrict__ logits) {
    __shared__ float hs[8][1032];
    int t0 = blockIdx.x * 8;
    int tid = threadIdx.x;
    const unsigned* src = (const unsigned*)(h2b + (size_t)t0 * CD);  // 2 bf16 each
#pragma unroll
    for (int it = 0; it < 16; ++it) {
        int j = tid + it * 256;              // 4096 x unsigned = 8192 bf16
        unsigned u = src[j];
        int fidx = j * 2;
        int r = fidx >> 10, c = fidx & 1023;
        hs[r][c] = __uint_as_float(u << 16);
        hs[r][c + 1] = __uint_as_float(u & 0xffff0000u);
    }
    __syncthreads();
    int e = tid >> 3, tl = tid & 7;
    const float4* wrow = (const float4*)(rwT + (size_t)e * CD);
    float acc = 0.f;
#pragma unroll 4
    for (int d4 = 0; d4 < 256; ++d4) {
        float4 w = wrow[d4];
        float4 h = *(const float4*)&hs[tl][d4 * 4];
        acc += w.x * h.x + w.y * h.y + w.z * h.z + w.w * h.w;
    }
    logits[(size_t)(t0 + tl) * CE + e] = acc + bias[e];
}

// ---------------- top-8 per token, one wave per token ----------------
__global__ void k_topk(const float* __restrict__ logits, int* __restrict__ topi,
                       float* __restrict__ topw, int* __restrict__ counts) {
    int t = blockIdx.x * 4 + (threadIdx.x >> 6);
    int lane = threadIdx.x & 63;
    int e = lane & 31;
    float lg = logits[(size_t)t * CE + e];
    float m = lg;
#pragma unroll
    for (int o = 16; o > 0; o >>= 1) m = fmaxf(m, __shfl_xor(m, o, 32));
    float ex = __expf(lg - m);
    float s = ex;
#pragma unroll
    for (int o = 16; o > 0; o >>= 1) s += __shfl_xor(s, o, 32);
    float val = ex / s;

    float vals[CKS]; int ids[CKS];
#pragma unroll
    for (int k = 0; k < CKS; ++k) {
        float mx = val;
#pragma unroll
        for (int o = 16; o > 0; o >>= 1) mx = fmaxf(mx, __shfl_xor(mx, o, 32));
        unsigned long long b = __ballot(val == mx);
        int sel = (__ffsll((long long)b) - 1) & 31;
        vals[k] = mx; ids[k] = sel;
        if (e == sel) val = -2.f;
    }
    float ss = 0.f; float ww[CKS];
#pragma unroll
    for (int k = 0; k < CKS; ++k) { ww[k] = __expf(vals[k] - vals[0]); ss += ww[k]; }
    float inv = 1.f / ss;
    if (lane == 0) {
#pragma unroll
        for (int k = 0; k < CKS; ++k) {
            topi[t * CKS + k] = ids[k];
            topw[t * CKS + k] = ww[k] * inv;
            atomicAdd(&counts[ids[k]], 1);
        }
    }
}

__global__ void k_scan(const int* __restrict__ counts, int* __restrict__ offs) {
    if (threadIdx.x == 0) {
        int a = 0;
        for (int e = 0; e < CE; ++e) { offs[e] = a; a += counts[e]; }
        offs[CE] = a;
    }
}

__global__ void k_fill(const int* __restrict__ topi, const float* __restrict__ topw,
                       const int* __restrict__ offs, int* __restrict__ cursor,
                       int* __restrict__ lists, float* __restrict__ wl) {
    int idx = blockIdx.x * 256 + threadIdx.x;
    if (idx >= CT * CKS) return;
    int e = topi[idx];
    int pos = atomicAdd(&cursor[e], 1);
    int slot = offs[e] + pos;
    lists[slot] = idx >> 3;
    wl[slot] = topw[idx];
}

__global__ void k_add(float* __restrict__ x, const float* __restrict__ y, int n4) {
    int i = blockIdx.x * 256 + threadIdx.x;
    if (i < n4) {
        float4 a = ((float4*)x)[i];
        float4 b = ((const float4*)y)[i];
        a.x += b.x; a.y += b.y; a.z += b.z; a.w += b.w;
        ((float4*)x)[i] = a;
    }
}

__global__ void k_pool(const float* __restrict__ nx, float* __restrict__ pooled) {
    int b = blockIdx.y;
    int d = blockIdx.x * 256 + threadIdx.x;
    float s = 0.f;
    for (int t = 0; t < CS; ++t) s += nx[((size_t)(b * CS + t)) * CD + d];
    pooled[b * CD + d] = s * (1.f / CS);
}

__global__ void k_head(const float* __restrict__ pooled, const float* __restrict__ cw,
                       const float* __restrict__ cb, float* __restrict__ out) {
    __shared__ float lg[CB * CNC];
    int i = threadIdx.x;
    if (i < CB * CNC) {
        int b = i / CNC, c = i % CNC;
        float s = cb[c];
        for (int d = 0; d < CD; ++d) s += pooled[b * CD + d] * cw[(size_t)d * CNC + c];
        lg[i] = s;
    }
    __syncthreads();
    if (i < CB) {
        float mx = -1e30f;
        for (int c = 0; c < CNC; ++c) mx = fmaxf(mx, lg[i * CNC + c]);
        float ex[CNC]; float s = 0.f;
        for (int c = 0; c < CNC; ++c) { ex[c] = __expf(lg[i * CNC + c] - mx); s += ex[c]; }
        for (int c = 0; c < CNC; ++c) out[i * CNC + c] = ex[c] / s;
    }
}

} // namespace

extern "C" void kernel_launch(void* const* d_in, const int* in_sizes, int n_in,
                              void* d_out, int out_size, void* d_ws, size_t ws_size,
                              hipStream_t stream) {
    const int*   tokens = (const int*)d_in[0];
    const float* emb    = (const float*)d_in[1];
    const float* n1w    = (const float*)d_in[2];
    const float* n2w    = (const float*)d_in[3];
    const float* Wq     = (const float*)d_in[4];
    const float* Wk     = (const float*)d_in[5];
    const float* Wv     = (const float*)d_in[6];
    const float* Wo     = (const float*)d_in[7];
    const float* rw     = (const float*)d_in[8];
    const float* ebias  = (const float*)d_in[9];
    const float* shw1   = (const float*)d_in[10];
    const float* shw3   = (const float*)d_in[11];
    const float* shw2   = (const float*)d_in[12];
    const float* exw1   = (const float*)d_in[13];
    const float* exw3   = (const float*)d_in[14];
    const float* exw2   = (const float*)d_in[15];
    const float* fnw    = (const float*)d_in[16];
    const float* clsw   = (const float*)d_in[17];
    const float* clsb   = (const float*)d_in[18];
    float* out = (float*)d_out;

    constexpr size_t MB = 1ull << 20;
    char* base = (char*)d_ws;
    // persistent f32
    float* X   = (float*)(base);             // 16 MB residual
    float* Xh  = (float*)(base + 16 * MB);   // 16 MB (h? no: X2 / X3)
    float* AO  = (float*)(base + 32 * MB);   // 16 MB shared+spec accumulator
    // misc @48MB
    float* pooled  = (float*)(base + 48 * MB);          // 16 KB
    float* topw    = pooled + 4096;                     // 128 KB
    float* wl      = topw + CT * CKS;                   // 128 KB
    float* logitsB = wl + CT * CKS;                     // 512 KB
    float* rwT     = logitsB + CT * CE;                 // 128 KB
    int* topi   = (int*)(rwT + CE * CD);                // 128 KB
    int* lists  = topi + CT * CKS;                      // 128 KB
    int* counts = lists + CT * CKS;
    int* cursor = counts + CE;
    int* offs   = cursor + CE;
    // phase pool @50MB
    char* pool = base + 50 * MB;
    // attention phase
    float* Vc = (float*)(pool);              // 4 MB
    hb* h1b  = (hb*)(pool + 4 * MB);         // 8 MB
    hb* Qbb  = (hb*)(pool + 12 * MB);        // 8 MB
    hb* Kb   = (hb*)(pool + 20 * MB);        // 2 MB
    hb* Vct  = (hb*)(pool + 22 * MB);        // 2 MB
    hb* Pb   = (hb*)(pool + 24 * MB);        // 32 MB
    hb* AOb  = (hb*)(pool + 56 * MB);        // 8 MB
    hb* Wqt  = (hb*)(pool + 64 * MB);        // 2 MB
    hb* Wot  = (hb*)(pool + 66 * MB);        // 2 MB
    hb* Wkt  = (hb*)(pool + 68 * MB);        // 1 MB
    hb* Wvt  = (hb*)(pool + 69 * MB);        // 1 MB
    // moe phase (overlays: all attn buffers dead by first write)
    hb* h2b   = (hb*)(pool);                 // 8 MB
    hb* HSb   = (hb*)(pool + 8 * MB);        // 4 MB
    hb* g     = (hb*)(pool + 12 * MB);       // 32 MB
    hb* shw1t = (hb*)(pool + 44 * MB);       // 1 MB
    hb* shw3t = (hb*)(pool + 45 * MB);       // 1 MB
    hb* shw2t = (hb*)(pool + 46 * MB);       // 1 MB
    hb* exw1t = (hb*)(pool + 47 * MB);       // 32 MB
    hb* exw3t = (hb*)(pool + 79 * MB);       // 32 MB
    hb* exw2t = (hb*)(pool + 111 * MB);      // 32 MB -> ends 193 MB total

    dim3 b256(256);

    // ---- prologue ----
    k_embed<<<CT, b256, 0, stream>>>(tokens, emb, X);
    k_rmsnorm_b<<<CT, b256, 0, stream>>>(X, n1w, h1b);
    k_t32<<<dim3(1, CD / 32), b256, 0, stream>>>(rw, rwT, CD, CE);
    // attention weight converts
    k_cvt_t<<<dim3(CD / 32, CD / 32, 1), b256, 0, stream>>>(Wq, Wqt, CD, CD);
    k_cvt_t<<<dim3(CDKV / 32, CD / 32, 1), b256, 0, stream>>>(Wk, Wkt, CD, CDKV);
    k_cvt_t<<<dim3(CDKV / 32, CD / 32, 1), b256, 0, stream>>>(Wv, Wvt, CD, CDKV);
    k_cvt_t<<<dim3(CD / 32, CD / 32, 1), b256, 0, stream>>>(Wo, Wot, CD, CD);

    // ---- attention (bf16 MFMA) ----
    // Q = h1 @ Wq   [T, D] bf16
    k_mf<false, false, 0><<<dim3(CD / 128, CT / 128, 1), b256, 0, stream>>>(
        h1b, CD, 0, 0, Wqt, nullptr, CD, 0, 0, nullptr, nullptr, Qbb, CD, 0, 0,
        nullptr, nullptr, nullptr, CT, CD, CD, 1, 1.f);
    // Kc = h1 @ Wk  [T, DKV] bf16
    k_mf<false, false, 0><<<dim3(CDKV / 128, CT / 128, 1), b256, 0, stream>>>(
        h1b, CD, 0, 0, Wkt, nullptr, CD, 0, 0, nullptr, nullptr, Kb, CDKV, 0, 0,
        nullptr, nullptr, nullptr, CT, CDKV, CD, 1, 1.f);
    // Vc = h1 @ Wv  [T, DKV] f32 -> transpose to Vct [b][DKV][S] bf16
    k_mf<false, false, 2><<<dim3(CDKV / 128, CT / 128, 1), b256, 0, stream>>>(
        h1b, CD, 0, 0, Wvt, nullptr, CD, 0, 0, nullptr, Vc, nullptr, CDKV, 0, 0,
        nullptr, nullptr, nullptr, CT, CDKV, CD, 1, 1.f);
    k_cvt_t<<<dim3(CDKV / 32, CS / 32, CB), b256, 0, stream>>>(Vc, Vct, CS, CDKV);
    // scores = (1/16) Q @ Kc^T -> Pb [b][h][S][S] bf16
    k_mf<false, false, 0><<<dim3(CS / 128, CS / 128, CB * CH), b256, 0, stream>>>(
        Qbb, CD, (long)CS * CD, CDK,
        Kb, nullptr, CDKV, (long)CS * CDKV, 0,
        nullptr, nullptr, Pb, CS, (long)CH * CS * CS, (long)CS * CS,
        nullptr, nullptr, nullptr, CS, CS, CDK, CH, 1.f / 16.f);
    k_softmaxb<<<CB * CH * CS, b256, 0, stream>>>(Pb);
    // AOb[t][h*DK+d] = P @ V
    k_mf<false, false, 0><<<dim3(CDK / 128, CS / 128, CB * CH), b256, 0, stream>>>(
        Pb, CS, (long)CH * CS * CS, (long)CS * CS,
        Vct, nullptr, CS, (long)CDKV * CS, 0,
        nullptr, nullptr, AOb, CD, (long)CS * CD, CDK,
        nullptr, nullptr, nullptr, CS, CDK, CS, CH, 1.f);
    // X2 = X + AOb @ Wo -> Xh (f32)
    k_mf<false, false, 4><<<dim3(CD / 128, CT / 128, 1), b256, 0, stream>>>(
        AOb, CD, 0, 0, Wot, nullptr, CD, 0, 0, X, Xh, nullptr, CD, 0, 0,
        nullptr, nullptr, nullptr, CT, CD, CD, 1, 1.f);

    // ---- MoE ----
    k_rmsnorm_b<<<CT, b256, 0, stream>>>(Xh, n2w, h2b);
    hipMemsetAsync(counts, 0, (size_t)(CE + CE + CE + 1) * sizeof(int), stream);
    k_logits<<<CT / 8, b256, 0, stream>>>(h2b, rwT, ebias, logitsB);
    k_topk<<<CT / 4, b256, 0, stream>>>(logitsB, topi, topw, counts);
    k_scan<<<1, 64, 0, stream>>>(counts, offs);
    k_fill<<<(CT * CKS + 255) / 256, b256, 0, stream>>>(topi, topw, offs, cursor, lists, wl);

    // MoE weight converts (after Wo: these overlay dead attention buffers)
    k_cvt_t<<<dim3(CF / 32, CD / 32, 1), b256, 0, stream>>>(shw1, shw1t, CD, CF);
    k_cvt_t<<<dim3(CF / 32, CD / 32, 1), b256, 0, stream>>>(shw3, shw3t, CD, CF);
    k_cvt_t<<<dim3(CD / 32, CF / 32, 1), b256, 0, stream>>>(shw2, shw2t, CF, CD);
    k_cvt_t<<<dim3(CF / 32, CD / 32, CE), b256, 0, stream>>>(exw1, exw1t, CD, CF);
    k_cvt_t<<<dim3(CF / 32, CD / 32, CE), b256, 0, stream>>>(exw3, exw3t, CD, CF);
    k_cvt_t<<<dim3(CD / 32, CF / 32, CE), b256, 0, stream>>>(exw2, exw2t, CF, CD);

    // shared expert: HSb = silu(h2@w1)*(h2@w3); AO = HSb @ w2 (plain f32 store)
    k_mf<false, true, 0><<<dim3(CF / 128, CT / 128, 1), b256, 0, stream>>>(
        h2b, CD, 0, 0, shw1t, shw3t, CD, 0, 0, nullptr, nullptr, HSb, CF, 0, 0,
        nullptr, nullptr, nullptr, CT, CF, CD, 1, 1.f);
    k_mf<false, false, 2><<<dim3(CD / 128, CT / 128, 1), b256, 0, stream>>>(
        HSb, CF, 0, 0, shw2t, nullptr, CF, 0, 0, nullptr, AO, nullptr, CD, 0, 0,
        nullptr, nullptr, nullptr, CT, CD, CF, 1, 1.f);
    // routed experts
    k_mf<true, true, 0><<<dim3(CF / 128, CT / 128, CE), b256, 0, stream>>>(
        h2b, CD, 0, 0, exw1t, exw3t, CD, (long)CD * CF, 0, nullptr, nullptr, g, CF, 0, 0,
        lists, nullptr, offs, 0, CF, CD, 1, 1.f);
    k_mf<false, false, 3><<<dim3(CD / 128, CT / 128, CE), b256, 0, stream>>>(
        g, CF, 0, 0, exw2t, nullptr, CF, (long)CF * CD, 0, nullptr, AO, nullptr, CD, 0, 0,
        lists, wl, offs, 0, CD, CF, 1, 1.f);

    // X3 = X2 + (shared + spec)
    k_add<<<(CT * CD / 4 + 255) / 256, b256, 0, stream>>>(Xh, AO, CT * CD / 4);

    // head
    k_rmsnorm<<<CT, b256, 0, stream>>>(Xh, fnw, X);
    k_pool<<<dim3(CD / 256, CB), b256, 0, stream>>>(X, pooled);
    k_head<<<1, b256, 0, stream>>>(pooled, clsw, clsb, out);
}

// Round 4
// 727.582 us; speedup vs baseline: 4.3242x; 1.3515x over previous
//
#include <hip/hip_runtime.h>
#include <hip/hip_bf16.h>
#include <cmath>

namespace {

constexpr int CB = 4, CS = 1024, CD = 1024, CH = 4, CE = 32, CF = 512;
constexpr int CKS = 8, CNC = 10, CDK = 256, CDKV = 256;
constexpr int CT = CB * CS;
constexpr float CEPS = 1e-6f;

using hb = __hip_bfloat16;
typedef __bf16 bf16x8 __attribute__((ext_vector_type(8)));
typedef float f32x4 __attribute__((ext_vector_type(4)));

__device__ __forceinline__ void gload16(const void* g, void* l) {
    __builtin_amdgcn_global_load_lds((const __attribute__((address_space(1))) void*)g,
                                     (__attribute__((address_space(3))) void*)l, 16, 0, 0);
}

__device__ __forceinline__ unsigned short f2bu(float x) {
    hb h = __float2bfloat16(x);
    unsigned short u;
    __builtin_memcpy(&u, &h, 2);
    return u;
}

// ---------------- reductions ----------------
__device__ __forceinline__ float blockSum256(float v) {
    __shared__ float red[4];
    int lane = threadIdx.x & 63, wid = threadIdx.x >> 6;
#pragma unroll
    for (int o = 32; o > 0; o >>= 1) v += __shfl_down(v, o, 64);
    if (lane == 0) red[wid] = v;
    __syncthreads();
    float s = red[0] + red[1] + red[2] + red[3];
    __syncthreads();
    return s;
}
__device__ __forceinline__ float blockMax256(float v) {
    __shared__ float red[4];
    int lane = threadIdx.x & 63, wid = threadIdx.x >> 6;
#pragma unroll
    for (int o = 32; o > 0; o >>= 1) v = fmaxf(v, __shfl_down(v, o, 64));
    if (lane == 0) red[wid] = v;
    __syncthreads();
    float s = fmaxf(fmaxf(red[0], red[1]), fmaxf(red[2], red[3]));
    __syncthreads();
    return s;
}

// ---------------- embedding gather ----------------
__global__ void k_embed(const int* __restrict__ tokens, const float* __restrict__ emb,
                        float* __restrict__ X) {
    int t = blockIdx.x;
    int tok = tokens[t];
    const float4* src = (const float4*)(emb + (size_t)tok * CD);
    float4* dst = (float4*)(X + (size_t)t * CD);
    dst[threadIdx.x] = src[threadIdx.x];
}

// ---------------- rmsnorm: f32 out / bf16 out ----------------
__global__ void k_rmsnorm(const float* __restrict__ in, const float* __restrict__ w,
                          float* __restrict__ out) {
    int t = blockIdx.x;
    const float* row = in + (size_t)t * CD;
    float ss = 0.f;
    for (int i = threadIdx.x; i < CD; i += 256) { float v = row[i]; ss += v * v; }
    float tot = blockSum256(ss);
    float sc = rsqrtf(tot / CD + CEPS);
    for (int i = threadIdx.x; i < CD; i += 256)
        out[(size_t)t * CD + i] = row[i] * sc * w[i];
}
__global__ void k_rmsnorm_b(const float* __restrict__ in, const float* __restrict__ w,
                            hb* __restrict__ out) {
    int t = blockIdx.x;
    const float* row = in + (size_t)t * CD;
    float ss = 0.f;
    for (int i = threadIdx.x; i < CD; i += 256) { float v = row[i]; ss += v * v; }
    float tot = blockSum256(ss);
    float sc = rsqrtf(tot / CD + CEPS);
    for (int i = threadIdx.x; i < CD; i += 256)
        out[(size_t)t * CD + i] = __float2bfloat16(row[i] * sc * w[i]);
}

// ---------------- bf16 MFMA GEMM: 128x128 tile, BK=32, 4 waves ----------------
template<bool GATHER, bool DUAL, int EPI>
__global__ __launch_bounds__(256, 2)
void k_mf(const hb* __restrict__ A, int lda, long sA1, long sA2,
          const hb* __restrict__ B1g, const hb* __restrict__ B3g, int ldb, long sB1, long sB2,
          const float* __restrict__ Cin, float* __restrict__ Cf, hb* __restrict__ Cb,
          int ldc, long sC1, long sC2,
          const int* __restrict__ lists, const float* __restrict__ wl,
          const int* __restrict__ offs,
          int M, int N, int K, int Zi, float alpha) {
    int z = blockIdx.z, z1 = z / Zi, z2 = z % Zi;
    A += (size_t)z1 * sA1 + (size_t)z2 * sA2;
    const hb* B1 = B1g + (size_t)z1 * sB1 + (size_t)z2 * sB2;
    const hb* B3 = DUAL ? (B3g + (size_t)z1 * sB1 + (size_t)z2 * sB2) : nullptr;
    long coff = (size_t)z1 * sC1 + (size_t)z2 * sC2;
    if (Cf) Cf += coff;
    if (Cb) Cb += coff;
    if (Cin) Cin += coff;

    int base = 0, cnt = M;
    if (offs) { base = offs[z]; cnt = offs[z + 1] - base; }
    int row0 = blockIdx.y * 128;
    if (row0 >= cnt) return;
    int col0 = blockIdx.x * 128;

    __shared__ hb As[128 * 32];
    __shared__ hb Bs1[128 * 32];
    __shared__ hb Bs3[DUAL ? 128 * 32 : 8];

    int tid = threadIdx.x;
    int kq = (tid & 3) * 8;
    int r0i = tid >> 2, r1i = 64 + (tid >> 2);

    auto arowOf = [&](int r) -> size_t {
        int gr = row0 + r; gr = gr < cnt ? gr : cnt - 1;
        if (GATHER) return (size_t)lists[base + gr];
        return (size_t)(base + gr);
    };
    const hb* aS0 = A + arowOf(r0i) * lda + kq;
    const hb* aS1 = A + arowOf(r1i) * lda + kq;
    const hb* b1S0 = B1 + (size_t)(col0 + r0i) * ldb + kq;
    const hb* b1S1 = B1 + (size_t)(col0 + r1i) * ldb + kq;
    const hb* b3S0 = DUAL ? (B3 + (size_t)(col0 + r0i) * ldb + kq) : nullptr;
    const hb* b3S1 = DUAL ? (B3 + (size_t)(col0 + r1i) * ldb + kq) : nullptr;
    hb* aD0 = As + tid * 8;   hb* aD1 = As + (256 + tid) * 8;
    hb* bD0 = Bs1 + tid * 8;  hb* bD1 = Bs1 + (256 + tid) * 8;
    hb* cD0 = Bs3 + tid * 8;  hb* cD1 = Bs3 + (256 + tid) * 8;

    int lane = tid & 63, wid = tid >> 6;
    int wr = wid >> 1, wc = wid & 1;
    int lrow = lane & 15, lk = (lane >> 4) * 8;

    f32x4 acc1[4][4], acc3[4][4];
#pragma unroll
    for (int m = 0; m < 4; ++m)
#pragma unroll
        for (int n = 0; n < 4; ++n) {
            acc1[m][n] = (f32x4){0.f, 0.f, 0.f, 0.f};
            acc3[m][n] = (f32x4){0.f, 0.f, 0.f, 0.f};
        }

    for (int k0 = 0; k0 < K; k0 += 32) {
        gload16(aS0 + k0, aD0);
        gload16(aS1 + k0, aD1);
        gload16(b1S0 + k0, bD0);
        gload16(b1S1 + k0, bD1);
        if constexpr (DUAL) {
            gload16(b3S0 + k0, cD0);
            gload16(b3S1 + k0, cD1);
        }
        __syncthreads();
        bf16x8 af[4], bf1[4], bf3[4];
#pragma unroll
        for (int m = 0; m < 4; ++m)
            af[m] = *(const bf16x8*)(As + (size_t)(wr * 64 + m * 16 + lrow) * 32 + lk);
#pragma unroll
        for (int n = 0; n < 4; ++n)
            bf1[n] = *(const bf16x8*)(Bs1 + (size_t)(wc * 64 + n * 16 + lrow) * 32 + lk);
        if constexpr (DUAL) {
#pragma unroll
            for (int n = 0; n < 4; ++n)
                bf3[n] = *(const bf16x8*)(Bs3 + (size_t)(wc * 64 + n * 16 + lrow) * 32 + lk);
        }
#pragma unroll
        for (int m = 0; m < 4; ++m)
#pragma unroll
            for (int n = 0; n < 4; ++n) {
                acc1[m][n] = __builtin_amdgcn_mfma_f32_16x16x32_bf16(af[m], bf1[n], acc1[m][n], 0, 0, 0);
                if constexpr (DUAL)
                    acc3[m][n] = __builtin_amdgcn_mfma_f32_16x16x32_bf16(af[m], bf3[n], acc3[m][n], 0, 0, 0);
            }
        __syncthreads();
    }

    int lr4 = (lane >> 4) * 4;
#pragma unroll
    for (int m = 0; m < 4; ++m) {
#pragma unroll
        for (int q = 0; q < 4; ++q) {
            int r = row0 + wr * 64 + m * 16 + lr4 + q;
            if (r >= cnt) continue;
            size_t orow;
            float wgt = 1.f;
            if (EPI == 3) {
                int tok = lists[base + r];
                wgt = wl[base + r];
                orow = (size_t)tok * ldc;
            } else {
                orow = (size_t)(base + r) * ldc;
            }
#pragma unroll
            for (int n = 0; n < 4; ++n) {
                int cc = col0 + wc * 64 + n * 16 + (lane & 15);
                float v = acc1[m][n][q];
                if constexpr (EPI == 0) {
                    if constexpr (DUAL) {
                        float y = acc3[m][n][q];
                        v = v / (1.f + __expf(-v)) * y;
                    } else {
                        v *= alpha;
                    }
                    Cb[orow + cc] = __float2bfloat16(v);
                } else if constexpr (EPI == 2) {
                    Cf[orow + cc] = alpha * v;
                } else if constexpr (EPI == 4) {
                    Cf[orow + cc] = alpha * v + Cin[orow + cc];
                } else {
                    atomicAdd(&Cf[orow + cc], wgt * v);
                }
            }
        }
    }
}

// ---------------- conversions ----------------
__global__ void k_cvt_t(const float* __restrict__ in, hb* __restrict__ out, int R, int C) {
    size_t zoff = (size_t)blockIdx.z * R * C;
    in += zoff; out += zoff;
    __shared__ float t[32][33];
    int c0 = blockIdx.x * 32, r0 = blockIdx.y * 32;
    int tx = threadIdx.x & 31, ty = threadIdx.x >> 5;
#pragma unroll
    for (int j = 0; j < 4; ++j)
        t[ty + 8 * j][tx] = in[(size_t)(r0 + ty + 8 * j) * C + c0 + tx];
    __syncthreads();
#pragma unroll
    for (int j = 0; j < 4; ++j)
        out[(size_t)(c0 + ty + 8 * j) * R + r0 + tx] = __float2bfloat16(t[tx][ty + 8 * j]);
}
__global__ void k_t32(const float* __restrict__ in, float* __restrict__ out, int R, int C) {
    __shared__ float t[32][33];
    int c0 = blockIdx.x * 32, r0 = blockIdx.y * 32;
    int tx = threadIdx.x & 31, ty = threadIdx.x >> 5;
#pragma unroll
    for (int j = 0; j < 4; ++j)
        t[ty + 8 * j][tx] = in[(size_t)(r0 + ty + 8 * j) * C + c0 + tx];
    __syncthreads();
#pragma unroll
    for (int j = 0; j < 4; ++j)
        out[(size_t)(c0 + ty + 8 * j) * R + r0 + tx] = t[tx][ty + 8 * j];
}

// ---------------- softmax rows of CS, bf16 in place ----------------
__global__ void k_softmaxb(hb* __restrict__ P) {
    unsigned* row = (unsigned*)(P + (size_t)blockIdx.x * CS);
    unsigned u0 = row[threadIdx.x * 2], u1 = row[threadIdx.x * 2 + 1];
    float f[4];
    f[0] = __uint_as_float(u0 << 16); f[1] = __uint_as_float(u0 & 0xffff0000u);
    f[2] = __uint_as_float(u1 << 16); f[3] = __uint_as_float(u1 & 0xffff0000u);
    float m = fmaxf(fmaxf(f[0], f[1]), fmaxf(f[2], f[3]));
    m = blockMax256(m);
    float s = 0.f;
#pragma unroll
    for (int i = 0; i < 4; ++i) { f[i] = __expf(f[i] - m); s += f[i]; }
    s = blockSum256(s);
    float inv = 1.f / s;
    unsigned o0 = ((unsigned)f2bu(f[0] * inv)) | (((unsigned)f2bu(f[1] * inv)) << 16);
    unsigned o1 = ((unsigned)f2bu(f[2] * inv)) | (((unsigned)f2bu(f[3] * inv)) << 16);
    row[threadIdx.x * 2] = o0; row[threadIdx.x * 2 + 1] = o1;
}

// ---------------- router: logits GEMM (8 tokens/block) ----------------
__global__ void k_logits(const hb* __restrict__ h2b, const float* __restrict__ rwT,
                         const float* __restrict__ bias, float* __restrict__ logits) {
    __shared__ float hs[8][1032];
    int t0 = blockIdx.x * 8;
    int tid = threadIdx.x;
    const unsigned* src = (const unsigned*)(h2b + (size_t)t0 * CD);
#pragma unroll
    for (int it = 0; it < 16; ++it) {
        int j = tid + it * 256;
        unsigned u = src[j];
        int fidx = j * 2;
        int r = fidx >> 10, c = fidx & 1023;
        hs[r][c] = __uint_as_float(u << 16);
        hs[r][c + 1] = __uint_as_float(u & 0xffff0000u);
    }
    __syncthreads();
    int e = tid >> 3, tl = tid & 7;
    const float4* wrow = (const float4*)(rwT + (size_t)e * CD);
    float acc = 0.f;
#pragma unroll 4
    for (int d4 = 0; d4 < 256; ++d4) {
        float4 w = wrow[d4];
        float4 h = *(const float4*)&hs[tl][d4 * 4];
        acc += w.x * h.x + w.y * h.y + w.z * h.z + w.w * h.w;
    }
    logits[(size_t)(t0 + tl) * CE + e] = acc + bias[e];
}

// ---------------- route: per-thread softmax + top-8 + LDS histogram ----------------
__global__ void k_route(const float* __restrict__ logits, int* __restrict__ topi,
                        float* __restrict__ topw, int* __restrict__ counts) {
    __shared__ int lc[CE];
    int tid = threadIdx.x;
    if (tid < CE) lc[tid] = 0;
    __syncthreads();
    int t = blockIdx.x * 256 + tid;
    float p[CE];
    const float4* row4 = (const float4*)(logits + (size_t)t * CE);
    float mx = -1e30f;
#pragma unroll
    for (int i = 0; i < CE / 4; ++i) {
        float4 v = row4[i];
        p[i * 4] = v.x; p[i * 4 + 1] = v.y; p[i * 4 + 2] = v.z; p[i * 4 + 3] = v.w;
    }
#pragma unroll
    for (int i = 0; i < CE; ++i) mx = fmaxf(mx, p[i]);
    float s = 0.f;
#pragma unroll
    for (int i = 0; i < CE; ++i) { p[i] = __expf(p[i] - mx); s += p[i]; }
    float inv = 1.f / s;
#pragma unroll
    for (int i = 0; i < CE; ++i) p[i] *= inv;

    float vals[CKS]; int ids[CKS];
#pragma unroll
    for (int k = 0; k < CKS; ++k) {
        float bv = -1.f; int bi = 0;
#pragma unroll
        for (int q = 0; q < CE; ++q)
            if (p[q] > bv) { bv = p[q]; bi = q; }
        vals[k] = bv; ids[k] = bi;
#pragma unroll
        for (int q = 0; q < CE; ++q)
            if (q == bi) p[q] = -2.f;
    }
    float ss = 0.f; float ww[CKS];
#pragma unroll
    for (int k = 0; k < CKS; ++k) { ww[k] = __expf(vals[k] - vals[0]); ss += ww[k]; }
    float wiv = 1.f / ss;
#pragma unroll
    for (int k = 0; k < CKS; ++k) {
        topi[t * CKS + k] = ids[k];
        topw[t * CKS + k] = ww[k] * wiv;
        atomicAdd(&lc[ids[k]], 1);
    }
    __syncthreads();
    if (tid < CE) atomicAdd(&counts[tid], lc[tid]);
}

__global__ void k_scan(const int* __restrict__ counts, int* __restrict__ offs) {
    if (threadIdx.x == 0) {
        int a = 0;
        for (int e = 0; e < CE; ++e) { offs[e] = a; a += counts[e]; }
        offs[CE] = a;
    }
}

// ---------------- fill: block-aggregated cursor reservation ----------------
__global__ void k_fill(const int* __restrict__ topi, const float* __restrict__ topw,
                       const int* __restrict__ offs, int* __restrict__ cursor,
                       int* __restrict__ lists, float* __restrict__ wl) {
    __shared__ int lcnt[CE];
    __shared__ int lbase[CE];
    int tid = threadIdx.x;
    if (tid < CE) lcnt[tid] = 0;
    __syncthreads();
    int idx = blockIdx.x * 256 + tid;
    int e = topi[idx];
    int lpos = atomicAdd(&lcnt[e], 1);
    __syncthreads();
    if (tid < CE) lbase[tid] = lcnt[tid] ? atomicAdd(&cursor[tid], lcnt[tid]) : 0;
    __syncthreads();
    int slot = offs[e] + lbase[e] + lpos;
    lists[slot] = idx >> 3;
    wl[slot] = topw[idx];
}

__global__ void k_add(float* __restrict__ x, const float* __restrict__ y, int n4) {
    int i = blockIdx.x * 256 + threadIdx.x;
    if (i < n4) {
        float4 a = ((float4*)x)[i];
        float4 b = ((const float4*)y)[i];
        a.x += b.x; a.y += b.y; a.z += b.z; a.w += b.w;
        ((float4*)x)[i] = a;
    }
}

__global__ void k_pool(const float* __restrict__ nx, float* __restrict__ pooled) {
    int b = blockIdx.y;
    int d = blockIdx.x * 256 + threadIdx.x;
    float s = 0.f;
    for (int t = 0; t < CS; ++t) s += nx[((size_t)(b * CS + t)) * CD + d];
    pooled[b * CD + d] = s * (1.f / CS);
}

__global__ void k_head(const float* __restrict__ pooled, const float* __restrict__ cw,
                       const float* __restrict__ cb, float* __restrict__ out) {
    __shared__ float lg[CB * CNC];
    int i = threadIdx.x;
    if (i < CB * CNC) {
        int b = i / CNC, c = i % CNC;
        float s = cb[c];
        for (int d = 0; d < CD; ++d) s += pooled[b * CD + d] * cw[(size_t)d * CNC + c];
        lg[i] = s;
    }
    __syncthreads();
    if (i < CB) {
        float mx = -1e30f;
        for (int c = 0; c < CNC; ++c) mx = fmaxf(mx, lg[i * CNC + c]);
        float ex[CNC]; float s = 0.f;
        for (int c = 0; c < CNC; ++c) { ex[c] = __expf(lg[i * CNC + c] - mx); s += ex[c]; }
        for (int c = 0; c < CNC; ++c) out[i * CNC + c] = ex[c] / s;
    }
}

} // namespace

extern "C" void kernel_launch(void* const* d_in, const int* in_sizes, int n_in,
                              void* d_out, int out_size, void* d_ws, size_t ws_size,
                              hipStream_t stream) {
    const int*   tokens = (const int*)d_in[0];
    const float* emb    = (const float*)d_in[1];
    const float* n1w    = (const float*)d_in[2];
    const float* n2w    = (const float*)d_in[3];
    const float* Wq     = (const float*)d_in[4];
    const float* Wk     = (const float*)d_in[5];
    const float* Wv     = (const float*)d_in[6];
    const float* Wo     = (const float*)d_in[7];
    const float* rw     = (const float*)d_in[8];
    const float* ebias  = (const float*)d_in[9];
    const float* shw1   = (const float*)d_in[10];
    const float* shw3   = (const float*)d_in[11];
    const float* shw2   = (const float*)d_in[12];
    const float* exw1   = (const float*)d_in[13];
    const float* exw3   = (const float*)d_in[14];
    const float* exw2   = (const float*)d_in[15];
    const float* fnw    = (const float*)d_in[16];
    const float* clsw   = (const float*)d_in[17];
    const float* clsb   = (const float*)d_in[18];
    float* out = (float*)d_out;

    constexpr size_t MB = 1ull << 20;
    char* base = (char*)d_ws;
    float* X   = (float*)(base);             // 16 MB residual
    float* Xh  = (float*)(base + 16 * MB);   // 16 MB X2/X3
    float* AO  = (float*)(base + 32 * MB);   // 16 MB shared+spec accumulator
    float* pooled  = (float*)(base + 48 * MB);
    float* topw    = pooled + 4096;
    float* wl      = topw + CT * CKS;
    float* logitsB = wl + CT * CKS;
    float* rwT     = logitsB + CT * CE;
    int* topi   = (int*)(rwT + CE * CD);
    int* lists  = topi + CT * CKS;
    int* counts = lists + CT * CKS;
    int* cursor = counts + CE;
    int* offs   = cursor + CE;
    char* pool = base + 50 * MB;
    // attention phase
    float* Vc = (float*)(pool);              // 4 MB
    hb* h1b  = (hb*)(pool + 4 * MB);         // 8 MB
    hb* Qbb  = (hb*)(pool + 12 * MB);        // 8 MB
    hb* Kb   = (hb*)(pool + 20 * MB);        // 2 MB
    hb* Vct  = (hb*)(pool + 22 * MB);        // 2 MB
    hb* Pb   = (hb*)(pool + 24 * MB);        // 32 MB
    hb* AOb  = (hb*)(pool + 56 * MB);        // 8 MB
    hb* Wqt  = (hb*)(pool + 64 * MB);        // 2 MB
    hb* Wot  = (hb*)(pool + 66 * MB);        // 2 MB
    hb* Wkt  = (hb*)(pool + 68 * MB);        // 1 MB
    hb* Wvt  = (hb*)(pool + 69 * MB);        // 1 MB
    // moe phase overlays
    hb* h2b   = (hb*)(pool);                 // 8 MB
    hb* HSb   = (hb*)(pool + 8 * MB);        // 4 MB
    hb* g     = (hb*)(pool + 12 * MB);       // 32 MB
    hb* shw1t = (hb*)(pool + 44 * MB);
    hb* shw3t = (hb*)(pool + 45 * MB);
    hb* shw2t = (hb*)(pool + 46 * MB);
    hb* exw1t = (hb*)(pool + 47 * MB);       // 32 MB
    hb* exw3t = (hb*)(pool + 79 * MB);       // 32 MB
    hb* exw2t = (hb*)(pool + 111 * MB);      // 32 MB

    dim3 b256(256);

    // ---- prologue ----
    k_embed<<<CT, b256, 0, stream>>>(tokens, emb, X);
    k_rmsnorm_b<<<CT, b256, 0, stream>>>(X, n1w, h1b);
    k_t32<<<dim3(1, CD / 32), b256, 0, stream>>>(rw, rwT, CD, CE);
    k_cvt_t<<<dim3(CD / 32, CD / 32, 1), b256, 0, stream>>>(Wq, Wqt, CD, CD);
    k_cvt_t<<<dim3(CDKV / 32, CD / 32, 1), b256, 0, stream>>>(Wk, Wkt, CD, CDKV);
    k_cvt_t<<<dim3(CDKV / 32, CD / 32, 1), b256, 0, stream>>>(Wv, Wvt, CD, CDKV);
    k_cvt_t<<<dim3(CD / 32, CD / 32, 1), b256, 0, stream>>>(Wo, Wot, CD, CD);

    // ---- attention (bf16 MFMA) ----
    k_mf<false, false, 0><<<dim3(CD / 128, CT / 128, 1), b256, 0, stream>>>(
        h1b, CD, 0, 0, Wqt, nullptr, CD, 0, 0, nullptr, nullptr, Qbb, CD, 0, 0,
        nullptr, nullptr, nullptr, CT, CD, CD, 1, 1.f);
    k_mf<false, false, 0><<<dim3(CDKV / 128, CT / 128, 1), b256, 0, stream>>>(
        h1b, CD, 0, 0, Wkt, nullptr, CD, 0, 0, nullptr, nullptr, Kb, CDKV, 0, 0,
        nullptr, nullptr, nullptr, CT, CDKV, CD, 1, 1.f);
    k_mf<false, false, 2><<<dim3(CDKV / 128, CT / 128, 1), b256, 0, stream>>>(
        h1b, CD, 0, 0, Wvt, nullptr, CD, 0, 0, nullptr, Vc, nullptr, CDKV, 0, 0,
        nullptr, nullptr, nullptr, CT, CDKV, CD, 1, 1.f);
    k_cvt_t<<<dim3(CDKV / 32, CS / 32, CB), b256, 0, stream>>>(Vc, Vct, CS, CDKV);
    k_mf<false, false, 0><<<dim3(CS / 128, CS / 128, CB * CH), b256, 0, stream>>>(
        Qbb, CD, (long)CS * CD, CDK,
        Kb, nullptr, CDKV, (long)CS * CDKV, 0,
        nullptr, nullptr, Pb, CS, (long)CH * CS * CS, (long)CS * CS,
        nullptr, nullptr, nullptr, CS, CS, CDK, CH, 1.f / 16.f);
    k_softmaxb<<<CB * CH * CS, b256, 0, stream>>>(Pb);
    k_mf<false, false, 0><<<dim3(CDK / 128, CS / 128, CB * CH), b256, 0, stream>>>(
        Pb, CS, (long)CH * CS * CS, (long)CS * CS,
        Vct, nullptr, CS, (long)CDKV * CS, 0,
        nullptr, nullptr, AOb, CD, (long)CS * CD, CDK,
        nullptr, nullptr, nullptr, CS, CDK, CS, CH, 1.f);
    k_mf<false, false, 4><<<dim3(CD / 128, CT / 128, 1), b256, 0, stream>>>(
        AOb, CD, 0, 0, Wot, nullptr, CD, 0, 0, X, Xh, nullptr, CD, 0, 0,
        nullptr, nullptr, nullptr, CT, CD, CD, 1, 1.f);

    // ---- MoE routing ----
    k_rmsnorm_b<<<CT, b256, 0, stream>>>(Xh, n2w, h2b);
    hipMemsetAsync(counts, 0, (size_t)(CE + CE + CE + 1) * sizeof(int), stream);
    k_logits<<<CT / 8, b256, 0, stream>>>(h2b, rwT, ebias, logitsB);
    k_route<<<CT / 256, b256, 0, stream>>>(logitsB, topi, topw, counts);
    k_scan<<<1, 64, 0, stream>>>(counts, offs);
    k_fill<<<CT * CKS / 256, b256, 0, stream>>>(topi, topw, offs, cursor, lists, wl);

    // MoE weight converts
    k_cvt_t<<<dim3(CF / 32, CD / 32, 1), b256, 0, stream>>>(shw1, shw1t, CD, CF);
    k_cvt_t<<<dim3(CF / 32, CD / 32, 1), b256, 0, stream>>>(shw3, shw3t, CD, CF);
    k_cvt_t<<<dim3(CD / 32, CF / 32, 1), b256, 0, stream>>>(shw2, shw2t, CF, CD);
    k_cvt_t<<<dim3(CF / 32, CD / 32, CE), b256, 0, stream>>>(exw1, exw1t, CD, CF);
    k_cvt_t<<<dim3(CF / 32, CD / 32, CE), b256, 0, stream>>>(exw3, exw3t, CD, CF);
    k_cvt_t<<<dim3(CD / 32, CF / 32, CE), b256, 0, stream>>>(exw2, exw2t, CF, CD);

    // shared expert
    k_mf<false, true, 0><<<dim3(CF / 128, CT / 128, 1), b256, 0, stream>>>(
        h2b, CD, 0, 0, shw1t, shw3t, CD, 0, 0, nullptr, nullptr, HSb, CF, 0, 0,
        nullptr, nullptr, nullptr, CT, CF, CD, 1, 1.f);
    k_mf<false, false, 2><<<dim3(CD / 128, CT / 128, 1), b256, 0, stream>>>(
        HSb, CF, 0, 0, shw2t, nullptr, CF, 0, 0, nullptr, AO, nullptr, CD, 0, 0,
        nullptr, nullptr, nullptr, CT, CD, CF, 1, 1.f);
    // routed experts
    k_mf<true, true, 0><<<dim3(CF / 128, CT / 128, CE), b256, 0, stream>>>(
        h2b, CD, 0, 0, exw1t, exw3t, CD, (long)CD * CF, 0, nullptr, nullptr, g, CF, 0, 0,
        lists, nullptr, offs, 0, CF, CD, 1, 1.f);
    k_mf<false, false, 3><<<dim3(CD / 128, CT / 128, CE), b256, 0, stream>>>(
        g, CF, 0, 0, exw2t, nullptr, CF, (long)CF * CD, 0, nullptr, AO, nullptr, CD, 0, 0,
        lists, wl, offs, 0, CD, CF, 1, 1.f);

    // X3 = X2 + (shared + spec)
    k_add<<<(CT * CD / 4 + 255) / 256, b256, 0, stream>>>(Xh, AO, CT * CD / 4);

    // head
    k_rmsnorm<<<CT, b256, 0, stream>>>(Xh, fnw, X);
    k_pool<<<dim3(CD / 256, CB), b256, 0, stream>>>(X, pooled);
    k_head<<<1, b256, 0, stream>>>(pooled, clsw, clsb, out);
}

// Round 5
// 657.131 us; speedup vs baseline: 4.7878x; 1.1072x over previous
//
#include <hip/hip_runtime.h>
#include <hip/hip_bf16.h>
#include <cmath>

namespace {

constexpr int CB = 4, CS = 1024, CD = 1024, CH = 4, CE = 32, CF = 512;
constexpr int CKS = 8, CNC = 10, CDK = 256, CDKV = 256;
constexpr int CT = CB * CS;
constexpr float CEPS = 1e-6f;

using hb = __hip_bfloat16;
typedef __bf16 bf16x8 __attribute__((ext_vector_type(8)));
typedef float f32x4 __attribute__((ext_vector_type(4)));

__device__ __forceinline__ void gload16(const void* g, void* l) {
    __builtin_amdgcn_global_load_lds((const __attribute__((address_space(1))) void*)g,
                                     (__attribute__((address_space(3))) void*)l, 16, 0, 0);
}

__device__ __forceinline__ unsigned short f2bu(float x) {
    hb h = __float2bfloat16(x);
    unsigned short u;
    __builtin_memcpy(&u, &h, 2);
    return u;
}

// ---------------- reductions ----------------
__device__ __forceinline__ float blockSum256(float v) {
    __shared__ float red[4];
    int lane = threadIdx.x & 63, wid = threadIdx.x >> 6;
#pragma unroll
    for (int o = 32; o > 0; o >>= 1) v += __shfl_down(v, o, 64);
    if (lane == 0) red[wid] = v;
    __syncthreads();
    float s = red[0] + red[1] + red[2] + red[3];
    __syncthreads();
    return s;
}
__device__ __forceinline__ float blockMax256(float v) {
    __shared__ float red[4];
    int lane = threadIdx.x & 63, wid = threadIdx.x >> 6;
#pragma unroll
    for (int o = 32; o > 0; o >>= 1) v = fmaxf(v, __shfl_down(v, o, 64));
    if (lane == 0) red[wid] = v;
    __syncthreads();
    float s = fmaxf(fmaxf(red[0], red[1]), fmaxf(red[2], red[3]));
    __syncthreads();
    return s;
}

// ---------------- embedding gather ----------------
__global__ void k_embed(const int* __restrict__ tokens, const float* __restrict__ emb,
                        float* __restrict__ X) {
    int t = blockIdx.x;
    int tok = tokens[t];
    const float4* src = (const float4*)(emb + (size_t)tok * CD);
    float4* dst = (float4*)(X + (size_t)t * CD);
    dst[threadIdx.x] = src[threadIdx.x];
}

// ---------------- rmsnorm (bf16 out) ----------------
__global__ void k_rmsnorm_b(const float* __restrict__ in, const float* __restrict__ w,
                            hb* __restrict__ out) {
    int t = blockIdx.x;
    const float* row = in + (size_t)t * CD;
    float ss = 0.f;
    for (int i = threadIdx.x; i < CD; i += 256) { float v = row[i]; ss += v * v; }
    float tot = blockSum256(ss);
    float sc = rsqrtf(tot / CD + CEPS);
    for (int i = threadIdx.x; i < CD; i += 256)
        out[(size_t)t * CD + i] = __float2bfloat16(row[i] * sc * w[i]);
}

// ---------------- bf16 MFMA GEMM: 128x128 tile, BK=32, 4 waves ----------------
// EPI: 0 bf16 store (silu(acc1)*acc3 if DUAL, else alpha*acc)
//      2 f32 store   4 f32 store alpha*acc + Cin
template<bool GATHER, bool DUAL, int EPI>
__global__ __launch_bounds__(256, 2)
void k_mf(const hb* __restrict__ A, int lda, long sA1, long sA2,
          const hb* __restrict__ B1g, const hb* __restrict__ B3g, int ldb, long sB1, long sB2,
          const float* __restrict__ Cin, float* __restrict__ Cf, hb* __restrict__ Cb,
          int ldc, long sC1, long sC2,
          const int* __restrict__ lists,
          const int* __restrict__ offs,
          int M, int N, int K, int Zi, float alpha) {
    int z = blockIdx.z, z1 = z / Zi, z2 = z % Zi;
    A += (size_t)z1 * sA1 + (size_t)z2 * sA2;
    const hb* B1 = B1g + (size_t)z1 * sB1 + (size_t)z2 * sB2;
    const hb* B3 = DUAL ? (B3g + (size_t)z1 * sB1 + (size_t)z2 * sB2) : nullptr;
    long coff = (size_t)z1 * sC1 + (size_t)z2 * sC2;
    if (Cf) Cf += coff;
    if (Cb) Cb += coff;
    if (Cin) Cin += coff;

    int base = 0, cnt = M;
    if (offs) { base = offs[z]; cnt = offs[z + 1] - base; }
    int row0 = blockIdx.y * 128;
    if (row0 >= cnt) return;
    int col0 = blockIdx.x * 128;

    __shared__ hb As[128 * 32];
    __shared__ hb Bs1[128 * 32];
    __shared__ hb Bs3[DUAL ? 128 * 32 : 8];

    int tid = threadIdx.x;
    int kq = (tid & 3) * 8;
    int r0i = tid >> 2, r1i = 64 + (tid >> 2);

    auto arowOf = [&](int r) -> size_t {
        int gr = row0 + r; gr = gr < cnt ? gr : cnt - 1;
        if (GATHER) return (size_t)lists[base + gr];
        return (size_t)(base + gr);
    };
    const hb* aS0 = A + arowOf(r0i) * lda + kq;
    const hb* aS1 = A + arowOf(r1i) * lda + kq;
    const hb* b1S0 = B1 + (size_t)(col0 + r0i) * ldb + kq;
    const hb* b1S1 = B1 + (size_t)(col0 + r1i) * ldb + kq;
    const hb* b3S0 = DUAL ? (B3 + (size_t)(col0 + r0i) * ldb + kq) : nullptr;
    const hb* b3S1 = DUAL ? (B3 + (size_t)(col0 + r1i) * ldb + kq) : nullptr;
    hb* aD0 = As + tid * 8;   hb* aD1 = As + (256 + tid) * 8;
    hb* bD0 = Bs1 + tid * 8;  hb* bD1 = Bs1 + (256 + tid) * 8;
    hb* cD0 = Bs3 + tid * 8;  hb* cD1 = Bs3 + (256 + tid) * 8;

    int lane = tid & 63, wid = tid >> 6;
    int wr = wid >> 1, wc = wid & 1;
    int lrow = lane & 15, lk = (lane >> 4) * 8;

    f32x4 acc1[4][4], acc3[4][4];
#pragma unroll
    for (int m = 0; m < 4; ++m)
#pragma unroll
        for (int n = 0; n < 4; ++n) {
            acc1[m][n] = (f32x4){0.f, 0.f, 0.f, 0.f};
            acc3[m][n] = (f32x4){0.f, 0.f, 0.f, 0.f};
        }

    for (int k0 = 0; k0 < K; k0 += 32) {
        gload16(aS0 + k0, aD0);
        gload16(aS1 + k0, aD1);
        gload16(b1S0 + k0, bD0);
        gload16(b1S1 + k0, bD1);
        if constexpr (DUAL) {
            gload16(b3S0 + k0, cD0);
            gload16(b3S1 + k0, cD1);
        }
        __syncthreads();
        bf16x8 af[4], bf1[4], bf3[4];
#pragma unroll
        for (int m = 0; m < 4; ++m)
            af[m] = *(const bf16x8*)(As + (size_t)(wr * 64 + m * 16 + lrow) * 32 + lk);
#pragma unroll
        for (int n = 0; n < 4; ++n)
            bf1[n] = *(const bf16x8*)(Bs1 + (size_t)(wc * 64 + n * 16 + lrow) * 32 + lk);
        if constexpr (DUAL) {
#pragma unroll
            for (int n = 0; n < 4; ++n)
                bf3[n] = *(const bf16x8*)(Bs3 + (size_t)(wc * 64 + n * 16 + lrow) * 32 + lk);
        }
#pragma unroll
        for (int m = 0; m < 4; ++m)
#pragma unroll
            for (int n = 0; n < 4; ++n) {
                acc1[m][n] = __builtin_amdgcn_mfma_f32_16x16x32_bf16(af[m], bf1[n], acc1[m][n], 0, 0, 0);
                if constexpr (DUAL)
                    acc3[m][n] = __builtin_amdgcn_mfma_f32_16x16x32_bf16(af[m], bf3[n], acc3[m][n], 0, 0, 0);
            }
        __syncthreads();
    }

    int lr4 = (lane >> 4) * 4;
#pragma unroll
    for (int m = 0; m < 4; ++m) {
#pragma unroll
        for (int q = 0; q < 4; ++q) {
            int r = row0 + wr * 64 + m * 16 + lr4 + q;
            if (r >= cnt) continue;
            size_t orow = (size_t)(base + r) * ldc;
#pragma unroll
            for (int n = 0; n < 4; ++n) {
                int cc = col0 + wc * 64 + n * 16 + (lane & 15);
                float v = acc1[m][n][q];
                if constexpr (EPI == 0) {
                    if constexpr (DUAL) {
                        float y = acc3[m][n][q];
                        v = v / (1.f + __expf(-v)) * y;
                    } else {
                        v *= alpha;
                    }
                    Cb[orow + cc] = __float2bfloat16(v);
                } else if constexpr (EPI == 2) {
                    Cf[orow + cc] = alpha * v;
                } else if constexpr (EPI == 4) {
                    Cf[orow + cc] = alpha * v + Cin[orow + cc];
                }
            }
        }
    }
}

// ---------------- conversions ----------------
__global__ void k_cvt_t(const float* __restrict__ in, hb* __restrict__ out, int R, int C) {
    size_t zoff = (size_t)blockIdx.z * R * C;
    in += zoff; out += zoff;
    __shared__ float t[32][33];
    int c0 = blockIdx.x * 32, r0 = blockIdx.y * 32;
    int tx = threadIdx.x & 31, ty = threadIdx.x >> 5;
#pragma unroll
    for (int j = 0; j < 4; ++j)
        t[ty + 8 * j][tx] = in[(size_t)(r0 + ty + 8 * j) * C + c0 + tx];
    __syncthreads();
#pragma unroll
    for (int j = 0; j < 4; ++j)
        out[(size_t)(c0 + ty + 8 * j) * R + r0 + tx] = __float2bfloat16(t[tx][ty + 8 * j]);
}
__global__ void k_t32(const float* __restrict__ in, float* __restrict__ out, int R, int C) {
    __shared__ float t[32][33];
    int c0 = blockIdx.x * 32, r0 = blockIdx.y * 32;
    int tx = threadIdx.x & 31, ty = threadIdx.x >> 5;
#pragma unroll
    for (int j = 0; j < 4; ++j)
        t[ty + 8 * j][tx] = in[(size_t)(r0 + ty + 8 * j) * C + c0 + tx];
    __syncthreads();
#pragma unroll
    for (int j = 0; j < 4; ++j)
        out[(size_t)(c0 + ty + 8 * j) * R + r0 + tx] = t[tx][ty + 8 * j];
}

// ---------------- softmax rows of CS, bf16 in place ----------------
__global__ void k_softmaxb(hb* __restrict__ P) {
    unsigned* row = (unsigned*)(P + (size_t)blockIdx.x * CS);
    unsigned u0 = row[threadIdx.x * 2], u1 = row[threadIdx.x * 2 + 1];
    float f[4];
    f[0] = __uint_as_float(u0 << 16); f[1] = __uint_as_float(u0 & 0xffff0000u);
    f[2] = __uint_as_float(u1 << 16); f[3] = __uint_as_float(u1 & 0xffff0000u);
    float m = fmaxf(fmaxf(f[0], f[1]), fmaxf(f[2], f[3]));
    m = blockMax256(m);
    float s = 0.f;
#pragma unroll
    for (int i = 0; i < 4; ++i) { f[i] = __expf(f[i] - m); s += f[i]; }
    s = blockSum256(s);
    float inv = 1.f / s;
    unsigned o0 = ((unsigned)f2bu(f[0] * inv)) | (((unsigned)f2bu(f[1] * inv)) << 16);
    unsigned o1 = ((unsigned)f2bu(f[2] * inv)) | (((unsigned)f2bu(f[3] * inv)) << 16);
    row[threadIdx.x * 2] = o0; row[threadIdx.x * 2 + 1] = o1;
}

// ---------------- router: logits GEMM (8 tokens/block) ----------------
__global__ void k_logits(const hb* __restrict__ h2b, const float* __restrict__ rwT,
                         const float* __restrict__ bias, float* __restrict__ logits) {
    __shared__ float hs[8][1032];
    int t0 = blockIdx.x * 8;
    int tid = threadIdx.x;
    const unsigned* src = (const unsigned*)(h2b + (size_t)t0 * CD);
#pragma unroll
    for (int it = 0; it < 16; ++it) {
        int j = tid + it * 256;
        unsigned u = src[j];
        int fidx = j * 2;
        int r = fidx >> 10, c = fidx & 1023;
        hs[r][c] = __uint_as_float(u << 16);
        hs[r][c + 1] = __uint_as_float(u & 0xffff0000u);
    }
    __syncthreads();
    int e = tid >> 3, tl = tid & 7;
    const float4* wrow = (const float4*)(rwT + (size_t)e * CD);
    float acc = 0.f;
#pragma unroll 4
    for (int d4 = 0; d4 < 256; ++d4) {
        float4 w = wrow[d4];
        float4 h = *(const float4*)&hs[tl][d4 * 4];
        acc += w.x * h.x + w.y * h.y + w.z * h.z + w.w * h.w;
    }
    logits[(size_t)(t0 + tl) * CE + e] = acc + bias[e];
}

// ---------------- route: per-thread softmax + top-8 + LDS histogram ----------------
__global__ void k_route(const float* __restrict__ logits, int* __restrict__ topi,
                        float* __restrict__ topw, int* __restrict__ counts) {
    __shared__ int lc[CE];
    int tid = threadIdx.x;
    if (tid < CE) lc[tid] = 0;
    __syncthreads();
    int t = blockIdx.x * 256 + tid;
    float p[CE];
    const float4* row4 = (const float4*)(logits + (size_t)t * CE);
    float mx = -1e30f;
#pragma unroll
    for (int i = 0; i < CE / 4; ++i) {
        float4 v = row4[i];
        p[i * 4] = v.x; p[i * 4 + 1] = v.y; p[i * 4 + 2] = v.z; p[i * 4 + 3] = v.w;
    }
#pragma unroll
    for (int i = 0; i < CE; ++i) mx = fmaxf(mx, p[i]);
    float s = 0.f;
#pragma unroll
    for (int i = 0; i < CE; ++i) { p[i] = __expf(p[i] - mx); s += p[i]; }
    float inv = 1.f / s;
#pragma unroll
    for (int i = 0; i < CE; ++i) p[i] *= inv;

    float vals[CKS]; int ids[CKS];
#pragma unroll
    for (int k = 0; k < CKS; ++k) {
        float bv = -1.f; int bi = 0;
#pragma unroll
        for (int q = 0; q < CE; ++q)
            if (p[q] > bv) { bv = p[q]; bi = q; }
        vals[k] = bv; ids[k] = bi;
#pragma unroll
        for (int q = 0; q < CE; ++q)
            if (q == bi) p[q] = -2.f;
    }
    float ss = 0.f; float ww[CKS];
#pragma unroll
    for (int k = 0; k < CKS; ++k) { ww[k] = __expf(vals[k] - vals[0]); ss += ww[k]; }
    float wiv = 1.f / ss;
#pragma unroll
    for (int k = 0; k < CKS; ++k) {
        topi[t * CKS + k] = ids[k];
        topw[t * CKS + k] = ww[k] * wiv;
        atomicAdd(&lc[ids[k]], 1);
    }
    __syncthreads();
    if (tid < CE) atomicAdd(&counts[tid], lc[tid]);
}

__global__ void k_scan(const int* __restrict__ counts, int* __restrict__ offs) {
    if (threadIdx.x == 0) {
        int a = 0;
        for (int e = 0; e < CE; ++e) { offs[e] = a; a += counts[e]; }
        offs[CE] = a;
    }
}

// ---------------- fill: block-aggregated cursor reservation + inverse map ----------------
__global__ void k_fill(const int* __restrict__ topi,
                       const int* __restrict__ offs, int* __restrict__ cursor,
                       int* __restrict__ lists, int* __restrict__ slot_of) {
    __shared__ int lcnt[CE];
    __shared__ int lbase[CE];
    int tid = threadIdx.x;
    if (tid < CE) lcnt[tid] = 0;
    __syncthreads();
    int idx = blockIdx.x * 256 + tid;
    int e = topi[idx];
    int lpos = atomicAdd(&lcnt[e], 1);
    __syncthreads();
    if (tid < CE) lbase[tid] = lcnt[tid] ? atomicAdd(&cursor[tid], lcnt[tid]) : 0;
    __syncthreads();
    int slot = offs[e] + lbase[e] + lpos;
    lists[slot] = idx >> 3;
    slot_of[idx] = slot;
}

// ---------------- fused combine + residual + final rmsnorm ----------------
__global__ void k_combine(const float* __restrict__ X2, const hb* __restrict__ HSd,
                          const hb* __restrict__ spec_b, const float* __restrict__ topw,
                          const int* __restrict__ slot_of, const float* __restrict__ fnw,
                          float* __restrict__ normX) {
    int t = blockIdx.x, tid = threadIdx.x;
    int d0 = tid * 4;
    __shared__ float wsm[CKS];
    __shared__ int ssm[CKS];
    if (tid < CKS) { wsm[tid] = topw[t * CKS + tid]; ssm[tid] = slot_of[t * CKS + tid]; }
    const float4 x = *(const float4*)(X2 + (size_t)t * CD + d0);
    uint2 hu = *(const uint2*)(HSd + (size_t)t * CD + d0);
    float a0 = x.x + __uint_as_float(hu.x << 16);
    float a1 = x.y + __uint_as_float(hu.x & 0xffff0000u);
    float a2 = x.z + __uint_as_float(hu.y << 16);
    float a3 = x.w + __uint_as_float(hu.y & 0xffff0000u);
    __syncthreads();
#pragma unroll
    for (int k = 0; k < CKS; ++k) {
        float w = wsm[k];
        uint2 u = *(const uint2*)(spec_b + (size_t)ssm[k] * CD + d0);
        a0 += w * __uint_as_float(u.x << 16);
        a1 += w * __uint_as_float(u.x & 0xffff0000u);
        a2 += w * __uint_as_float(u.y << 16);
        a3 += w * __uint_as_float(u.y & 0xffff0000u);
    }
    float ss = a0 * a0 + a1 * a1 + a2 * a2 + a3 * a3;
    float tot = blockSum256(ss);
    float sc = rsqrtf(tot / CD + CEPS);
    float4 o;
    o.x = a0 * sc * fnw[d0];     o.y = a1 * sc * fnw[d0 + 1];
    o.z = a2 * sc * fnw[d0 + 2]; o.w = a3 * sc * fnw[d0 + 3];
    *(float4*)(normX + (size_t)t * CD + d0) = o;
}

__global__ void k_pool(const float* __restrict__ nx, float* __restrict__ pooled) {
    int b = blockIdx.y;
    int d = blockIdx.x * 256 + threadIdx.x;
    float s = 0.f;
    for (int t = 0; t < CS; ++t) s += nx[((size_t)(b * CS + t)) * CD + d];
    pooled[b * CD + d] = s * (1.f / CS);
}

__global__ void k_head(const float* __restrict__ pooled, const float* __restrict__ cw,
                       const float* __restrict__ cb, float* __restrict__ out) {
    __shared__ float lg[CB * CNC];
    int i = threadIdx.x;
    if (i < CB * CNC) {
        int b = i / CNC, c = i % CNC;
        float s = cb[c];
        for (int d = 0; d < CD; ++d) s += pooled[b * CD + d] * cw[(size_t)d * CNC + c];
        lg[i] = s;
    }
    __syncthreads();
    if (i < CB) {
        float mx = -1e30f;
        for (int c = 0; c < CNC; ++c) mx = fmaxf(mx, lg[i * CNC + c]);
        float ex[CNC]; float s = 0.f;
        for (int c = 0; c < CNC; ++c) { ex[c] = __expf(lg[i * CNC + c] - mx); s += ex[c]; }
        for (int c = 0; c < CNC; ++c) out[i * CNC + c] = ex[c] / s;
    }
}

} // namespace

extern "C" void kernel_launch(void* const* d_in, const int* in_sizes, int n_in,
                              void* d_out, int out_size, void* d_ws, size_t ws_size,
                              hipStream_t stream) {
    const int*   tokens = (const int*)d_in[0];
    const float* emb    = (const float*)d_in[1];
    const float* n1w    = (const float*)d_in[2];
    const float* n2w    = (const float*)d_in[3];
    const float* Wq     = (const float*)d_in[4];
    const float* Wk     = (const float*)d_in[5];
    const float* Wv     = (const float*)d_in[6];
    const float* Wo     = (const float*)d_in[7];
    const float* rw     = (const float*)d_in[8];
    const float* ebias  = (const float*)d_in[9];
    const float* shw1   = (const float*)d_in[10];
    const float* shw3   = (const float*)d_in[11];
    const float* shw2   = (const float*)d_in[12];
    const float* exw1   = (const float*)d_in[13];
    const float* exw3   = (const float*)d_in[14];
    const float* exw2   = (const float*)d_in[15];
    const float* fnw    = (const float*)d_in[16];
    const float* clsw   = (const float*)d_in[17];
    const float* clsb   = (const float*)d_in[18];
    float* out = (float*)d_out;

    constexpr size_t MB = 1ull << 20;
    char* base = (char*)d_ws;
    float* X   = (float*)(base);             // 16 MB residual / normX
    float* Xh  = (float*)(base + 16 * MB);   // 16 MB X2
    hb*  HSd   = (hb*)(base + 32 * MB);      // 8 MB shared-expert down output (bf16)
    float* pooled  = (float*)(base + 48 * MB);
    float* topw    = pooled + 4096;
    float* logitsB = topw + CT * CKS;
    float* rwT     = logitsB + CT * CE;
    int* topi    = (int*)(rwT + CE * CD);
    int* lists   = topi + CT * CKS;
    int* slot_of = lists + CT * CKS;
    int* counts  = slot_of + CT * CKS;
    int* cursor  = counts + CE;
    int* offs    = cursor + CE;
    char* pool = base + 50 * MB;
    // attention phase
    float* Vc = (float*)(pool);              // 4 MB
    hb* h1b  = (hb*)(pool + 4 * MB);         // 8 MB
    hb* Qbb  = (hb*)(pool + 12 * MB);        // 8 MB
    hb* Kb   = (hb*)(pool + 20 * MB);        // 2 MB
    hb* Vct  = (hb*)(pool + 22 * MB);        // 2 MB
    hb* Pb   = (hb*)(pool + 24 * MB);        // 32 MB
    hb* AOb  = (hb*)(pool + 56 * MB);        // 8 MB
    hb* Wqt  = (hb*)(pool + 64 * MB);        // 2 MB
    hb* Wot  = (hb*)(pool + 66 * MB);        // 2 MB
    hb* Wkt  = (hb*)(pool + 68 * MB);        // 1 MB
    hb* Wvt  = (hb*)(pool + 69 * MB);        // 1 MB
    // moe phase overlays
    hb* h2b   = (hb*)(pool);                 // 8 MB
    hb* HSb   = (hb*)(pool + 8 * MB);        // 4 MB
    hb* g     = (hb*)(pool + 12 * MB);       // 32 MB
    hb* shw1t = (hb*)(pool + 44 * MB);
    hb* shw3t = (hb*)(pool + 45 * MB);
    hb* shw2t = (hb*)(pool + 46 * MB);
    hb* exw1t = (hb*)(pool + 47 * MB);       // 32 MB
    hb* exw3t = (hb*)(pool + 79 * MB);       // 32 MB
    hb* exw2t = (hb*)(pool + 111 * MB);      // 32 MB (ends 193 MB)
    hb* spec_b = exw1t;                      // 64 MB, overlays exw1t+exw3t (dead at down-proj)

    dim3 b256(256);

    // ---- prologue ----
    k_embed<<<CT, b256, 0, stream>>>(tokens, emb, X);
    k_rmsnorm_b<<<CT, b256, 0, stream>>>(X, n1w, h1b);
    k_t32<<<dim3(1, CD / 32), b256, 0, stream>>>(rw, rwT, CD, CE);
    k_cvt_t<<<dim3(CD / 32, CD / 32, 1), b256, 0, stream>>>(Wq, Wqt, CD, CD);
    k_cvt_t<<<dim3(CDKV / 32, CD / 32, 1), b256, 0, stream>>>(Wk, Wkt, CD, CDKV);
    k_cvt_t<<<dim3(CDKV / 32, CD / 32, 1), b256, 0, stream>>>(Wv, Wvt, CD, CDKV);
    k_cvt_t<<<dim3(CD / 32, CD / 32, 1), b256, 0, stream>>>(Wo, Wot, CD, CD);

    // ---- attention (bf16 MFMA) ----
    k_mf<false, false, 0><<<dim3(CD / 128, CT / 128, 1), b256, 0, stream>>>(
        h1b, CD, 0, 0, Wqt, nullptr, CD, 0, 0, nullptr, nullptr, Qbb, CD, 0, 0,
        nullptr, nullptr, CT, CD, CD, 1, 1.f);
    k_mf<false, false, 0><<<dim3(CDKV / 128, CT / 128, 1), b256, 0, stream>>>(
        h1b, CD, 0, 0, Wkt, nullptr, CD, 0, 0, nullptr, nullptr, Kb, CDKV, 0, 0,
        nullptr, nullptr, CT, CDKV, CD, 1, 1.f);
    k_mf<false, false, 2><<<dim3(CDKV / 128, CT / 128, 1), b256, 0, stream>>>(
        h1b, CD, 0, 0, Wvt, nullptr, CD, 0, 0, nullptr, Vc, nullptr, CDKV, 0, 0,
        nullptr, nullptr, CT, CDKV, CD, 1, 1.f);
    k_cvt_t<<<dim3(CDKV / 32, CS / 32, CB), b256, 0, stream>>>(Vc, Vct, CS, CDKV);
    k_mf<false, false, 0><<<dim3(CS / 128, CS / 128, CB * CH), b256, 0, stream>>>(
        Qbb, CD, (long)CS * CD, CDK,
        Kb, nullptr, CDKV, (long)CS * CDKV, 0,
        nullptr, nullptr, Pb, CS, (long)CH * CS * CS, (long)CS * CS,
        nullptr, nullptr, CS, CS, CDK, CH, 1.f / 16.f);
    k_softmaxb<<<CB * CH * CS, b256, 0, stream>>>(Pb);
    k_mf<false, false, 0><<<dim3(CDK / 128, CS / 128, CB * CH), b256, 0, stream>>>(
        Pb, CS, (long)CH * CS * CS, (long)CS * CS,
        Vct, nullptr, CS, (long)CDKV * CS, 0,
        nullptr, nullptr, AOb, CD, (long)CS * CD, CDK,
        nullptr, nullptr, CS, CDK, CS, CH, 1.f);
    k_mf<false, false, 4><<<dim3(CD / 128, CT / 128, 1), b256, 0, stream>>>(
        AOb, CD, 0, 0, Wot, nullptr, CD, 0, 0, X, Xh, nullptr, CD, 0, 0,
        nullptr, nullptr, CT, CD, CD, 1, 1.f);

    // ---- MoE routing ----
    k_rmsnorm_b<<<CT, b256, 0, stream>>>(Xh, n2w, h2b);
    hipMemsetAsync(counts, 0, (size_t)(CE + CE + CE + 1) * sizeof(int), stream);
    k_logits<<<CT / 8, b256, 0, stream>>>(h2b, rwT, ebias, logitsB);
    k_route<<<CT / 256, b256, 0, stream>>>(logitsB, topi, topw, counts);
    k_scan<<<1, 64, 0, stream>>>(counts, offs);
    k_fill<<<CT * CKS / 256, b256, 0, stream>>>(topi, offs, cursor, lists, slot_of);

    // MoE weight converts
    k_cvt_t<<<dim3(CF / 32, CD / 32, 1), b256, 0, stream>>>(shw1, shw1t, CD, CF);
    k_cvt_t<<<dim3(CF / 32, CD / 32, 1), b256, 0, stream>>>(shw3, shw3t, CD, CF);
    k_cvt_t<<<dim3(CD / 32, CF / 32, 1), b256, 0, stream>>>(shw2, shw2t, CF, CD);
    k_cvt_t<<<dim3(CF / 32, CD / 32, CE), b256, 0, stream>>>(exw1, exw1t, CD, CF);
    k_cvt_t<<<dim3(CF / 32, CD / 32, CE), b256, 0, stream>>>(exw3, exw3t, CD, CF);
    k_cvt_t<<<dim3(CD / 32, CF / 32, CE), b256, 0, stream>>>(exw2, exw2t, CF, CD);

    // shared expert: HSb = silu(h2@w1)*(h2@w3); HSd = (HSb @ w2) bf16
    k_mf<false, true, 0><<<dim3(CF / 128, CT / 128, 1), b256, 0, stream>>>(
        h2b, CD, 0, 0, shw1t, shw3t, CD, 0, 0, nullptr, nullptr, HSb, CF, 0, 0,
        nullptr, nullptr, CT, CF, CD, 1, 1.f);
    // routed experts: g[slot] = silu/mul up-proj (gathered A rows)
    k_mf<true, true, 0><<<dim3(CF / 128, CT / 128, CE), b256, 0, stream>>>(
        h2b, CD, 0, 0, exw1t, exw3t, CD, (long)CD * CF, 0, nullptr, nullptr, g, CF, 0, 0,
        lists, offs, 0, CF, CD, 1, 1.f);
    // shared down AFTER routed up-proj (spec_b overlays exw1t/exw3t which must stay live until here? no:
    // spec_b writes happen in the NEXT kernel; order here only requires exw1t/exw3t dead before down-proj)
    k_mf<false, false, 0><<<dim3(CD / 128, CT / 128, 1), b256, 0, stream>>>(
        HSb, CF, 0, 0, shw2t, nullptr, CF, 0, 0, nullptr, nullptr, HSd, CD, 0, 0,
        nullptr, nullptr, CT, CD, CF, 1, 1.f);
    // routed down: spec_b[slot] = g[slot] @ w2[e]  (plain bf16 rows, no atomics)
    k_mf<false, false, 0><<<dim3(CD / 128, CT / 128, CE), b256, 0, stream>>>(
        g, CF, 0, 0, exw2t, nullptr, CF, (long)CF * CD, 0, nullptr, nullptr, spec_b, CD, 0, 0,
        nullptr, offs, 0, CD, CF, 1, 1.f);

    // fused: X3 = X2 + HSd + sum_k topw*spec_b ; final rmsnorm -> X (normX)
    k_combine<<<CT, b256, 0, stream>>>(Xh, HSd, spec_b, topw, slot_of, fnw, X);

    // head
    k_pool<<<dim3(CD / 256, CB), b256, 0, stream>>>(X, pooled);
    k_head<<<1, b256, 0, stream>>>(pooled, clsw, clsb, out);
}

// Round 6
// 648.406 us; speedup vs baseline: 4.8522x; 1.0135x over previous
//
#include <hip/hip_runtime.h>
#include <hip/hip_bf16.h>
#include <cmath>

namespace {

constexpr int CB = 4, CS = 1024, CD = 1024, CH = 4, CE = 32, CF = 512;
constexpr int CKS = 8, CNC = 10, CDK = 256, CDKV = 256;
constexpr int CT = CB * CS;
constexpr float CEPS = 1e-6f;

using hb = __hip_bfloat16;
typedef __bf16 bf16x8 __attribute__((ext_vector_type(8)));
typedef float f32x4 __attribute__((ext_vector_type(4)));

__device__ __forceinline__ void gload16(const void* g, void* l) {
    __builtin_amdgcn_global_load_lds((const __attribute__((address_space(1))) void*)g,
                                     (__attribute__((address_space(3))) void*)l, 16, 0, 0);
}

__device__ __forceinline__ unsigned short f2bu(float x) {
    hb h = __float2bfloat16(x);
    unsigned short u;
    __builtin_memcpy(&u, &h, 2);
    return u;
}

// ---------------- reductions ----------------
__device__ __forceinline__ float blockSum256(float v) {
    __shared__ float red[4];
    int lane = threadIdx.x & 63, wid = threadIdx.x >> 6;
#pragma unroll
    for (int o = 32; o > 0; o >>= 1) v += __shfl_down(v, o, 64);
    if (lane == 0) red[wid] = v;
    __syncthreads();
    float s = red[0] + red[1] + red[2] + red[3];
    __syncthreads();
    return s;
}
__device__ __forceinline__ float blockMax256(float v) {
    __shared__ float red[4];
    int lane = threadIdx.x & 63, wid = threadIdx.x >> 6;
#pragma unroll
    for (int o = 32; o > 0; o >>= 1) v = fmaxf(v, __shfl_down(v, o, 64));
    if (lane == 0) red[wid] = v;
    __syncthreads();
    float s = fmaxf(fmaxf(red[0], red[1]), fmaxf(red[2], red[3]));
    __syncthreads();
    return s;
}

// ---------------- embedding gather ----------------
__global__ void k_embed(const int* __restrict__ tokens, const float* __restrict__ emb,
                        float* __restrict__ X) {
    int t = blockIdx.x;
    int tok = tokens[t];
    const float4* src = (const float4*)(emb + (size_t)tok * CD);
    float4* dst = (float4*)(X + (size_t)t * CD);
    dst[threadIdx.x] = src[threadIdx.x];
}

// ---------------- rmsnorm (bf16 out) ----------------
__global__ void k_rmsnorm_b(const float* __restrict__ in, const float* __restrict__ w,
                            hb* __restrict__ out) {
    int t = blockIdx.x;
    const float* row = in + (size_t)t * CD;
    float ss = 0.f;
    for (int i = threadIdx.x; i < CD; i += 256) { float v = row[i]; ss += v * v; }
    float tot = blockSum256(ss);
    float sc = rsqrtf(tot / CD + CEPS);
    for (int i = threadIdx.x; i < CD; i += 256)
        out[(size_t)t * CD + i] = __float2bfloat16(row[i] * sc * w[i]);
}

// ---------------- bf16 MFMA GEMM: 128x128 tile, BK=32, 4 waves ----------------
// LDS chunk-swizzle: LDS[row][chunk] holds global chunk (chunk ^ ((row>>1)&3)).
// Applied on the global SOURCE address at staging (LDS dest stays linear for
// global_load_lds) and on the ds_read chunk index. Breaks the 8-way bank
// conflict of the 64B-row layout (lanes 0-15 same-chunk reads).
// EPI: 0 bf16 store (silu(acc1)*acc3 if DUAL, else alpha*acc)
//      2 f32 store   4 f32 store alpha*acc + Cin
template<bool GATHER, bool DUAL, int EPI>
__global__ __launch_bounds__(256, 2)
void k_mf(const hb* __restrict__ A, int lda, long sA1, long sA2,
          const hb* __restrict__ B1g, const hb* __restrict__ B3g, int ldb, long sB1, long sB2,
          const float* __restrict__ Cin, float* __restrict__ Cf, hb* __restrict__ Cb,
          int ldc, long sC1, long sC2,
          const int* __restrict__ lists,
          const int* __restrict__ offs,
          int M, int N, int K, int Zi, float alpha) {
    int z = blockIdx.z, z1 = z / Zi, z2 = z % Zi;
    A += (size_t)z1 * sA1 + (size_t)z2 * sA2;
    const hb* B1 = B1g + (size_t)z1 * sB1 + (size_t)z2 * sB2;
    const hb* B3 = DUAL ? (B3g + (size_t)z1 * sB1 + (size_t)z2 * sB2) : nullptr;
    long coff = (size_t)z1 * sC1 + (size_t)z2 * sC2;
    if (Cf) Cf += coff;
    if (Cb) Cb += coff;
    if (Cin) Cin += coff;

    int base = 0, cnt = M;
    if (offs) { base = offs[z]; cnt = offs[z + 1] - base; }
    int row0 = blockIdx.y * 128;
    if (row0 >= cnt) return;
    int col0 = blockIdx.x * 128;

    __shared__ hb As[128 * 32];
    __shared__ hb Bs1[128 * 32];
    __shared__ hb Bs3[DUAL ? 128 * 32 : 8];

    int tid = threadIdx.x;
    int r0i = tid >> 2, r1i = 64 + (tid >> 2);
    // swizzled source k-chunk: chunk (tid&3) of LDS row r holds global chunk (tid&3)^((r>>1)&3)
    // (r0i and r1i differ by 64 -> same (r>>1)&3)
    int kq = (((tid & 3) ^ ((r0i >> 1) & 3)) * 8);

    auto arowOf = [&](int r) -> size_t {
        int gr = row0 + r; gr = gr < cnt ? gr : cnt - 1;
        if (GATHER) return (size_t)lists[base + gr];
        return (size_t)(base + gr);
    };
    const hb* aS0 = A + arowOf(r0i) * lda + kq;
    const hb* aS1 = A + arowOf(r1i) * lda + kq;
    const hb* b1S0 = B1 + (size_t)(col0 + r0i) * ldb + kq;
    const hb* b1S1 = B1 + (size_t)(col0 + r1i) * ldb + kq;
    const hb* b3S0 = DUAL ? (B3 + (size_t)(col0 + r0i) * ldb + kq) : nullptr;
    const hb* b3S1 = DUAL ? (B3 + (size_t)(col0 + r1i) * ldb + kq) : nullptr;
    hb* aD0 = As + tid * 8;   hb* aD1 = As + (256 + tid) * 8;
    hb* bD0 = Bs1 + tid * 8;  hb* bD1 = Bs1 + (256 + tid) * 8;
    hb* cD0 = Bs3 + tid * 8;  hb* cD1 = Bs3 + (256 + tid) * 8;

    int lane = tid & 63, wid = tid >> 6;
    int wr = wid >> 1, wc = wid & 1;
    int lrow = lane & 15;
    // swizzled read chunk: rows read are wr*64+m*16+lrow / wc*64+n*16+lrow,
    // whose (row>>1)&3 == (lrow>>1)&3 for all m,n.
    int lk = (((lane >> 4) ^ ((lrow >> 1) & 3)) * 8);

    f32x4 acc1[4][4], acc3[4][4];
#pragma unroll
    for (int m = 0; m < 4; ++m)
#pragma unroll
        for (int n = 0; n < 4; ++n) {
            acc1[m][n] = (f32x4){0.f, 0.f, 0.f, 0.f};
            acc3[m][n] = (f32x4){0.f, 0.f, 0.f, 0.f};
        }

    for (int k0 = 0; k0 < K; k0 += 32) {
        gload16(aS0 + k0, aD0);
        gload16(aS1 + k0, aD1);
        gload16(b1S0 + k0, bD0);
        gload16(b1S1 + k0, bD1);
        if constexpr (DUAL) {
            gload16(b3S0 + k0, cD0);
            gload16(b3S1 + k0, cD1);
        }
        __syncthreads();
        bf16x8 af[4], bf1[4], bf3[4];
#pragma unroll
        for (int m = 0; m < 4; ++m)
            af[m] = *(const bf16x8*)(As + (size_t)(wr * 64 + m * 16 + lrow) * 32 + lk);
#pragma unroll
        for (int n = 0; n < 4; ++n)
            bf1[n] = *(const bf16x8*)(Bs1 + (size_t)(wc * 64 + n * 16 + lrow) * 32 + lk);
        if constexpr (DUAL) {
#pragma unroll
            for (int n = 0; n < 4; ++n)
                bf3[n] = *(const bf16x8*)(Bs3 + (size_t)(wc * 64 + n * 16 + lrow) * 32 + lk);
        }
#pragma unroll
        for (int m = 0; m < 4; ++m)
#pragma unroll
            for (int n = 0; n < 4; ++n) {
                acc1[m][n] = __builtin_amdgcn_mfma_f32_16x16x32_bf16(af[m], bf1[n], acc1[m][n], 0, 0, 0);
                if constexpr (DUAL)
                    acc3[m][n] = __builtin_amdgcn_mfma_f32_16x16x32_bf16(af[m], bf3[n], acc3[m][n], 0, 0, 0);
            }
        __syncthreads();
    }

    int lr4 = ((lane >> 4) & 3) * 4;
#pragma unroll
    for (int m = 0; m < 4; ++m) {
#pragma unroll
        for (int q = 0; q < 4; ++q) {
            int r = row0 + wr * 64 + m * 16 + lr4 + q;
            if (r >= cnt) continue;
            size_t orow = (size_t)(base + r) * ldc;
#pragma unroll
            for (int n = 0; n < 4; ++n) {
                int cc = col0 + wc * 64 + n * 16 + (lane & 15);
                float v = acc1[m][n][q];
                if constexpr (EPI == 0) {
                    if constexpr (DUAL) {
                        float y = acc3[m][n][q];
                        v = v / (1.f + __expf(-v)) * y;
                    } else {
                        v *= alpha;
                    }
                    Cb[orow + cc] = __float2bfloat16(v);
                } else if constexpr (EPI == 2) {
                    Cf[orow + cc] = alpha * v;
                } else if constexpr (EPI == 4) {
                    Cf[orow + cc] = alpha * v + Cin[orow + cc];
                }
            }
        }
    }
}

// ---------------- conversions ----------------
__global__ void k_cvt_t(const float* __restrict__ in, hb* __restrict__ out, int R, int C) {
    size_t zoff = (size_t)blockIdx.z * R * C;
    in += zoff; out += zoff;
    __shared__ float t[32][33];
    int c0 = blockIdx.x * 32, r0 = blockIdx.y * 32;
    int tx = threadIdx.x & 31, ty = threadIdx.x >> 5;
#pragma unroll
    for (int j = 0; j < 4; ++j)
        t[ty + 8 * j][tx] = in[(size_t)(r0 + ty + 8 * j) * C + c0 + tx];
    __syncthreads();
#pragma unroll
    for (int j = 0; j < 4; ++j)
        out[(size_t)(c0 + ty + 8 * j) * R + r0 + tx] = __float2bfloat16(t[tx][ty + 8 * j]);
}
__global__ void k_t32(const float* __restrict__ in, float* __restrict__ out, int R, int C) {
    __shared__ float t[32][33];
    int c0 = blockIdx.x * 32, r0 = blockIdx.y * 32;
    int tx = threadIdx.x & 31, ty = threadIdx.x >> 5;
#pragma unroll
    for (int j = 0; j < 4; ++j)
        t[ty + 8 * j][tx] = in[(size_t)(r0 + ty + 8 * j) * C + c0 + tx];
    __syncthreads();
#pragma unroll
    for (int j = 0; j < 4; ++j)
        out[(size_t)(c0 + ty + 8 * j) * R + r0 + tx] = t[tx][ty + 8 * j];
}

// ---------------- softmax rows of CS, bf16 in place ----------------
__global__ void k_softmaxb(hb* __restrict__ P) {
    unsigned* row = (unsigned*)(P + (size_t)blockIdx.x * CS);
    unsigned u0 = row[threadIdx.x * 2], u1 = row[threadIdx.x * 2 + 1];
    float f[4];
    f[0] = __uint_as_float(u0 << 16); f[1] = __uint_as_float(u0 & 0xffff0000u);
    f[2] = __uint_as_float(u1 << 16); f[3] = __uint_as_float(u1 & 0xffff0000u);
    float m = fmaxf(fmaxf(f[0], f[1]), fmaxf(f[2], f[3]));
    m = blockMax256(m);
    float s = 0.f;
#pragma unroll
    for (int i = 0; i < 4; ++i) { f[i] = __expf(f[i] - m); s += f[i]; }
    s = blockSum256(s);
    float inv = 1.f / s;
    unsigned o0 = ((unsigned)f2bu(f[0] * inv)) | (((unsigned)f2bu(f[1] * inv)) << 16);
    unsigned o1 = ((unsigned)f2bu(f[2] * inv)) | (((unsigned)f2bu(f[3] * inv)) << 16);
    row[threadIdx.x * 2] = o0; row[threadIdx.x * 2 + 1] = o1;
}

// ---------------- router: logits GEMM (8 tokens/block) ----------------
__global__ void k_logits(const hb* __restrict__ h2b, const float* __restrict__ rwT,
                         const float* __restrict__ bias, float* __restrict__ logits) {
    __shared__ float hs[8][1032];
    int t0 = blockIdx.x * 8;
    int tid = threadIdx.x;
    const unsigned* src = (const unsigned*)(h2b + (size_t)t0 * CD);
#pragma unroll
    for (int it = 0; it < 16; ++it) {
        int j = tid + it * 256;
        unsigned u = src[j];
        int fidx = j * 2;
        int r = fidx >> 10, c = fidx & 1023;
        hs[r][c] = __uint_as_float(u << 16);
        hs[r][c + 1] = __uint_as_float(u & 0xffff0000u);
    }
    __syncthreads();
    int e = tid >> 3, tl = tid & 7;
    const float4* wrow = (const float4*)(rwT + (size_t)e * CD);
    float acc = 0.f;
#pragma unroll 4
    for (int d4 = 0; d4 < 256; ++d4) {
        float4 w = wrow[d4];
        float4 h = *(const float4*)&hs[tl][d4 * 4];
        acc += w.x * h.x + w.y * h.y + w.z * h.z + w.w * h.w;
    }
    logits[(size_t)(t0 + tl) * CE + e] = acc + bias[e];
}

// ---------------- route: per-thread softmax + top-8 + LDS histogram ----------------
__global__ void k_route(const float* __restrict__ logits, int* __restrict__ topi,
                        float* __restrict__ topw, int* __restrict__ counts) {
    __shared__ int lc[CE];
    int tid = threadIdx.x;
    if (tid < CE) lc[tid] = 0;
    __syncthreads();
    int t = blockIdx.x * 256 + tid;
    float p[CE];
    const float4* row4 = (const float4*)(logits + (size_t)t * CE);
    float mx = -1e30f;
#pragma unroll
    for (int i = 0; i < CE / 4; ++i) {
        float4 v = row4[i];
        p[i * 4] = v.x; p[i * 4 + 1] = v.y; p[i * 4 + 2] = v.z; p[i * 4 + 3] = v.w;
    }
#pragma unroll
    for (int i = 0; i < CE; ++i) mx = fmaxf(mx, p[i]);
    float s = 0.f;
#pragma unroll
    for (int i = 0; i < CE; ++i) { p[i] = __expf(p[i] - mx); s += p[i]; }
    float inv = 1.f / s;
#pragma unroll
    for (int i = 0; i < CE; ++i) p[i] *= inv;

    float vals[CKS]; int ids[CKS];
#pragma unroll
    for (int k = 0; k < CKS; ++k) {
        float bv = -1.f; int bi = 0;
#pragma unroll
        for (int q = 0; q < CE; ++q)
            if (p[q] > bv) { bv = p[q]; bi = q; }
        vals[k] = bv; ids[k] = bi;
#pragma unroll
        for (int q = 0; q < CE; ++q)
            if (q == bi) p[q] = -2.f;
    }
    float ss = 0.f; float ww[CKS];
#pragma unroll
    for (int k = 0; k < CKS; ++k) { ww[k] = __expf(vals[k] - vals[0]); ss += ww[k]; }
    float wiv = 1.f / ss;
#pragma unroll
    for (int k = 0; k < CKS; ++k) {
        topi[t * CKS + k] = ids[k];
        topw[t * CKS + k] = ww[k] * wiv;
        atomicAdd(&lc[ids[k]], 1);
    }
    __syncthreads();
    if (tid < CE) atomicAdd(&counts[tid], lc[tid]);
}

__global__ void k_scan(const int* __restrict__ counts, int* __restrict__ offs) {
    if (threadIdx.x == 0) {
        int a = 0;
        for (int e = 0; e < CE; ++e) { offs[e] = a; a += counts[e]; }
        offs[CE] = a;
    }
}

// ---------------- fill: block-aggregated cursor reservation + inverse map ----------------
__global__ void k_fill(const int* __restrict__ topi,
                       const int* __restrict__ offs, int* __restrict__ cursor,
                       int* __restrict__ lists, int* __restrict__ slot_of) {
    __shared__ int lcnt[CE];
    __shared__ int lbase[CE];
    int tid = threadIdx.x;
    if (tid < CE) lcnt[tid] = 0;
    __syncthreads();
    int idx = blockIdx.x * 256 + tid;
    int e = topi[idx];
    int lpos = atomicAdd(&lcnt[e], 1);
    __syncthreads();
    if (tid < CE) lbase[tid] = lcnt[tid] ? atomicAdd(&cursor[tid], lcnt[tid]) : 0;
    __syncthreads();
    int slot = offs[e] + lbase[e] + lpos;
    lists[slot] = idx >> 3;
    slot_of[idx] = slot;
}

// ---------------- fused combine + residual + final rmsnorm ----------------
__global__ void k_combine(const float* __restrict__ X2, const hb* __restrict__ HSd,
                          const hb* __restrict__ spec_b, const float* __restrict__ topw,
                          const int* __restrict__ slot_of, const float* __restrict__ fnw,
                          float* __restrict__ normX) {
    int t = blockIdx.x, tid = threadIdx.x;
    int d0 = tid * 4;
    __shared__ float wsm[CKS];
    __shared__ int ssm[CKS];
    if (tid < CKS) { wsm[tid] = topw[t * CKS + tid]; ssm[tid] = slot_of[t * CKS + tid]; }
    const float4 x = *(const float4*)(X2 + (size_t)t * CD + d0);
    uint2 hu = *(const uint2*)(HSd + (size_t)t * CD + d0);
    float a0 = x.x + __uint_as_float(hu.x << 16);
    float a1 = x.y + __uint_as_float(hu.x & 0xffff0000u);
    float a2 = x.z + __uint_as_float(hu.y << 16);
    float a3 = x.w + __uint_as_float(hu.y & 0xffff0000u);
    __syncthreads();
#pragma unroll
    for (int k = 0; k < CKS; ++k) {
        float w = wsm[k];
        uint2 u = *(const uint2*)(spec_b + (size_t)ssm[k] * CD + d0);
        a0 += w * __uint_as_float(u.x << 16);
        a1 += w * __uint_as_float(u.x & 0xffff0000u);
        a2 += w * __uint_as_float(u.y << 16);
        a3 += w * __uint_as_float(u.y & 0xffff0000u);
    }
    float ss = a0 * a0 + a1 * a1 + a2 * a2 + a3 * a3;
    float tot = blockSum256(ss);
    float sc = rsqrtf(tot / CD + CEPS);
    float4 o;
    o.x = a0 * sc * fnw[d0];     o.y = a1 * sc * fnw[d0 + 1];
    o.z = a2 * sc * fnw[d0 + 2]; o.w = a3 * sc * fnw[d0 + 3];
    *(float4*)(normX + (size_t)t * CD + d0) = o;
}

__global__ void k_pool(const float* __restrict__ nx, float* __restrict__ pooled) {
    int b = blockIdx.y;
    int d = blockIdx.x * 256 + threadIdx.x;
    float s = 0.f;
    for (int t = 0; t < CS; ++t) s += nx[((size_t)(b * CS + t)) * CD + d];
    pooled[b * CD + d] = s * (1.f / CS);
}

__global__ void k_head(const float* __restrict__ pooled, const float* __restrict__ cw,
                       const float* __restrict__ cb, float* __restrict__ out) {
    __shared__ float lg[CB * CNC];
    int i = threadIdx.x;
    if (i < CB * CNC) {
        int b = i / CNC, c = i % CNC;
        float s = cb[c];
        for (int d = 0; d < CD; ++d) s += pooled[b * CD + d] * cw[(size_t)d * CNC + c];
        lg[i] = s;
    }
    __syncthreads();
    if (i < CB) {
        float mx = -1e30f;
        for (int c = 0; c < CNC; ++c) mx = fmaxf(mx, lg[i * CNC + c]);
        float ex[CNC]; float s = 0.f;
        for (int c = 0; c < CNC; ++c) { ex[c] = __expf(lg[i * CNC + c] - mx); s += ex[c]; }
        for (int c = 0; c < CNC; ++c) out[i * CNC + c] = ex[c] / s;
    }
}

} // namespace

extern "C" void kernel_launch(void* const* d_in, const int* in_sizes, int n_in,
                              void* d_out, int out_size, void* d_ws, size_t ws_size,
                              hipStream_t stream) {
    const int*   tokens = (const int*)d_in[0];
    const float* emb    = (const float*)d_in[1];
    const float* n1w    = (const float*)d_in[2];
    const float* n2w    = (const float*)d_in[3];
    const float* Wq     = (const float*)d_in[4];
    const float* Wk     = (const float*)d_in[5];
    const float* Wv     = (const float*)d_in[6];
    const float* Wo     = (const float*)d_in[7];
    const float* rw     = (const float*)d_in[8];
    const float* ebias  = (const float*)d_in[9];
    const float* shw1   = (const float*)d_in[10];
    const float* shw3   = (const float*)d_in[11];
    const float* shw2   = (const float*)d_in[12];
    const float* exw1   = (const float*)d_in[13];
    const float* exw3   = (const float*)d_in[14];
    const float* exw2   = (const float*)d_in[15];
    const float* fnw    = (const float*)d_in[16];
    const float* clsw   = (const float*)d_in[17];
    const float* clsb   = (const float*)d_in[18];
    float* out = (float*)d_out;

    constexpr size_t MB = 1ull << 20;
    char* base = (char*)d_ws;
    float* X   = (float*)(base);             // 16 MB residual / normX
    float* Xh  = (float*)(base + 16 * MB);   // 16 MB X2
    hb*  HSd   = (hb*)(base + 32 * MB);      // 8 MB shared-expert down output (bf16)
    float* pooled  = (float*)(base + 48 * MB);
    float* topw    = pooled + 4096;
    float* logitsB = topw + CT * CKS;
    float* rwT     = logitsB + CT * CE;
    int* topi    = (int*)(rwT + CE * CD);
    int* lists   = topi + CT * CKS;
    int* slot_of = lists + CT * CKS;
    int* counts  = slot_of + CT * CKS;
    int* cursor  = counts + CE;
    int* offs    = cursor + CE;
    char* pool = base + 50 * MB;
    // attention phase
    float* Vc = (float*)(pool);              // 4 MB
    hb* h1b  = (hb*)(pool + 4 * MB);         // 8 MB
    hb* Qbb  = (hb*)(pool + 12 * MB);        // 8 MB
    hb* Kb   = (hb*)(pool + 20 * MB);        // 2 MB
    hb* Vct  = (hb*)(pool + 22 * MB);        // 2 MB
    hb* Pb   = (hb*)(pool + 24 * MB);        // 32 MB
    hb* AOb  = (hb*)(pool + 56 * MB);        // 8 MB
    hb* Wqt  = (hb*)(pool + 64 * MB);        // 2 MB
    hb* Wot  = (hb*)(pool + 66 * MB);        // 2 MB
    hb* Wkt  = (hb*)(pool + 68 * MB);        // 1 MB
    hb* Wvt  = (hb*)(pool + 69 * MB);        // 1 MB
    // moe phase overlays
    hb* h2b   = (hb*)(pool);                 // 8 MB
    hb* HSb   = (hb*)(pool + 8 * MB);        // 4 MB
    hb* g     = (hb*)(pool + 12 * MB);       // 32 MB
    hb* shw1t = (hb*)(pool + 44 * MB);
    hb* shw3t = (hb*)(pool + 45 * MB);
    hb* shw2t = (hb*)(pool + 46 * MB);
    hb* exw1t = (hb*)(pool + 47 * MB);       // 32 MB
    hb* exw3t = (hb*)(pool + 79 * MB);       // 32 MB
    hb* exw2t = (hb*)(pool + 111 * MB);      // 32 MB (ends 193 MB)
    hb* spec_b = exw1t;                      // 64 MB, overlays exw1t+exw3t (dead at down-proj)

    dim3 b256(256);

    // ---- prologue ----
    k_embed<<<CT, b256, 0, stream>>>(tokens, emb, X);
    k_rmsnorm_b<<<CT, b256, 0, stream>>>(X, n1w, h1b);
    k_t32<<<dim3(1, CD / 32), b256, 0, stream>>>(rw, rwT, CD, CE);
    k_cvt_t<<<dim3(CD / 32, CD / 32, 1), b256, 0, stream>>>(Wq, Wqt, CD, CD);
    k_cvt_t<<<dim3(CDKV / 32, CD / 32, 1), b256, 0, stream>>>(Wk, Wkt, CD, CDKV);
    k_cvt_t<<<dim3(CDKV / 32, CD / 32, 1), b256, 0, stream>>>(Wv, Wvt, CD, CDKV);
    k_cvt_t<<<dim3(CD / 32, CD / 32, 1), b256, 0, stream>>>(Wo, Wot, CD, CD);

    // ---- attention (bf16 MFMA) ----
    k_mf<false, false, 0><<<dim3(CD / 128, CT / 128, 1), b256, 0, stream>>>(
        h1b, CD, 0, 0, Wqt, nullptr, CD, 0, 0, nullptr, nullptr, Qbb, CD, 0, 0,
        nullptr, nullptr, CT, CD, CD, 1, 1.f);
    k_mf<false, false, 0><<<dim3(CDKV / 128, CT / 128, 1), b256, 0, stream>>>(
        h1b, CD, 0, 0, Wkt, nullptr, CD, 0, 0, nullptr, nullptr, Kb, CDKV, 0, 0,
        nullptr, nullptr, CT, CDKV, CD, 1, 1.f);
    k_mf<false, false, 2><<<dim3(CDKV / 128, CT / 128, 1), b256, 0, stream>>>(
        h1b, CD, 0, 0, Wvt, nullptr, CD, 0, 0, nullptr, Vc, nullptr, CDKV, 0, 0,
        nullptr, nullptr, CT, CDKV, CD, 1, 1.f);
    k_cvt_t<<<dim3(CDKV / 32, CS / 32, CB), b256, 0, stream>>>(Vc, Vct, CS, CDKV);
    k_mf<false, false, 0><<<dim3(CS / 128, CS / 128, CB * CH), b256, 0, stream>>>(
        Qbb, CD, (long)CS * CD, CDK,
        Kb, nullptr, CDKV, (long)CS * CDKV, 0,
        nullptr, nullptr, Pb, CS, (long)CH * CS * CS, (long)CS * CS,
        nullptr, nullptr, CS, CS, CDK, CH, 1.f / 16.f);
    k_softmaxb<<<CB * CH * CS, b256, 0, stream>>>(Pb);
    k_mf<false, false, 0><<<dim3(CDK / 128, CS / 128, CB * CH), b256, 0, stream>>>(
        Pb, CS, (long)CH * CS * CS, (long)CS * CS,
        Vct, nullptr, CS, (long)CDKV * CS, 0,
        nullptr, nullptr, AOb, CD, (long)CS * CD, CDK,
        nullptr, nullptr, CS, CDK, CS, CH, 1.f);
    k_mf<false, false, 4><<<dim3(CD / 128, CT / 128, 1), b256, 0, stream>>>(
        AOb, CD, 0, 0, Wot, nullptr, CD, 0, 0, X, Xh, nullptr, CD, 0, 0,
        nullptr, nullptr, CT, CD, CD, 1, 1.f);

    // ---- MoE routing ----
    k_rmsnorm_b<<<CT, b256, 0, stream>>>(Xh, n2w, h2b);
    hipMemsetAsync(counts, 0, (size_t)(CE + CE + CE + 1) * sizeof(int), stream);
    k_logits<<<CT / 8, b256, 0, stream>>>(h2b, rwT, ebias, logitsB);
    k_route<<<CT / 256, b256, 0, stream>>>(logitsB, topi, topw, counts);
    k_scan<<<1, 64, 0, stream>>>(counts, offs);
    k_fill<<<CT * CKS / 256, b256, 0, stream>>>(topi, offs, cursor, lists, slot_of);

    // MoE weight converts
    k_cvt_t<<<dim3(CF / 32, CD / 32, 1), b256, 0, stream>>>(shw1, shw1t, CD, CF);
    k_cvt_t<<<dim3(CF / 32, CD / 32, 1), b256, 0, stream>>>(shw3, shw3t, CD, CF);
    k_cvt_t<<<dim3(CD / 32, CF / 32, 1), b256, 0, stream>>>(shw2, shw2t, CF, CD);
    k_cvt_t<<<dim3(CF / 32, CD / 32, CE), b256, 0, stream>>>(exw1, exw1t, CD, CF);
    k_cvt_t<<<dim3(CF / 32, CD / 32, CE), b256, 0, stream>>>(exw3, exw3t, CD, CF);
    k_cvt_t<<<dim3(CD / 32, CF / 32, CE), b256, 0, stream>>>(exw2, exw2t, CF, CD);

    // shared expert: HSb = silu(h2@w1)*(h2@w3); HSd = (HSb @ w2) bf16
    k_mf<false, true, 0><<<dim3(CF / 128, CT / 128, 1), b256, 0, stream>>>(
        h2b, CD, 0, 0, shw1t, shw3t, CD, 0, 0, nullptr, nullptr, HSb, CF, 0, 0,
        nullptr, nullptr, CT, CF, CD, 1, 1.f);
    // routed experts: g[slot] = silu/mul up-proj (gathered A rows)
    k_mf<true, true, 0><<<dim3(CF / 128, CT / 128, CE), b256, 0, stream>>>(
        h2b, CD, 0, 0, exw1t, exw3t, CD, (long)CD * CF, 0, nullptr, nullptr, g, CF, 0, 0,
        lists, offs, 0, CF, CD, 1, 1.f);
    // shared down
    k_mf<false, false, 0><<<dim3(CD / 128, CT / 128, 1), b256, 0, stream>>>(
        HSb, CF, 0, 0, shw2t, nullptr, CF, 0, 0, nullptr, nullptr, HSd, CD, 0, 0,
        nullptr, nullptr, CT, CD, CF, 1, 1.f);
    // routed down: spec_b[slot] = g[slot] @ w2[e]  (plain bf16 rows, no atomics)
    k_mf<false, false, 0><<<dim3(CD / 128, CT / 128, CE), b256, 0, stream>>>(
        g, CF, 0, 0, exw2t, nullptr, CF, (long)CF * CD, 0, nullptr, nullptr, spec_b, CD, 0, 0,
        nullptr, offs, 0, CD, CF, 1, 1.f);

    // fused: X3 = X2 + HSd + sum_k topw*spec_b ; final rmsnorm -> X (normX)
    k_combine<<<CT, b256, 0, stream>>>(Xh, HSd, spec_b, topw, slot_of, fnw, X);

    // head
    k_pool<<<dim3(CD / 256, CB), b256, 0, stream>>>(X, pooled);
    k_head<<<1, b256, 0, stream>>>(pooled, clsw, clsb, out);
}

// Round 7
// 626.856 us; speedup vs baseline: 5.0190x; 1.0344x over previous
//
#include <hip/hip_runtime.h>
#include <hip/hip_bf16.h>
#include <cmath>

namespace {

constexpr int CB = 4, CS = 1024, CD = 1024, CH = 4, CE = 32, CF = 512;
constexpr int CKS = 8, CNC = 10, CDK = 256, CDKV = 256;
constexpr int CT = CB * CS;
constexpr float CEPS = 1e-6f;

using hb = __hip_bfloat16;
typedef __bf16 bf16x8 __attribute__((ext_vector_type(8)));
typedef float f32x4 __attribute__((ext_vector_type(4)));

__device__ __forceinline__ void gload16(const void* g, void* l) {
    __builtin_amdgcn_global_load_lds((const __attribute__((address_space(1))) void*)g,
                                     (__attribute__((address_space(3))) void*)l, 16, 0, 0);
}

__device__ __forceinline__ unsigned short f2bu(float x) {
    hb h = __float2bfloat16(x);
    unsigned short u;
    __builtin_memcpy(&u, &h, 2);
    return u;
}

// ---------------- reductions ----------------
__device__ __forceinline__ float blockSum256(float v) {
    __shared__ float red[4];
    int lane = threadIdx.x & 63, wid = threadIdx.x >> 6;
#pragma unroll
    for (int o = 32; o > 0; o >>= 1) v += __shfl_down(v, o, 64);
    if (lane == 0) red[wid] = v;
    __syncthreads();
    float s = red[0] + red[1] + red[2] + red[3];
    __syncthreads();
    return s;
}
__device__ __forceinline__ float blockMax256(float v) {
    __shared__ float red[4];
    int lane = threadIdx.x & 63, wid = threadIdx.x >> 6;
#pragma unroll
    for (int o = 32; o > 0; o >>= 1) v = fmaxf(v, __shfl_down(v, o, 64));
    if (lane == 0) red[wid] = v;
    __syncthreads();
    float s = fmaxf(fmaxf(red[0], red[1]), fmaxf(red[2], red[3]));
    __syncthreads();
    return s;
}

// ---------------- embedding gather ----------------
__global__ void k_embed(const int* __restrict__ tokens, const float* __restrict__ emb,
                        float* __restrict__ X) {
    int t = blockIdx.x;
    int tok = tokens[t];
    const float4* src = (const float4*)(emb + (size_t)tok * CD);
    float4* dst = (float4*)(X + (size_t)t * CD);
    dst[threadIdx.x] = src[threadIdx.x];
}

// ---------------- rmsnorm (bf16 out) ----------------
__global__ void k_rmsnorm_b(const float* __restrict__ in, const float* __restrict__ w,
                            hb* __restrict__ out) {
    int t = blockIdx.x;
    const float* row = in + (size_t)t * CD;
    float ss = 0.f;
    for (int i = threadIdx.x; i < CD; i += 256) { float v = row[i]; ss += v * v; }
    float tot = blockSum256(ss);
    float sc = rsqrtf(tot / CD + CEPS);
    for (int i = threadIdx.x; i < CD; i += 256)
        out[(size_t)t * CD + i] = __float2bfloat16(row[i] * sc * w[i]);
}

// ---------------- bf16 MFMA GEMM: 128x128 tile, BK=32, 4 waves ----------------
// Double-buffered LDS with overlapped staging: stage(k+1) issued before compute(k),
// one barrier per K-step (compiler's vmcnt(0)-at-barrier drains overlapped loads).
// LDS chunk-swizzle vs 64B-row bank conflicts (source-side, linear dest).
// XCD-aware work-id swizzle: consecutive work tiles cluster per XCD (weight L2 reuse).
// EPI: 0 bf16 store (silu(acc1)*acc3 if DUAL, else alpha*acc)
//      2 f32 store   4 f32 store alpha*acc + Cin
template<bool GATHER, bool DUAL, int EPI>
__global__ __launch_bounds__(256, 2)
void k_mf(const hb* __restrict__ A, int lda, long sA1, long sA2,
          const hb* __restrict__ B1g, const hb* __restrict__ B3g, int ldb, long sB1, long sB2,
          const float* __restrict__ Cin, float* __restrict__ Cf, hb* __restrict__ Cb,
          int ldc, long sC1, long sC2,
          const int* __restrict__ lists,
          const int* __restrict__ offs,
          int M, int N, int K, int Zi, float alpha) {
    // bijective XCD swizzle on the flat work id (grid sizes are multiples of 8)
    unsigned gx = gridDim.x, gy = gridDim.y;
    unsigned nb = gx * gy * gridDim.z;
    unsigned a0id = blockIdx.x + gx * (blockIdx.y + gy * blockIdx.z);
    unsigned wfl = (a0id & 7) * (nb >> 3) + (a0id >> 3);
    unsigned bx = wfl % gx; unsigned tt = wfl / gx;
    unsigned by = tt % gy;  unsigned bz = tt / gy;

    int z = bz, z1 = z / Zi, z2 = z % Zi;
    A += (size_t)z1 * sA1 + (size_t)z2 * sA2;
    const hb* B1 = B1g + (size_t)z1 * sB1 + (size_t)z2 * sB2;
    const hb* B3 = DUAL ? (B3g + (size_t)z1 * sB1 + (size_t)z2 * sB2) : nullptr;
    long coff = (size_t)z1 * sC1 + (size_t)z2 * sC2;
    if (Cf) Cf += coff;
    if (Cb) Cb += coff;
    if (Cin) Cin += coff;

    int base = 0, cnt = M;
    if (offs) { base = offs[z]; cnt = offs[z + 1] - base; }
    int row0 = by * 128;
    if (row0 >= cnt) return;
    int col0 = bx * 128;

    __shared__ hb As[2][128 * 32];
    __shared__ hb Bs1[2][128 * 32];
    __shared__ hb Bs3[DUAL ? 2 : 1][DUAL ? 128 * 32 : 8];

    int tid = threadIdx.x;
    int r0i = tid >> 2, r1i = 64 + (tid >> 2);
    // swizzled source k-chunk (LDS dest linear; see round-5 notes)
    int kq = (((tid & 3) ^ ((r0i >> 1) & 3)) * 8);

    auto arowOf = [&](int r) -> size_t {
        int gr = row0 + r; gr = gr < cnt ? gr : cnt - 1;
        if (GATHER) return (size_t)lists[base + gr];
        return (size_t)(base + gr);
    };
    const hb* aS0 = A + arowOf(r0i) * lda + kq;
    const hb* aS1 = A + arowOf(r1i) * lda + kq;
    const hb* b1S0 = B1 + (size_t)(col0 + r0i) * ldb + kq;
    const hb* b1S1 = B1 + (size_t)(col0 + r1i) * ldb + kq;
    const hb* b3S0 = DUAL ? (B3 + (size_t)(col0 + r0i) * ldb + kq) : nullptr;
    const hb* b3S1 = DUAL ? (B3 + (size_t)(col0 + r1i) * ldb + kq) : nullptr;

    auto stage = [&](int buf, int k0) {
        gload16(aS0 + k0, As[buf] + tid * 8);
        gload16(aS1 + k0, As[buf] + (256 + tid) * 8);
        gload16(b1S0 + k0, Bs1[buf] + tid * 8);
        gload16(b1S1 + k0, Bs1[buf] + (256 + tid) * 8);
        if constexpr (DUAL) {
            gload16(b3S0 + k0, Bs3[buf] + tid * 8);
            gload16(b3S1 + k0, Bs3[buf] + (256 + tid) * 8);
        }
    };

    int lane = tid & 63, wid = tid >> 6;
    int wr = wid >> 1, wc = wid & 1;
    int lrow = lane & 15;
    int lk = (((lane >> 4) ^ ((lrow >> 1) & 3)) * 8);

    f32x4 acc1[4][4], acc3[4][4];
#pragma unroll
    for (int m = 0; m < 4; ++m)
#pragma unroll
        for (int n = 0; n < 4; ++n) {
            acc1[m][n] = (f32x4){0.f, 0.f, 0.f, 0.f};
            acc3[m][n] = (f32x4){0.f, 0.f, 0.f, 0.f};
        }

    stage(0, 0);
    __syncthreads();          // compiler drains vmcnt here
    int cur = 0;

    for (int k0 = 0; k0 < K; k0 += 32) {
        if (k0 + 32 < K) stage(cur ^ 1, k0 + 32);   // overlapped prefetch
        bf16x8 af[4], bf1[4], bf3[4];
#pragma unroll
        for (int m = 0; m < 4; ++m)
            af[m] = *(const bf16x8*)(As[cur] + (size_t)(wr * 64 + m * 16 + lrow) * 32 + lk);
#pragma unroll
        for (int n = 0; n < 4; ++n)
            bf1[n] = *(const bf16x8*)(Bs1[cur] + (size_t)(wc * 64 + n * 16 + lrow) * 32 + lk);
        if constexpr (DUAL) {
#pragma unroll
            for (int n = 0; n < 4; ++n)
                bf3[n] = *(const bf16x8*)(Bs3[cur] + (size_t)(wc * 64 + n * 16 + lrow) * 32 + lk);
        }
        __builtin_amdgcn_s_setprio(1);
#pragma unroll
        for (int m = 0; m < 4; ++m)
#pragma unroll
            for (int n = 0; n < 4; ++n) {
                acc1[m][n] = __builtin_amdgcn_mfma_f32_16x16x32_bf16(af[m], bf1[n], acc1[m][n], 0, 0, 0);
                if constexpr (DUAL)
                    acc3[m][n] = __builtin_amdgcn_mfma_f32_16x16x32_bf16(af[m], bf3[n], acc3[m][n], 0, 0, 0);
            }
        __builtin_amdgcn_s_setprio(0);
        __syncthreads();      // single barrier: drains prefetch, protects buffer swap
        cur ^= 1;
    }

    int lr4 = ((lane >> 4) & 3) * 4;
#pragma unroll
    for (int m = 0; m < 4; ++m) {
#pragma unroll
        for (int q = 0; q < 4; ++q) {
            int r = row0 + wr * 64 + m * 16 + lr4 + q;
            if (r >= cnt) continue;
            size_t orow = (size_t)(base + r) * ldc;
#pragma unroll
            for (int n = 0; n < 4; ++n) {
                int cc = col0 + wc * 64 + n * 16 + (lane & 15);
                float v = acc1[m][n][q];
                if constexpr (EPI == 0) {
                    if constexpr (DUAL) {
                        float y = acc3[m][n][q];
                        v = v / (1.f + __expf(-v)) * y;
                    } else {
                        v *= alpha;
                    }
                    Cb[orow + cc] = __float2bfloat16(v);
                } else if constexpr (EPI == 2) {
                    Cf[orow + cc] = alpha * v;
                } else if constexpr (EPI == 4) {
                    Cf[orow + cc] = alpha * v + Cin[orow + cc];
                }
            }
        }
    }
}

// ---------------- conversions ----------------
__global__ void k_cvt_t(const float* __restrict__ in, hb* __restrict__ out, int R, int C) {
    size_t zoff = (size_t)blockIdx.z * R * C;
    in += zoff; out += zoff;
    __shared__ float t[32][33];
    int c0 = blockIdx.x * 32, r0 = blockIdx.y * 32;
    int tx = threadIdx.x & 31, ty = threadIdx.x >> 5;
#pragma unroll
    for (int j = 0; j < 4; ++j)
        t[ty + 8 * j][tx] = in[(size_t)(r0 + ty + 8 * j) * C + c0 + tx];
    __syncthreads();
#pragma unroll
    for (int j = 0; j < 4; ++j)
        out[(size_t)(c0 + ty + 8 * j) * R + r0 + tx] = __float2bfloat16(t[tx][ty + 8 * j]);
}
__global__ void k_t32(const float* __restrict__ in, float* __restrict__ out, int R, int C) {
    __shared__ float t[32][33];
    int c0 = blockIdx.x * 32, r0 = blockIdx.y * 32;
    int tx = threadIdx.x & 31, ty = threadIdx.x >> 5;
#pragma unroll
    for (int j = 0; j < 4; ++j)
        t[ty + 8 * j][tx] = in[(size_t)(r0 + ty + 8 * j) * C + c0 + tx];
    __syncthreads();
#pragma unroll
    for (int j = 0; j < 4; ++j)
        out[(size_t)(c0 + ty + 8 * j) * R + r0 + tx] = t[tx][ty + 8 * j];
}

// ---------------- softmax rows of CS, bf16 in place ----------------
__global__ void k_softmaxb(hb* __restrict__ P) {
    unsigned* row = (unsigned*)(P + (size_t)blockIdx.x * CS);
    unsigned u0 = row[threadIdx.x * 2], u1 = row[threadIdx.x * 2 + 1];
    float f[4];
    f[0] = __uint_as_float(u0 << 16); f[1] = __uint_as_float(u0 & 0xffff0000u);
    f[2] = __uint_as_float(u1 << 16); f[3] = __uint_as_float(u1 & 0xffff0000u);
    float m = fmaxf(fmaxf(f[0], f[1]), fmaxf(f[2], f[3]));
    m = blockMax256(m);
    float s = 0.f;
#pragma unroll
    for (int i = 0; i < 4; ++i) { f[i] = __expf(f[i] - m); s += f[i]; }
    s = blockSum256(s);
    float inv = 1.f / s;
    unsigned o0 = ((unsigned)f2bu(f[0] * inv)) | (((unsigned)f2bu(f[1] * inv)) << 16);
    unsigned o1 = ((unsigned)f2bu(f[2] * inv)) | (((unsigned)f2bu(f[3] * inv)) << 16);
    row[threadIdx.x * 2] = o0; row[threadIdx.x * 2 + 1] = o1;
}

// ---------------- router: logits GEMM (8 tokens/block) ----------------
__global__ void k_logits(const hb* __restrict__ h2b, const float* __restrict__ rwT,
                         const float* __restrict__ bias, float* __restrict__ logits) {
    __shared__ float hs[8][1032];
    int t0 = blockIdx.x * 8;
    int tid = threadIdx.x;
    const unsigned* src = (const unsigned*)(h2b + (size_t)t0 * CD);
#pragma unroll
    for (int it = 0; it < 16; ++it) {
        int j = tid + it * 256;
        unsigned u = src[j];
        int fidx = j * 2;
        int r = fidx >> 10, c = fidx & 1023;
        hs[r][c] = __uint_as_float(u << 16);
        hs[r][c + 1] = __uint_as_float(u & 0xffff0000u);
    }
    __syncthreads();
    int e = tid >> 3, tl = tid & 7;
    const float4* wrow = (const float4*)(rwT + (size_t)e * CD);
    float acc = 0.f;
#pragma unroll 4
    for (int d4 = 0; d4 < 256; ++d4) {
        float4 w = wrow[d4];
        float4 h = *(const float4*)&hs[tl][d4 * 4];
        acc += w.x * h.x + w.y * h.y + w.z * h.z + w.w * h.w;
    }
    logits[(size_t)(t0 + tl) * CE + e] = acc + bias[e];
}

// ---------------- route: per-thread softmax + top-8 + LDS histogram ----------------
__global__ void k_route(const float* __restrict__ logits, int* __restrict__ topi,
                        float* __restrict__ topw, int* __restrict__ counts) {
    __shared__ int lc[CE];
    int tid = threadIdx.x;
    if (tid < CE) lc[tid] = 0;
    __syncthreads();
    int t = blockIdx.x * 256 + tid;
    float p[CE];
    const float4* row4 = (const float4*)(logits + (size_t)t * CE);
    float mx = -1e30f;
#pragma unroll
    for (int i = 0; i < CE / 4; ++i) {
        float4 v = row4[i];
        p[i * 4] = v.x; p[i * 4 + 1] = v.y; p[i * 4 + 2] = v.z; p[i * 4 + 3] = v.w;
    }
#pragma unroll
    for (int i = 0; i < CE; ++i) mx = fmaxf(mx, p[i]);
    float s = 0.f;
#pragma unroll
    for (int i = 0; i < CE; ++i) { p[i] = __expf(p[i] - mx); s += p[i]; }
    float inv = 1.f / s;
#pragma unroll
    for (int i = 0; i < CE; ++i) p[i] *= inv;

    float vals[CKS]; int ids[CKS];
#pragma unroll
    for (int k = 0; k < CKS; ++k) {
        float bv = -1.f; int bi = 0;
#pragma unroll
        for (int q = 0; q < CE; ++q)
            if (p[q] > bv) { bv = p[q]; bi = q; }
        vals[k] = bv; ids[k] = bi;
#pragma unroll
        for (int q = 0; q < CE; ++q)
            if (q == bi) p[q] = -2.f;
    }
    float ss = 0.f; float ww[CKS];
#pragma unroll
    for (int k = 0; k < CKS; ++k) { ww[k] = __expf(vals[k] - vals[0]); ss += ww[k]; }
    float wiv = 1.f / ss;
#pragma unroll
    for (int k = 0; k < CKS; ++k) {
        topi[t * CKS + k] = ids[k];
        topw[t * CKS + k] = ww[k] * wiv;
        atomicAdd(&lc[ids[k]], 1);
    }
    __syncthreads();
    if (tid < CE) atomicAdd(&counts[tid], lc[tid]);
}

__global__ void k_scan(const int* __restrict__ counts, int* __restrict__ offs) {
    if (threadIdx.x == 0) {
        int a = 0;
        for (int e = 0; e < CE; ++e) { offs[e] = a; a += counts[e]; }
        offs[CE] = a;
    }
}

// ---------------- fill: block-aggregated cursor reservation + inverse map ----------------
__global__ void k_fill(const int* __restrict__ topi,
                       const int* __restrict__ offs, int* __restrict__ cursor,
                       int* __restrict__ lists, int* __restrict__ slot_of) {
    __shared__ int lcnt[CE];
    __shared__ int lbase[CE];
    int tid = threadIdx.x;
    if (tid < CE) lcnt[tid] = 0;
    __syncthreads();
    int idx = blockIdx.x * 256 + tid;
    int e = topi[idx];
    int lpos = atomicAdd(&lcnt[e], 1);
    __syncthreads();
    if (tid < CE) lbase[tid] = lcnt[tid] ? atomicAdd(&cursor[tid], lcnt[tid]) : 0;
    __syncthreads();
    int slot = offs[e] + lbase[e] + lpos;
    lists[slot] = idx >> 3;
    slot_of[idx] = slot;
}

// ---------------- fused combine + residual + final rmsnorm ----------------
__global__ void k_combine(const float* __restrict__ X2, const hb* __restrict__ HSd,
                          const hb* __restrict__ spec_b, const float* __restrict__ topw,
                          const int* __restrict__ slot_of, const float* __restrict__ fnw,
                          float* __restrict__ normX) {
    int t = blockIdx.x, tid = threadIdx.x;
    int d0 = tid * 4;
    __shared__ float wsm[CKS];
    __shared__ int ssm[CKS];
    if (tid < CKS) { wsm[tid] = topw[t * CKS + tid]; ssm[tid] = slot_of[t * CKS + tid]; }
    const float4 x = *(const float4*)(X2 + (size_t)t * CD + d0);
    uint2 hu = *(const uint2*)(HSd + (size_t)t * CD + d0);
    float a0 = x.x + __uint_as_float(hu.x << 16);
    float a1 = x.y + __uint_as_float(hu.x & 0xffff0000u);
    float a2 = x.z + __uint_as_float(hu.y << 16);
    float a3 = x.w + __uint_as_float(hu.y & 0xffff0000u);
    __syncthreads();
#pragma unroll
    for (int k = 0; k < CKS; ++k) {
        float w = wsm[k];
        uint2 u = *(const uint2*)(spec_b + (size_t)ssm[k] * CD + d0);
        a0 += w * __uint_as_float(u.x << 16);
        a1 += w * __uint_as_float(u.x & 0xffff0000u);
        a2 += w * __uint_as_float(u.y << 16);
        a3 += w * __uint_as_float(u.y & 0xffff0000u);
    }
    float ss = a0 * a0 + a1 * a1 + a2 * a2 + a3 * a3;
    float tot = blockSum256(ss);
    float sc = rsqrtf(tot / CD + CEPS);
    float4 o;
    o.x = a0 * sc * fnw[d0];     o.y = a1 * sc * fnw[d0 + 1];
    o.z = a2 * sc * fnw[d0 + 2]; o.w = a3 * sc * fnw[d0 + 3];
    *(float4*)(normX + (size_t)t * CD + d0) = o;
}

__global__ void k_pool(const float* __restrict__ nx, float* __restrict__ pooled) {
    int b = blockIdx.y;
    int d = blockIdx.x * 256 + threadIdx.x;
    float s = 0.f;
    for (int t = 0; t < CS; ++t) s += nx[((size_t)(b * CS + t)) * CD + d];
    pooled[b * CD + d] = s * (1.f / CS);
}

__global__ void k_head(const float* __restrict__ pooled, const float* __restrict__ cw,
                       const float* __restrict__ cb, float* __restrict__ out) {
    __shared__ float lg[CB * CNC];
    int i = threadIdx.x;
    if (i < CB * CNC) {
        int b = i / CNC, c = i % CNC;
        float s = cb[c];
        for (int d = 0; d < CD; ++d) s += pooled[b * CD + d] * cw[(size_t)d * CNC + c];
        lg[i] = s;
    }
    __syncthreads();
    if (i < CB) {
        float mx = -1e30f;
        for (int c = 0; c < CNC; ++c) mx = fmaxf(mx, lg[i * CNC + c]);
        float ex[CNC]; float s = 0.f;
        for (int c = 0; c < CNC; ++c) { ex[c] = __expf(lg[i * CNC + c] - mx); s += ex[c]; }
        for (int c = 0; c < CNC; ++c) out[i * CNC + c] = ex[c] / s;
    }
}

} // namespace

extern "C" void kernel_launch(void* const* d_in, const int* in_sizes, int n_in,
                              void* d_out, int out_size, void* d_ws, size_t ws_size,
                              hipStream_t stream) {
    const int*   tokens = (const int*)d_in[0];
    const float* emb    = (const float*)d_in[1];
    const float* n1w    = (const float*)d_in[2];
    const float* n2w    = (const float*)d_in[3];
    const float* Wq     = (const float*)d_in[4];
    const float* Wk     = (const float*)d_in[5];
    const float* Wv     = (const float*)d_in[6];
    const float* Wo     = (const float*)d_in[7];
    const float* rw     = (const float*)d_in[8];
    const float* ebias  = (const float*)d_in[9];
    const float* shw1   = (const float*)d_in[10];
    const float* shw3   = (const float*)d_in[11];
    const float* shw2   = (const float*)d_in[12];
    const float* exw1   = (const float*)d_in[13];
    const float* exw3   = (const float*)d_in[14];
    const float* exw2   = (const float*)d_in[15];
    const float* fnw    = (const float*)d_in[16];
    const float* clsw   = (const float*)d_in[17];
    const float* clsb   = (const float*)d_in[18];
    float* out = (float*)d_out;

    constexpr size_t MB = 1ull << 20;
    char* base = (char*)d_ws;
    float* X   = (float*)(base);             // 16 MB residual / normX
    float* Xh  = (float*)(base + 16 * MB);   // 16 MB X2
    hb*  HSd   = (hb*)(base + 32 * MB);      // 8 MB shared-expert down output (bf16)
    float* pooled  = (float*)(base + 48 * MB);
    float* topw    = pooled + 4096;
    float* logitsB = topw + CT * CKS;
    float* rwT     = logitsB + CT * CE;
    int* topi    = (int*)(rwT + CE * CD);
    int* lists   = topi + CT * CKS;
    int* slot_of = lists + CT * CKS;
    int* counts  = slot_of + CT * CKS;
    int* cursor  = counts + CE;
    int* offs    = cursor + CE;
    char* pool = base + 50 * MB;
    // attention phase
    float* Vc = (float*)(pool);              // 4 MB
    hb* h1b  = (hb*)(pool + 4 * MB);         // 8 MB
    hb* Qbb  = (hb*)(pool + 12 * MB);        // 8 MB
    hb* Kb   = (hb*)(pool + 20 * MB);        // 2 MB
    hb* Vct  = (hb*)(pool + 22 * MB);        // 2 MB
    hb* Pb   = (hb*)(pool + 24 * MB);        // 32 MB
    hb* AOb  = (hb*)(pool + 56 * MB);        // 8 MB
    hb* Wqt  = (hb*)(pool + 64 * MB);        // 2 MB
    hb* Wot  = (hb*)(pool + 66 * MB);        // 2 MB
    hb* Wkt  = (hb*)(pool + 68 * MB);        // 1 MB
    hb* Wvt  = (hb*)(pool + 69 * MB);        // 1 MB
    // moe phase overlays
    hb* h2b   = (hb*)(pool);                 // 8 MB
    hb* HSb   = (hb*)(pool + 8 * MB);        // 4 MB
    hb* g     = (hb*)(pool + 12 * MB);       // 32 MB
    hb* shw1t = (hb*)(pool + 44 * MB);
    hb* shw3t = (hb*)(pool + 45 * MB);
    hb* shw2t = (hb*)(pool + 46 * MB);
    hb* exw1t = (hb*)(pool + 47 * MB);       // 32 MB
    hb* exw3t = (hb*)(pool + 79 * MB);       // 32 MB
    hb* exw2t = (hb*)(pool + 111 * MB);      // 32 MB (ends 193 MB)
    hb* spec_b = exw1t;                      // 64 MB, overlays exw1t+exw3t (dead at down-proj)

    dim3 b256(256);

    // ---- prologue ----
    k_embed<<<CT, b256, 0, stream>>>(tokens, emb, X);
    k_rmsnorm_b<<<CT, b256, 0, stream>>>(X, n1w, h1b);
    k_t32<<<dim3(1, CD / 32), b256, 0, stream>>>(rw, rwT, CD, CE);
    k_cvt_t<<<dim3(CD / 32, CD / 32, 1), b256, 0, stream>>>(Wq, Wqt, CD, CD);
    k_cvt_t<<<dim3(CDKV / 32, CD / 32, 1), b256, 0, stream>>>(Wk, Wkt, CD, CDKV);
    k_cvt_t<<<dim3(CDKV / 32, CD / 32, 1), b256, 0, stream>>>(Wv, Wvt, CD, CDKV);
    k_cvt_t<<<dim3(CD / 32, CD / 32, 1), b256, 0, stream>>>(Wo, Wot, CD, CD);

    // ---- attention (bf16 MFMA) ----
    k_mf<false, false, 0><<<dim3(CD / 128, CT / 128, 1), b256, 0, stream>>>(
        h1b, CD, 0, 0, Wqt, nullptr, CD, 0, 0, nullptr, nullptr, Qbb, CD, 0, 0,
        nullptr, nullptr, CT, CD, CD, 1, 1.f);
    k_mf<false, false, 0><<<dim3(CDKV / 128, CT / 128, 1), b256, 0, stream>>>(
        h1b, CD, 0, 0, Wkt, nullptr, CD, 0, 0, nullptr, nullptr, Kb, CDKV, 0, 0,
        nullptr, nullptr, CT, CDKV, CD, 1, 1.f);
    k_mf<false, false, 2><<<dim3(CDKV / 128, CT / 128, 1), b256, 0, stream>>>(
        h1b, CD, 0, 0, Wvt, nullptr, CD, 0, 0, nullptr, Vc, nullptr, CDKV, 0, 0,
        nullptr, nullptr, CT, CDKV, CD, 1, 1.f);
    k_cvt_t<<<dim3(CDKV / 32, CS / 32, CB), b256, 0, stream>>>(Vc, Vct, CS, CDKV);
    k_mf<false, false, 0><<<dim3(CS / 128, CS / 128, CB * CH), b256, 0, stream>>>(
        Qbb, CD, (long)CS * CD, CDK,
        Kb, nullptr, CDKV, (long)CS * CDKV, 0,
        nullptr, nullptr, Pb, CS, (long)CH * CS * CS, (long)CS * CS,
        nullptr, nullptr, CS, CS, CDK, CH, 1.f / 16.f);
    k_softmaxb<<<CB * CH * CS, b256, 0, stream>>>(Pb);
    k_mf<false, false, 0><<<dim3(CDK / 128, CS / 128, CB * CH), b256, 0, stream>>>(
        Pb, CS, (long)CH * CS * CS, (long)CS * CS,
        Vct, nullptr, CS, (long)CDKV * CS, 0,
        nullptr, nullptr, AOb, CD, (long)CS * CD, CDK,
        nullptr, nullptr, CS, CDK, CS, CH, 1.f);
    k_mf<false, false, 4><<<dim3(CD / 128, CT / 128, 1), b256, 0, stream>>>(
        AOb, CD, 0, 0, Wot, nullptr, CD, 0, 0, X, Xh, nullptr, CD, 0, 0,
        nullptr, nullptr, CT, CD, CD, 1, 1.f);

    // ---- MoE routing ----
    k_rmsnorm_b<<<CT, b256, 0, stream>>>(Xh, n2w, h2b);
    hipMemsetAsync(counts, 0, (size_t)(CE + CE + CE + 1) * sizeof(int), stream);
    k_logits<<<CT / 8, b256, 0, stream>>>(h2b, rwT, ebias, logitsB);
    k_route<<<CT / 256, b256, 0, stream>>>(logitsB, topi, topw, counts);
    k_scan<<<1, 64, 0, stream>>>(counts, offs);
    k_fill<<<CT * CKS / 256, b256, 0, stream>>>(topi, offs, cursor, lists, slot_of);

    // MoE weight converts
    k_cvt_t<<<dim3(CF / 32, CD / 32, 1), b256, 0, stream>>>(shw1, shw1t, CD, CF);
    k_cvt_t<<<dim3(CF / 32, CD / 32, 1), b256, 0, stream>>>(shw3, shw3t, CD, CF);
    k_cvt_t<<<dim3(CD / 32, CF / 32, 1), b256, 0, stream>>>(shw2, shw2t, CF, CD);
    k_cvt_t<<<dim3(CF / 32, CD / 32, CE), b256, 0, stream>>>(exw1, exw1t, CD, CF);
    k_cvt_t<<<dim3(CF / 32, CD / 32, CE), b256, 0, stream>>>(exw3, exw3t, CD, CF);
    k_cvt_t<<<dim3(CD / 32, CF / 32, CE), b256, 0, stream>>>(exw2, exw2t, CF, CD);

    // shared expert: HSb = silu(h2@w1)*(h2@w3); HSd = (HSb @ w2) bf16
    k_mf<false, true, 0><<<dim3(CF / 128, CT / 128, 1), b256, 0, stream>>>(
        h2b, CD, 0, 0, shw1t, shw3t, CD, 0, 0, nullptr, nullptr, HSb, CF, 0, 0,
        nullptr, nullptr, CT, CF, CD, 1, 1.f);
    // routed experts: g[slot] = silu/mul up-proj (gathered A rows)
    k_mf<true, true, 0><<<dim3(CF / 128, CT / 128, CE), b256, 0, stream>>>(
        h2b, CD, 0, 0, exw1t, exw3t, CD, (long)CD * CF, 0, nullptr, nullptr, g, CF, 0, 0,
        lists, offs, 0, CF, CD, 1, 1.f);
    // shared down
    k_mf<false, false, 0><<<dim3(CD / 128, CT / 128, 1), b256, 0, stream>>>(
        HSb, CF, 0, 0, shw2t, nullptr, CF, 0, 0, nullptr, nullptr, HSd, CD, 0, 0,
        nullptr, nullptr, CT, CD, CF, 1, 1.f);
    // routed down: spec_b[slot] = g[slot] @ w2[e]  (plain bf16 rows, no atomics)
    k_mf<false, false, 0><<<dim3(CD / 128, CT / 128, CE), b256, 0, stream>>>(
        g, CF, 0, 0, exw2t, nullptr, CF, (long)CF * CD, 0, nullptr, nullptr, spec_b, CD, 0, 0,
        nullptr, offs, 0, CD, CF, 1, 1.f);

    // fused: X3 = X2 + HSd + sum_k topw*spec_b ; final rmsnorm -> X (normX)
    k_combine<<<CT, b256, 0, stream>>>(Xh, HSd, spec_b, topw, slot_of, fnw, X);

    // head
    k_pool<<<dim3(CD / 256, CB), b256, 0, stream>>>(X, pooled);
    k_head<<<1, b256, 0, stream>>>(pooled, clsw, clsb, out);
}